// Round 5
// baseline (1374.185 us; speedup 1.0000x reference)
//
#include <hip/hip_runtime.h>
#include <math.h>

typedef unsigned short u16;
typedef u16 u16x4 __attribute__((ext_vector_type(4)));
typedef u16 u16x8 __attribute__((ext_vector_type(8)));

__device__ __forceinline__ float b2f(u16 u) {
    return __uint_as_float(((unsigned)u) << 16);
}
__device__ __forceinline__ u16 f2b(float f) {        // RNE
    unsigned u = __float_as_uint(f);
    unsigned r = (u + 0x7FFFu + ((u >> 16) & 1u)) >> 16;
    return (u16)r;
}

// ---------------------------------------------------------------------------
// fp32 -> bf16 table conversion (vectorized float4 -> u16x4)
// ---------------------------------------------------------------------------
__global__ __launch_bounds__(256) void k_cvt(
    const float* __restrict__ in, u16* __restrict__ out, int n4)
{
    int i = blockIdx.x * 256 + threadIdx.x;
    if (i < n4) {
        float4 v = ((const float4*)in)[i];
        u16x4 o = { f2b(v.x), f2b(v.y), f2b(v.z), f2b(v.w) };
        *(u16x4*)(out + (size_t)i * 4) = o;
    }
}

// ---------------------------------------------------------------------------
// Vocab projection fp32: out[v][j] = dot(emb[v], W[j]) + bias[j], stride 152.
// ---------------------------------------------------------------------------
__global__ __launch_bounds__(256) void k_proj(
    const float* __restrict__ W, const float* __restrict__ bias,
    const float* __restrict__ emb, float* __restrict__ out, int K, int V)
{
    __shared__ float smem[9728];
    __shared__ const float* rptr[64];
    float* eT = smem;
    float* wT = smem + 64 * 44;
    const int t = threadIdx.x;
    const long blockR = (long)blockIdx.x * 64;

    if (t < 64) {
        long gr = blockR + t;
        if (gr >= V) gr = V - 1;
        rptr[t] = emb + (size_t)gr * (size_t)K;
    }
    const int r0 = t & 31, r1 = r0 + 32, jg = t >> 5;

    float acc0[19], acc1[19];
#pragma unroll
    for (int i = 0; i < 19; ++i) {
        int j = jg + 8 * i;
        float b = (j < 150) ? bias[j] : 0.f;
        acc0[i] = b; acc1[i] = b;
    }
    const int nch = K / 40;
    for (int c = 0; c < nch; ++c) {
        const int k0 = c * 40;
        __syncthreads();
        for (int fid = t; fid < 640; fid += 256) {
            int r = fid / 10, ko = (fid % 10) * 4;
            *(float4*)&eT[r * 44 + ko] = *(const float4*)(rptr[r] + k0 + ko);
        }
        for (int fid = t; fid < 1500; fid += 256) {
            int r = fid / 10, ko = (fid % 10) * 4;
            *(float4*)&wT[r * 44 + ko] = *(const float4*)(W + (size_t)r * K + k0 + ko);
        }
        __syncthreads();
#pragma unroll
        for (int kk = 0; kk < 40; kk += 4) {
            float4 a0 = *(float4*)&eT[r0 * 44 + kk];
            float4 a1 = *(float4*)&eT[r1 * 44 + kk];
#pragma unroll
            for (int i = 0; i < 19; ++i) {
                int j = jg + 8 * i;
                float4 w = *(float4*)&wT[j * 44 + kk];
                acc0[i] += a0.x * w.x + a0.y * w.y + a0.z * w.z + a0.w * w.w;
                acc1[i] += a1.x * w.x + a1.y * w.y + a1.z * w.z + a1.w * w.w;
            }
        }
    }
    __syncthreads();
#pragma unroll
    for (int i = 0; i < 19; ++i) {
        int j = jg + 8 * i;
        if (j < 150) { smem[r0 * 152 + j] = acc0[i]; smem[r1 * 152 + j] = acc1[i]; }
    }
    __syncthreads();
    float4* og = (float4*)(out + blockR * 152);
    for (int fid = t; fid < 2432; fid += 256)
        og[fid] = *(float4*)&smem[fid * 4];
}

// ---------------------------------------------------------------------------
// Vocab projection with bf16-packed output (stride 152 shorts).
// ---------------------------------------------------------------------------
__global__ __launch_bounds__(256) void k_proj_b16(
    const float* __restrict__ W, const float* __restrict__ bias,
    const float* __restrict__ emb, u16* __restrict__ out, int K, int V)
{
    __shared__ float smem[9728];
    __shared__ const float* rptr[64];
    float* eT = smem;
    float* wT = smem + 64 * 44;
    const int t = threadIdx.x;
    const long blockR = (long)blockIdx.x * 64;

    if (t < 64) {
        long gr = blockR + t;
        if (gr >= V) gr = V - 1;
        rptr[t] = emb + (size_t)gr * (size_t)K;
    }
    const int r0 = t & 31, r1 = r0 + 32, jg = t >> 5;

    float acc0[19], acc1[19];
#pragma unroll
    for (int i = 0; i < 19; ++i) {
        int j = jg + 8 * i;
        float b = (j < 150) ? bias[j] : 0.f;
        acc0[i] = b; acc1[i] = b;
    }
    const int nch = K / 40;
    for (int c = 0; c < nch; ++c) {
        const int k0 = c * 40;
        __syncthreads();
        for (int fid = t; fid < 640; fid += 256) {
            int r = fid / 10, ko = (fid % 10) * 4;
            *(float4*)&eT[r * 44 + ko] = *(const float4*)(rptr[r] + k0 + ko);
        }
        for (int fid = t; fid < 1500; fid += 256) {
            int r = fid / 10, ko = (fid % 10) * 4;
            *(float4*)&wT[r * 44 + ko] = *(const float4*)(W + (size_t)r * K + k0 + ko);
        }
        __syncthreads();
#pragma unroll
        for (int kk = 0; kk < 40; kk += 4) {
            float4 a0 = *(float4*)&eT[r0 * 44 + kk];
            float4 a1 = *(float4*)&eT[r1 * 44 + kk];
#pragma unroll
            for (int i = 0; i < 19; ++i) {
                int j = jg + 8 * i;
                float4 w = *(float4*)&wT[j * 44 + kk];
                acc0[i] += a0.x * w.x + a0.y * w.y + a0.z * w.z + a0.w * w.w;
                acc1[i] += a1.x * w.x + a1.y * w.y + a1.z * w.z + a1.w * w.w;
            }
        }
    }
    __syncthreads();
#pragma unroll
    for (int i = 0; i < 19; ++i) {
        int j = jg + 8 * i;
        if (j < 150) { smem[r0 * 152 + j] = acc0[i]; smem[r1 * 152 + j] = acc1[i]; }
    }
    __syncthreads();
    u16* og = out + blockR * 152;
    for (int fid = t; fid < 1216; fid += 256) {           // 64*152/8
        float4 a = *(float4*)&smem[fid * 8];
        float4 b = *(float4*)&smem[fid * 8 + 4];
        u16x8 v = { f2b(a.x), f2b(a.y), f2b(a.z), f2b(a.w),
                    f2b(b.x), f2b(b.y), f2b(b.z), f2b(b.w) };
        *(u16x8*)(og + fid * 8) = v;
    }
}

// ---------------------------------------------------------------------------
// Generic GEMM (direct rows): out[r][j] (stride 152) = dot(src[r], W[j]) + b[j]
// ---------------------------------------------------------------------------
__global__ __launch_bounds__(256) void k_gemm150(
    const float* __restrict__ W, const float* __restrict__ bias,
    const float* __restrict__ src, float* __restrict__ out, int K)
{
    __shared__ float smem[9728];
    __shared__ const float* rptr[64];
    float* eT = smem;
    float* wT = smem + 64 * 44;
    const int t = threadIdx.x;
    const long blockR = (long)blockIdx.x * 64;

    if (t < 64) rptr[t] = src + (size_t)(blockR + t) * (size_t)K;
    const int r0 = t & 31, r1 = r0 + 32, jg = t >> 5;

    float acc0[19], acc1[19];
#pragma unroll
    for (int i = 0; i < 19; ++i) {
        int j = jg + 8 * i;
        float b = (j < 150) ? bias[j] : 0.f;
        acc0[i] = b; acc1[i] = b;
    }
    const int nch = K / 40;
    for (int c = 0; c < nch; ++c) {
        const int k0 = c * 40;
        __syncthreads();
        for (int fid = t; fid < 640; fid += 256) {
            int r = fid / 10, ko = (fid % 10) * 4;
            *(float4*)&eT[r * 44 + ko] = *(const float4*)(rptr[r] + k0 + ko);
        }
        for (int fid = t; fid < 1500; fid += 256) {
            int r = fid / 10, ko = (fid % 10) * 4;
            *(float4*)&wT[r * 44 + ko] = *(const float4*)(W + (size_t)r * K + k0 + ko);
        }
        __syncthreads();
#pragma unroll
        for (int kk = 0; kk < 40; kk += 4) {
            float4 a0 = *(float4*)&eT[r0 * 44 + kk];
            float4 a1 = *(float4*)&eT[r1 * 44 + kk];
#pragma unroll
            for (int i = 0; i < 19; ++i) {
                int j = jg + 8 * i;
                float4 w = *(float4*)&wT[j * 44 + kk];
                acc0[i] += a0.x * w.x + a0.y * w.y + a0.z * w.z + a0.w * w.w;
                acc1[i] += a1.x * w.x + a1.y * w.y + a1.z * w.z + a1.w * w.w;
            }
        }
    }
    __syncthreads();
#pragma unroll
    for (int i = 0; i < 19; ++i) {
        int j = jg + 8 * i;
        if (j < 150) { smem[r0 * 152 + j] = acc0[i]; smem[r1 * 152 + j] = acc1[i]; }
    }
    __syncthreads();
    float4* og = (float4*)(out + blockR * 152);
    for (int fid = t; fid < 2432; fid += 256)
        og[fid] = *(float4*)&smem[fid * 4];
}

// ---------------------------------------------------------------------------
// GRU scan. MODE 0: direct fp32 xp (stride 152), fp32 hs.
//           MODE 1: gather fp32 xp via idx, fp32 hs.
//           MODE 2: gather bf16 xp via idx, bf16 hs.
// 8 seqs/block; double-buffered prefetch of next step's x rows.
// ---------------------------------------------------------------------------
template<int MODE>
__global__ __launch_bounds__(256) void k_gru_scan(
    const void* __restrict__ xp_, const int* __restrict__ idx,
    const float* __restrict__ Whh, const float* __restrict__ bhh,
    void* __restrict__ hs_, int T)
{
    __shared__ float whhT[50 * 160];
    __shared__ float ghL[8 * 160];
    __shared__ float hL[8 * 52];
    __shared__ float xbuf[2][8 * 152];
    const int t = threadIdx.x;
    for (int e = t; e < 7500; e += 256) {
        int k = e / 150, j = e % 150;
        whhT[k * 160 + j] = Whh[j * 50 + k];
    }
    for (int e = t; e < 8 * 52; e += 256) hL[e] = 0.f;

    const int s = t >> 5, jc = t & 31;
    const long seqbase = (long)blockIdx.x * 8;
    float4 bb4 = *(const float4*)(bhh + 4 * jc);
    float bt = (jc < 22) ? bhh[128 + jc] : 0.f;

    const float* xpf = (const float*)xp_;
    const u16*   xph = (const u16*)xp_;
    float* hsf = (float*)hs_;
    u16*   hsh = (u16*)hs_;

    // prefetch mapping
    const int rA = (MODE == 2) ? t / 19 : t / 38;
    const int oA = (MODE == 2) ? (t % 19) * 8 : (t % 38) * 4;
    const int rB = (t + 256) / 38, oB = ((t + 256) % 38) * 4;
    const bool actA = (MODE == 2) ? (t < 152) : true;
    const bool hasB = (MODE == 2) ? false : (t < 48);

    auto rowbase = [&](int rr, int stp) -> size_t {
        long r = seqbase + rr;
        long src = (MODE == 0) ? (r * T + stp) : (long)idx[r * T + stp];
        return (size_t)src * 152;
    };

    if (MODE == 2) {
        if (actA) {
            u16x8 v = *(const u16x8*)(xph + rowbase(rA, 0) + oA);
            float4 lo = { b2f(v[0]), b2f(v[1]), b2f(v[2]), b2f(v[3]) };
            float4 hi = { b2f(v[4]), b2f(v[5]), b2f(v[6]), b2f(v[7]) };
            *(float4*)&xbuf[0][rA * 152 + oA] = lo;
            *(float4*)&xbuf[0][rA * 152 + oA + 4] = hi;
        }
    } else {
        *(float4*)&xbuf[0][rA * 152 + oA] = *(const float4*)(xpf + rowbase(rA, 0) + oA);
        if (hasB)
            *(float4*)&xbuf[0][rB * 152 + oB] = *(const float4*)(xpf + rowbase(rB, 0) + oB);
    }
    __syncthreads();

    for (int st = 0; st < T; ++st) {
        const int cur = st & 1;
        u16x8 pfh;
        float4 pf0, pf1;
        if (st + 1 < T) {
            if (MODE == 2) {
                if (actA) pfh = *(const u16x8*)(xph + rowbase(rA, st + 1) + oA);
            } else {
                pf0 = *(const float4*)(xpf + rowbase(rA, st + 1) + oA);
                if (hasB) pf1 = *(const float4*)(xpf + rowbase(rB, st + 1) + oB);
            }
        }
        // GEMV: g[j] = bhh[j] + sum_k h[k] * Whh[j][k]
        float4 g4 = bb4; float gt = bt;
#pragma unroll 10
        for (int k = 0; k < 50; ++k) {
            float hk = hL[s * 52 + k];
            float4 w4 = *(float4*)&whhT[k * 160 + 4 * jc];
            g4.x += hk * w4.x; g4.y += hk * w4.y;
            g4.z += hk * w4.z; g4.w += hk * w4.w;
            if (jc < 22) gt += hk * whhT[k * 160 + 128 + jc];
        }
        *(float4*)&ghL[s * 160 + 4 * jc] = g4;
        if (jc < 22) ghL[s * 160 + 128 + jc] = gt;
        __syncthreads();
        if (st + 1 < T) {
            if (MODE == 2) {
                if (actA) {
                    float4 lo = { b2f(pfh[0]), b2f(pfh[1]), b2f(pfh[2]), b2f(pfh[3]) };
                    float4 hi = { b2f(pfh[4]), b2f(pfh[5]), b2f(pfh[6]), b2f(pfh[7]) };
                    *(float4*)&xbuf[cur ^ 1][rA * 152 + oA] = lo;
                    *(float4*)&xbuf[cur ^ 1][rA * 152 + oA + 4] = hi;
                }
            } else {
                *(float4*)&xbuf[cur ^ 1][rA * 152 + oA] = pf0;
                if (hasB) *(float4*)&xbuf[cur ^ 1][rB * 152 + oB] = pf1;
            }
        }
        for (int item = t; item < 400; item += 256) {
            int ss = item / 50, hh = item % 50;
            const float* xr = &xbuf[cur][ss * 152];
            float vr  = xr[hh]       + ghL[ss * 160 + hh];
            float vz  = xr[50 + hh]  + ghL[ss * 160 + 50 + hh];
            float ghn = ghL[ss * 160 + 100 + hh];
            float r = 1.f / (1.f + __expf(-vr));
            float z = 1.f / (1.f + __expf(-vz));
            float a = xr[100 + hh] + r * ghn;
            a = fminf(fmaxf(a, -15.f), 15.f);
            float e2 = __expf(-2.f * a);
            float n = (1.f - e2) / (1.f + e2);
            float hn = (1.f - z) * n + z * hL[ss * 52 + hh];
            hL[ss * 52 + hh] = hn;
            size_t ofs = ((seqbase + ss) * T + st) * 50 + hh;
            if (MODE == 2) hsh[ofs] = f2b(hn); else hsf[ofs] = hn;
        }
        __syncthreads();
    }
}

// ---------------------------------------------------------------------------
// ctx_hA[r][k] = sum_j ctx_h[r][j] * A[j][k]
// ---------------------------------------------------------------------------
__global__ __launch_bounds__(256) void k_matA(
    const float* __restrict__ inp, const float* __restrict__ A,
    float* __restrict__ outp)
{
    __shared__ float AL[50 * 52];
    __shared__ float inL[32 * 52];
    const int t = threadIdx.x;
    for (int e = t; e < 2500; e += 256) AL[(e / 50) * 52 + (e % 50)] = A[e];
    const long rbase = (long)blockIdx.x * 32;
    for (int e = t; e < 1600; e += 256) {
        int r = e / 50, j = e % 50;
        inL[r * 52 + j] = inp[(rbase + r) * 50 + j];
    }
    __syncthreads();
    for (int item = t; item < 1600; item += 256) {
        int r = item / 50, kk = item % 50;
        float acc = 0.f;
#pragma unroll 10
        for (int j = 0; j < 50; ++j)
            acc += inL[r * 52 + j] * AL[j * 52 + kk];
        outp[(rbase + r) * 50 + kk] = acc;
    }
}

// ---------------------------------------------------------------------------
// Fused match (M1 bf16-emb or M2 fp32xbf16) + conv3x3 + maxpool3x3/3.
// M tile stride 33 (conflict-free conv reads); M1 LDS stride 100 (4-way min).
// ---------------------------------------------------------------------------
__global__ __launch_bounds__(256) void k_matchconv(
    const u16* __restrict__ embh, const int* __restrict__ ctx_idx,
    const int* __restrict__ cand_idx, const float* __restrict__ ctxA,
    const u16* __restrict__ candh_h, const float* __restrict__ conv_w,
    float* __restrict__ feats, int b0)
{
    __shared__ float Msh[2][1056];
    __shared__ float wL[144];
    __shared__ float pool[9600];   // M1: ctxL[32][100] + canL[64][100]; M2 prefix
    __shared__ int ci[32], qi[2][32];
    const int t = threadIdx.x;
    const int nl = blockIdx.x;
    const int bl = nl / 14, r = nl % 14;
    const int b = b0 + bl;
    const int q = t & 31, pb = t >> 5;
    float acc[2][4] = { {0,0,0,0}, {0,0,0,0} };

    if (t < 144) wL[t] = conv_w[t];

    if (r < 7) {
        const int c0 = 2 * r;
        if (t < 32) ci[t] = ctx_idx[b * 32 + t];
        else if (t < 96)
            qi[(t - 32) >> 5][t & 31] =
                cand_idx[((long)b * 14 + c0 + ((t - 32) >> 5)) * 32 + (t & 31)];
        float* ctxL = pool;                  // [32][100]
        float* canL = pool + 3200;           // [64][100]
        for (int kc = 0; kc < 200; kc += 100) {
            __syncthreads();
            for (int fid = t; fid < 2400; fid += 256) {
                int mat = fid / 800, rr = (fid % 800) / 25, k4 = fid % 25;
                int row = (mat == 0) ? ci[rr] : qi[mat - 1][rr];
                u16x4 v = *(const u16x4*)(embh + (size_t)row * 200 + kc + k4 * 4);
                float4 f = { b2f(v[0]), b2f(v[1]), b2f(v[2]), b2f(v[3]) };
                float* dst = (mat == 0) ? &ctxL[rr * 100 + k4 * 4]
                                        : &canL[((mat - 1) * 32 + rr) * 100 + k4 * 4];
                *(float4*)dst = f;
            }
            __syncthreads();
            for (int k4 = 0; k4 < 25; ++k4) {
                float4 cq0 = *(float4*)&canL[q * 100 + k4 * 4];
                float4 cq1 = *(float4*)&canL[(32 + q) * 100 + k4 * 4];
#pragma unroll
                for (int i = 0; i < 4; ++i) {
                    float4 cp = *(float4*)&ctxL[(pb + 8 * i) * 100 + k4 * 4];  // broadcast
                    acc[0][i] += cp.x * cq0.x + cp.y * cq0.y + cp.z * cq0.z + cp.w * cq0.w;
                    acc[1][i] += cp.x * cq1.x + cp.y * cq1.y + cp.z * cq1.z + cp.w * cq1.w;
                }
            }
        }
    } else {
        const int c0 = 2 * (r - 7);
        float* aL = pool;               // [32][53]
        float* cL = pool + 32 * 53;     // [2][32][53]
        for (int e = t; e < 1600; e += 256) {
            int rr = e / 50, k = e % 50;
            aL[rr * 53 + k] = ctxA[((long)b * 32 + rr) * 50 + k];
            cL[rr * 53 + k]        = b2f(candh_h[(((long)bl * 14 + c0) * 32 + rr) * 50 + k]);
            cL[(32 + rr) * 53 + k] = b2f(candh_h[(((long)bl * 14 + c0 + 1) * 32 + rr) * 50 + k]);
        }
        __syncthreads();
#pragma unroll 10
        for (int k = 0; k < 50; ++k) {
            float cq0 = cL[q * 53 + k];
            float cq1 = cL[(32 + q) * 53 + k];
#pragma unroll
            for (int i = 0; i < 4; ++i) {
                float a = aL[(pb + 8 * i) * 53 + k];
                acc[0][i] += a * cq0;
                acc[1][i] += a * cq1;
            }
        }
    }

#pragma unroll
    for (int i = 0; i < 4; ++i) {
        Msh[0][(pb + 8 * i) * 33 + q] = acc[0][i];
        Msh[1][(pb + 8 * i) * 33 + q] = acc[1][i];
    }
    __syncthreads();

    for (int item = t; item < 800; item += 256) {
        int oc = item / 100, rem = item % 100, py = rem / 10, px = rem % 10;
        float pv[2][5][5];
#pragma unroll
        for (int ch = 0; ch < 2; ++ch)
#pragma unroll
            for (int dy = 0; dy < 5; ++dy)
#pragma unroll
                for (int dx = 0; dx < 5; ++dx)
                    pv[ch][dy][dx] = Msh[ch][(3 * py + dy) * 33 + (3 * px + dx)];
        float m = -1e30f;
#pragma unroll
        for (int dy0 = 0; dy0 < 3; ++dy0)
#pragma unroll
            for (int dx0 = 0; dx0 < 3; ++dx0) {
                float sacc = 0.f;
#pragma unroll
                for (int ch = 0; ch < 2; ++ch)
#pragma unroll
                    for (int ky = 0; ky < 3; ++ky)
#pragma unroll
                        for (int kx = 0; kx < 3; ++kx)
                            sacc += pv[ch][dy0 + ky][dx0 + kx] * wL[(oc * 2 + ch) * 9 + ky * 3 + kx];
                m = fmaxf(m, sacc);
            }
        feats[(long)nl * 800 + item] = m;
    }
}

// ---------------------------------------------------------------------------
__global__ __launch_bounds__(128) void k_fc1(
    const float* __restrict__ Hs, const float* __restrict__ w,
    const float* __restrict__ bias, float* __restrict__ hid)
{
    __shared__ float hr[700];
    const int t = threadIdx.x;
    const long b = blockIdx.x;
    for (int e = t; e < 700; e += 128) hr[e] = Hs[b * 700 + e];
    __syncthreads();
    if (t < 100) {
        float acc = bias[t];
        const float4* wp = (const float4*)(w + (size_t)t * 700);
        for (int k4 = 0; k4 < 175; ++k4) {
            float4 wv = wp[k4];
            float4 hv = *(float4*)&hr[k4 * 4];
            acc += wv.x * hv.x + wv.y * hv.y + wv.z * hv.z + wv.w * hv.w;
        }
        hid[b * 100 + t] = fmaxf(acc, 0.f);
    }
}

__global__ __launch_bounds__(64) void k_final(
    const float* __restrict__ hid, const float* __restrict__ w2,
    const float* __restrict__ b2, const float* __restrict__ y,
    float* __restrict__ partial)
{
    __shared__ float hL[100];
    const int t = threadIdx.x;
    const long b = blockIdx.x;
    for (int e = t; e < 100; e += 64) hL[e] = hid[b * 100 + e];
    __syncthreads();
    float logit = -1e30f;
    if (t < 14) {
        logit = b2[t];
        for (int k = 0; k < 100; ++k) logit += hL[k] * w2[t * 100 + k];
    }
    float m = logit;
    for (int off = 8; off; off >>= 1) m = fmaxf(m, __shfl_xor(m, off, 16));
    float ex = (t < 14) ? __expf(logit - m) : 0.f;
    float se = ex;
    for (int off = 8; off; off >>= 1) se += __shfl_xor(se, off, 16);
    float kl = 0.f;
    if (t < 14) {
        float lp = logit - m - __logf(se);
        float yv = y[b * 14 + t];
        kl = (yv > 0.f) ? yv * (__logf(yv) - lp) : 0.f;
    }
    for (int off = 8; off; off >>= 1) kl += __shfl_xor(kl, off, 16);
    if (t == 0) partial[b] = kl;
}

__global__ __launch_bounds__(256) void k_reduce(
    const float* __restrict__ partial, float* __restrict__ out)
{
    __shared__ float sm[256];
    const int t = threadIdx.x;
    sm[t] = partial[t] + partial[t + 256] + partial[t + 512] + partial[t + 768];
    __syncthreads();
    for (int off = 128; off; off >>= 1) {
        if (t < off) sm[t] += sm[t + off];
        __syncthreads();
    }
    if (t == 0) out[0] = sm[0] * (1.f / 14336.f);
}

// ---------------------------------------------------------------------------
extern "C" void kernel_launch(void* const* d_in, const int* in_sizes, int n_in,
                              void* d_out, int out_size, void* d_ws, size_t ws_size,
                              hipStream_t stream)
{
    const int*   ctx_idx  = (const int*)d_in[0];
    const int*   cand_idx = (const int*)d_in[1];
    const float* y_dev    = (const float*)d_in[2];
    const float* emb      = (const float*)d_in[3];
    const float* A        = (const float*)d_in[4];
    const float* Wih_c    = (const float*)d_in[5];
    const float* Whh_c    = (const float*)d_in[6];
    const float* bih_c    = (const float*)d_in[7];
    const float* bhh_c    = (const float*)d_in[8];
    const float* Wih_r    = (const float*)d_in[9];
    const float* Whh_r    = (const float*)d_in[10];
    const float* bih_r    = (const float*)d_in[11];
    const float* bhh_r    = (const float*)d_in[12];
    const float* conv_w   = (const float*)d_in[13];
    const float* Wih2     = (const float*)d_in[14];
    const float* Whh2     = (const float*)d_in[15];
    const float* bih2     = (const float*)d_in[16];
    const float* bhh2     = (const float*)d_in[17];
    const float* fc1_w    = (const float*)d_in[18];
    const float* fc1_b    = (const float*)d_in[19];
    const float* fc2_w    = (const float*)d_in[20];
    const float* fc2_b    = (const float*)d_in[21];

    float* ws = (float*)d_ws;
    // Arena (float slots), total 36,156,448 = 144.6 MB
    u16*   embh    = (u16*)ws;               // [21128][200] bf16 = 2,112,800 f
    float* proj_c  = ws + 2112800;           // [21184][152] f32  = 3,219,968 f
    u16*   proj_rh = (u16*)(ws + 5332768);   // [21184][152] bf16 = 1,609,984 f
    float* ctx_h   = ws + 6942752;           // 1,638,400
    float* ctxA    = ws + 8581152;           // 1,638,400
    u16*   candh_h = (u16*)(ws + 10219552);  // [14336*32][50] bf16 = 11,468,800 f
    float* feats   = ws + 21688352;          // 11,468,800
    float* xp2     = ws + 33157152;          // [14336][152] = 2,179,072
    float* hs2     = ws + 35336224;          // 716,800
    float* hid     = ws + 36053024;          // 102,400
    float* part    = ws + 36155424;          // 1,024

    // 0. bf16 emb table
    k_cvt      <<<4127, 256, 0, stream>>>(emb, embh, 1056400);
    // 1. vocab projections (bih folded)
    k_proj     <<<331, 256, 0, stream>>>(Wih_c, bih_c, emb, proj_c, 200, 21128);
    k_proj_b16 <<<331, 256, 0, stream>>>(Wih_r, bih_r, emb, proj_rh, 200, 21128);
    // 2. GRU scans (gather from proj tables)
    k_gru_scan<1><<<128,  256, 0, stream>>>(proj_c, ctx_idx,  Whh_c, bhh_c, ctx_h, 32);
    k_gru_scan<2><<<1792, 256, 0, stream>>>(proj_rh, cand_idx, Whh_r, bhh_r, candh_h, 32);
    k_matA     <<<1024, 256, 0, stream>>>(ctx_h, A, ctxA);
    // 3. match + conv + pool
    k_matchconv<<<14336, 256, 0, stream>>>(embh, ctx_idx, cand_idx, ctxA, candh_h,
                                           conv_w, feats, 0);
    // 4. accumulation GRU + head
    k_gemm150  <<<224, 256, 0, stream>>>(Wih2, bih2, feats, xp2, 800);
    k_gru_scan<0><<<128, 256, 0, stream>>>(xp2, nullptr, Whh2, bhh2, hs2, 14);
    k_fc1      <<<1024, 128, 0, stream>>>(hs2, fc1_w, fc1_b, hid);
    k_final    <<<1024, 64, 0, stream>>>(hid, fc2_w, fc2_b, y_dev, part);
    k_reduce   <<<1, 256, 0, stream>>>(part, (float*)d_out);
}

// Round 6
// 863.902 us; speedup vs baseline: 1.5907x; 1.5907x over previous
//
#include <hip/hip_runtime.h>
#include <math.h>

typedef unsigned short u16;
typedef short s16;
typedef u16 u16x8 __attribute__((ext_vector_type(8)));
typedef s16 short8v __attribute__((ext_vector_type(8)));
typedef float f32x4 __attribute__((ext_vector_type(4)));

__device__ __forceinline__ float b2f(u16 u) {
    return __uint_as_float(((unsigned)u) << 16);
}
__device__ __forceinline__ u16 f2b(float f) {        // RNE
    unsigned u = __float_as_uint(f);
    unsigned r = (u + 0x7FFFu + ((u >> 16) & 1u)) >> 16;
    return (u16)r;
}

// ---------------------------------------------------------------------------
// fp32 -> bf16 table conversion
// ---------------------------------------------------------------------------
__global__ __launch_bounds__(256) void k_cvt(
    const float* __restrict__ in, u16* __restrict__ out, int n4)
{
    int i = blockIdx.x * 256 + threadIdx.x;
    if (i < n4) {
        float4 v = ((const float4*)in)[i];
        u16 o0 = f2b(v.x), o1 = f2b(v.y), o2 = f2b(v.z), o3 = f2b(v.w);
        u16x8 dummy; (void)dummy;
        *(ushort4*)(out + (size_t)i * 4) = make_ushort4(o0, o1, o2, o3);
    }
}

// ---------------------------------------------------------------------------
// Vocab projection fp32: out[v][j] = dot(emb[v], W[j]) + bias[j], stride 152.
// ---------------------------------------------------------------------------
__global__ __launch_bounds__(256) void k_proj(
    const float* __restrict__ W, const float* __restrict__ bias,
    const float* __restrict__ emb, float* __restrict__ out, int K, int V)
{
    __shared__ float smem[9728];
    __shared__ const float* rptr[64];
    float* eT = smem;
    float* wT = smem + 64 * 44;
    const int t = threadIdx.x;
    const long blockR = (long)blockIdx.x * 64;

    if (t < 64) {
        long gr = blockR + t;
        if (gr >= V) gr = V - 1;
        rptr[t] = emb + (size_t)gr * (size_t)K;
    }
    const int r0 = t & 31, r1 = r0 + 32, jg = t >> 5;

    float acc0[19], acc1[19];
#pragma unroll
    for (int i = 0; i < 19; ++i) {
        int j = jg + 8 * i;
        float b = (j < 150) ? bias[j] : 0.f;
        acc0[i] = b; acc1[i] = b;
    }
    const int nch = K / 40;
    for (int c = 0; c < nch; ++c) {
        const int k0 = c * 40;
        __syncthreads();
        for (int fid = t; fid < 640; fid += 256) {
            int r = fid / 10, ko = (fid % 10) * 4;
            *(float4*)&eT[r * 44 + ko] = *(const float4*)(rptr[r] + k0 + ko);
        }
        for (int fid = t; fid < 1500; fid += 256) {
            int r = fid / 10, ko = (fid % 10) * 4;
            *(float4*)&wT[r * 44 + ko] = *(const float4*)(W + (size_t)r * K + k0 + ko);
        }
        __syncthreads();
#pragma unroll
        for (int kk = 0; kk < 40; kk += 4) {
            float4 a0 = *(float4*)&eT[r0 * 44 + kk];
            float4 a1 = *(float4*)&eT[r1 * 44 + kk];
#pragma unroll
            for (int i = 0; i < 19; ++i) {
                int j = jg + 8 * i;
                float4 w = *(float4*)&wT[j * 44 + kk];
                acc0[i] += a0.x * w.x + a0.y * w.y + a0.z * w.z + a0.w * w.w;
                acc1[i] += a1.x * w.x + a1.y * w.y + a1.z * w.z + a1.w * w.w;
            }
        }
    }
    __syncthreads();
#pragma unroll
    for (int i = 0; i < 19; ++i) {
        int j = jg + 8 * i;
        if (j < 150) { smem[r0 * 152 + j] = acc0[i]; smem[r1 * 152 + j] = acc1[i]; }
    }
    __syncthreads();
    float4* og = (float4*)(out + blockR * 152);
    for (int fid = t; fid < 2432; fid += 256)
        og[fid] = *(float4*)&smem[fid * 4];
}

// ---------------------------------------------------------------------------
// Vocab projection, bf16-packed output (stride 152 shorts).
// ---------------------------------------------------------------------------
__global__ __launch_bounds__(256) void k_proj_b16(
    const float* __restrict__ W, const float* __restrict__ bias,
    const float* __restrict__ emb, u16* __restrict__ out, int K, int V)
{
    __shared__ float smem[9728];
    __shared__ const float* rptr[64];
    float* eT = smem;
    float* wT = smem + 64 * 44;
    const int t = threadIdx.x;
    const long blockR = (long)blockIdx.x * 64;

    if (t < 64) {
        long gr = blockR + t;
        if (gr >= V) gr = V - 1;
        rptr[t] = emb + (size_t)gr * (size_t)K;
    }
    const int r0 = t & 31, r1 = r0 + 32, jg = t >> 5;

    float acc0[19], acc1[19];
#pragma unroll
    for (int i = 0; i < 19; ++i) {
        int j = jg + 8 * i;
        float b = (j < 150) ? bias[j] : 0.f;
        acc0[i] = b; acc1[i] = b;
    }
    const int nch = K / 40;
    for (int c = 0; c < nch; ++c) {
        const int k0 = c * 40;
        __syncthreads();
        for (int fid = t; fid < 640; fid += 256) {
            int r = fid / 10, ko = (fid % 10) * 4;
            *(float4*)&eT[r * 44 + ko] = *(const float4*)(rptr[r] + k0 + ko);
        }
        for (int fid = t; fid < 1500; fid += 256) {
            int r = fid / 10, ko = (fid % 10) * 4;
            *(float4*)&wT[r * 44 + ko] = *(const float4*)(W + (size_t)r * K + k0 + ko);
        }
        __syncthreads();
#pragma unroll
        for (int kk = 0; kk < 40; kk += 4) {
            float4 a0 = *(float4*)&eT[r0 * 44 + kk];
            float4 a1 = *(float4*)&eT[r1 * 44 + kk];
#pragma unroll
            for (int i = 0; i < 19; ++i) {
                int j = jg + 8 * i;
                float4 w = *(float4*)&wT[j * 44 + kk];
                acc0[i] += a0.x * w.x + a0.y * w.y + a0.z * w.z + a0.w * w.w;
                acc1[i] += a1.x * w.x + a1.y * w.y + a1.z * w.z + a1.w * w.w;
            }
        }
    }
    __syncthreads();
#pragma unroll
    for (int i = 0; i < 19; ++i) {
        int j = jg + 8 * i;
        if (j < 150) { smem[r0 * 152 + j] = acc0[i]; smem[r1 * 152 + j] = acc1[i]; }
    }
    __syncthreads();
    u16* og = out + blockR * 152;
    for (int fid = t; fid < 1216; fid += 256) {
        float4 a = *(float4*)&smem[fid * 8];
        float4 b = *(float4*)&smem[fid * 8 + 4];
        u16x8 v = { f2b(a.x), f2b(a.y), f2b(a.z), f2b(a.w),
                    f2b(b.x), f2b(b.y), f2b(b.z), f2b(b.w) };
        *(u16x8*)(og + fid * 8) = v;
    }
}

// ---------------------------------------------------------------------------
// Generic GEMM (direct rows): out[r][j] (stride 152) = dot(src[r], W[j]) + b[j]
// ---------------------------------------------------------------------------
__global__ __launch_bounds__(256) void k_gemm150(
    const float* __restrict__ W, const float* __restrict__ bias,
    const float* __restrict__ src, float* __restrict__ out, int K)
{
    __shared__ float smem[9728];
    __shared__ const float* rptr[64];
    float* eT = smem;
    float* wT = smem + 64 * 44;
    const int t = threadIdx.x;
    const long blockR = (long)blockIdx.x * 64;

    if (t < 64) rptr[t] = src + (size_t)(blockR + t) * (size_t)K;
    const int r0 = t & 31, r1 = r0 + 32, jg = t >> 5;

    float acc0[19], acc1[19];
#pragma unroll
    for (int i = 0; i < 19; ++i) {
        int j = jg + 8 * i;
        float b = (j < 150) ? bias[j] : 0.f;
        acc0[i] = b; acc1[i] = b;
    }
    const int nch = K / 40;
    for (int c = 0; c < nch; ++c) {
        const int k0 = c * 40;
        __syncthreads();
        for (int fid = t; fid < 640; fid += 256) {
            int r = fid / 10, ko = (fid % 10) * 4;
            *(float4*)&eT[r * 44 + ko] = *(const float4*)(rptr[r] + k0 + ko);
        }
        for (int fid = t; fid < 1500; fid += 256) {
            int r = fid / 10, ko = (fid % 10) * 4;
            *(float4*)&wT[r * 44 + ko] = *(const float4*)(W + (size_t)r * K + k0 + ko);
        }
        __syncthreads();
#pragma unroll
        for (int kk = 0; kk < 40; kk += 4) {
            float4 a0 = *(float4*)&eT[r0 * 44 + kk];
            float4 a1 = *(float4*)&eT[r1 * 44 + kk];
#pragma unroll
            for (int i = 0; i < 19; ++i) {
                int j = jg + 8 * i;
                float4 w = *(float4*)&wT[j * 44 + kk];
                acc0[i] += a0.x * w.x + a0.y * w.y + a0.z * w.z + a0.w * w.w;
                acc1[i] += a1.x * w.x + a1.y * w.y + a1.z * w.z + a1.w * w.w;
            }
        }
    }
    __syncthreads();
#pragma unroll
    for (int i = 0; i < 19; ++i) {
        int j = jg + 8 * i;
        if (j < 150) { smem[r0 * 152 + j] = acc0[i]; smem[r1 * 152 + j] = acc1[i]; }
    }
    __syncthreads();
    float4* og = (float4*)(out + blockR * 152);
    for (int fid = t; fid < 2432; fid += 256)
        og[fid] = *(float4*)&smem[fid * 4];
}

// ---------------------------------------------------------------------------
// GRU scan with MFMA GEMV. MODE 0: direct fp32 xp, fp32 hs (stride 50).
// MODE 1: gather fp32 xp via idx, fp32 hs (50). MODE 2: gather bf16 xp,
// bf16 hs (stride 56). 8 seqs/block. G(8x150) = H(8x50)@WhhT via
// mfma_16x16x32_bf16 (k-slot bijection shared by A and B => exact contraction).
// h carried fp32 in hL; only GEMV input rounds to bf16.
// ---------------------------------------------------------------------------
template<int MODE>
__global__ __launch_bounds__(256) void k_gru_scan(
    const void* __restrict__ xp_, const int* __restrict__ idx,
    const float* __restrict__ Whh, const float* __restrict__ bhh,
    void* __restrict__ hs_, int T)
{
    __shared__ s16  wfrag[10240];      // [kc8][col160][e8] bf16
    __shared__ s16  hbuf[1024];        // [kc8][row16][e8]
    __shared__ float ghL[8 * 160];
    __shared__ float hL[8 * 52];
    __shared__ float bhL[152];
    __shared__ float xbuf[2][8 * 152];
    const int t = threadIdx.x;
    const int w = t >> 6, l = t & 63, lg = l >> 4, lr = l & 15;
    constexpr int HST = (MODE == 2) ? 56 : 50;

    // stage WhhT -> frag layout: slot(kc,col,e) = Whh[col][kc*8+e]
    for (int li = t; li < 1280; li += 256) {
        int col = li % 160, kc = li / 160;
        short8v v = {0,0,0,0,0,0,0,0};
#pragma unroll
        for (int e = 0; e < 8; ++e) {
            int k = kc * 8 + e;
            if (col < 150 && k < 50) v[e] = (s16)f2b(Whh[col * 50 + k]);
        }
        *(short8v*)&wfrag[li * 8] = v;
    }
    for (int li = t; li < 1024; li += 256) hbuf[li] = 0;
    for (int e = t; e < 416; e += 256) hL[e] = 0.f;
    if (t < 152) bhL[t] = (t < 150) ? bhh[t] : 0.f;

    const long seqbase = (long)blockIdx.x * 8;
    const float* xpf = (const float*)xp_;
    const u16*   xph = (const u16*)xp_;
    float* hsf = (float*)hs_;
    u16*   hsh = (u16*)hs_;

    const int rA = (MODE == 2) ? t / 19 : t / 38;
    const int oA = (MODE == 2) ? (t % 19) * 8 : (t % 38) * 4;
    const int rB = (t + 256) / 38, oB = ((t + 256) % 38) * 4;
    const bool actA = (MODE == 2) ? (t < 152) : true;
    const bool hasB = (MODE == 2) ? false : (t < 48);

    auto rowbase = [&](int rr, int stp) -> size_t {
        long r = seqbase + rr;
        long src = (MODE == 0) ? (r * T + stp) : (long)idx[r * T + stp];
        return (size_t)src * 152;
    };

    // initial x rows
    if (MODE == 2) {
        if (actA) {
            u16x8 v = *(const u16x8*)(xph + rowbase(rA, 0) + oA);
            float4 lo = { b2f(v[0]), b2f(v[1]), b2f(v[2]), b2f(v[3]) };
            float4 hi = { b2f(v[4]), b2f(v[5]), b2f(v[6]), b2f(v[7]) };
            *(float4*)&xbuf[0][rA * 152 + oA] = lo;
            *(float4*)&xbuf[0][rA * 152 + oA + 4] = hi;
        }
    } else {
        *(float4*)&xbuf[0][rA * 152 + oA] = *(const float4*)(xpf + rowbase(rA, 0) + oA);
        if (hasB)
            *(float4*)&xbuf[0][rB * 152 + oB] = *(const float4*)(xpf + rowbase(rB, 0) + oB);
    }
    __syncthreads();

    const int tt0 = w * 3;
    const int te0 = (tt0     > 9) ? 9 : tt0;       // wave 3 duplicates tile 9
    const int te1 = (tt0 + 1 > 9) ? 9 : tt0 + 1;   // (same values, benign)
    const int te2 = (tt0 + 2 > 9) ? 9 : tt0 + 2;

    for (int st = 0; st < T; ++st) {
        const int cur = st & 1;
        u16x8 pfh;
        float4 pf0, pf1;
        if (st + 1 < T) {
            if (MODE == 2) {
                if (actA) pfh = *(const u16x8*)(xph + rowbase(rA, st + 1) + oA);
            } else {
                pf0 = *(const float4*)(xpf + rowbase(rA, st + 1) + oA);
                if (hasB) pf1 = *(const float4*)(xpf + rowbase(rB, st + 1) + oB);
            }
        }
        // GEMV via mfma: A from hbuf, B from wfrag
        short8v a0 = *(short8v*)&hbuf[((0 + lg) * 16 + lr) * 8];
        short8v a1 = *(short8v*)&hbuf[((4 + lg) * 16 + lr) * 8];
        f32x4 c0 = {0,0,0,0}, c1 = {0,0,0,0}, c2 = {0,0,0,0};
        {
            short8v b0 = *(short8v*)&wfrag[((0 + lg) * 160 + te0 * 16 + lr) * 8];
            short8v b1 = *(short8v*)&wfrag[((4 + lg) * 160 + te0 * 16 + lr) * 8];
            c0 = __builtin_amdgcn_mfma_f32_16x16x32_bf16(a0, b0, c0, 0, 0, 0);
            c0 = __builtin_amdgcn_mfma_f32_16x16x32_bf16(a1, b1, c0, 0, 0, 0);
        }
        {
            short8v b0 = *(short8v*)&wfrag[((0 + lg) * 160 + te1 * 16 + lr) * 8];
            short8v b1 = *(short8v*)&wfrag[((4 + lg) * 160 + te1 * 16 + lr) * 8];
            c1 = __builtin_amdgcn_mfma_f32_16x16x32_bf16(a0, b0, c1, 0, 0, 0);
            c1 = __builtin_amdgcn_mfma_f32_16x16x32_bf16(a1, b1, c1, 0, 0, 0);
        }
        {
            short8v b0 = *(short8v*)&wfrag[((0 + lg) * 160 + te2 * 16 + lr) * 8];
            short8v b1 = *(short8v*)&wfrag[((4 + lg) * 160 + te2 * 16 + lr) * 8];
            c2 = __builtin_amdgcn_mfma_f32_16x16x32_bf16(a0, b0, c2, 0, 0, 0);
            c2 = __builtin_amdgcn_mfma_f32_16x16x32_bf16(a1, b1, c2, 0, 0, 0);
        }
        if (lg < 2) {            // D: row = lg*4+r (= seq), col = tile*16+lr
            int col0 = te0 * 16 + lr, col1 = te1 * 16 + lr, col2 = te2 * 16 + lr;
            if (col0 < 150) {
#pragma unroll
                for (int r = 0; r < 4; ++r) ghL[(lg * 4 + r) * 160 + col0] = c0[r] + bhL[col0];
            }
            if (col1 < 150) {
#pragma unroll
                for (int r = 0; r < 4; ++r) ghL[(lg * 4 + r) * 160 + col1] = c1[r] + bhL[col1];
            }
            if (col2 < 150) {
#pragma unroll
                for (int r = 0; r < 4; ++r) ghL[(lg * 4 + r) * 160 + col2] = c2[r] + bhL[col2];
            }
        }
        __syncthreads();
        // stash prefetched x rows
        if (st + 1 < T) {
            if (MODE == 2) {
                if (actA) {
                    float4 lo = { b2f(pfh[0]), b2f(pfh[1]), b2f(pfh[2]), b2f(pfh[3]) };
                    float4 hi = { b2f(pfh[4]), b2f(pfh[5]), b2f(pfh[6]), b2f(pfh[7]) };
                    *(float4*)&xbuf[cur ^ 1][rA * 152 + oA] = lo;
                    *(float4*)&xbuf[cur ^ 1][rA * 152 + oA + 4] = hi;
                }
            } else {
                *(float4*)&xbuf[cur ^ 1][rA * 152 + oA] = pf0;
                if (hasB) *(float4*)&xbuf[cur ^ 1][rB * 152 + oB] = pf1;
            }
        }
        // activation + state update
        for (int item = t; item < 400; item += 256) {
            int ss = item / 50, hh = item % 50;
            const float* xr = &xbuf[cur][ss * 152];
            float vr  = xr[hh]       + ghL[ss * 160 + hh];
            float vz  = xr[50 + hh]  + ghL[ss * 160 + 50 + hh];
            float ghn = ghL[ss * 160 + 100 + hh];
            float rg = 1.f / (1.f + __expf(-vr));
            float zg = 1.f / (1.f + __expf(-vz));
            float a = xr[100 + hh] + rg * ghn;
            a = fminf(fmaxf(a, -15.f), 15.f);
            float e2 = __expf(-2.f * a);
            float nn2 = (1.f - e2) / (1.f + e2);
            float hn = (1.f - zg) * nn2 + zg * hL[ss * 52 + hh];
            hL[ss * 52 + hh] = hn;
            hbuf[((hh >> 3) * 16 + ss) * 8 + (hh & 7)] = (s16)f2b(hn);
            size_t ofs = ((size_t)(seqbase + ss) * T + st) * HST + hh;
            if (MODE == 2) hsh[ofs] = f2b(hn); else hsf[ofs] = hn;
        }
        __syncthreads();
    }
}

// ---------------------------------------------------------------------------
// ctx_hA[r][k] = sum_j ctx_h[r][j] * A[j][k]
// ---------------------------------------------------------------------------
__global__ __launch_bounds__(256) void k_matA(
    const float* __restrict__ inp, const float* __restrict__ A,
    float* __restrict__ outp)
{
    __shared__ float AL[50 * 52];
    __shared__ float inL[32 * 52];
    const int t = threadIdx.x;
    for (int e = t; e < 2500; e += 256) AL[(e / 50) * 52 + (e % 50)] = A[e];
    const long rbase = (long)blockIdx.x * 32;
    for (int e = t; e < 1600; e += 256) {
        int r = e / 50, j = e % 50;
        inL[r * 52 + j] = inp[(rbase + r) * 50 + j];
    }
    __syncthreads();
    for (int item = t; item < 1600; item += 256) {
        int r = item / 50, kk = item % 50;
        float acc = 0.f;
#pragma unroll 10
        for (int j = 0; j < 50; ++j)
            acc += inL[r * 52 + j] * AL[j * 52 + kk];
        outp[(rbase + r) * 50 + kk] = acc;
    }
}

// ---------------------------------------------------------------------------
// Fused match (MFMA) + conv3x3 + maxpool3x3/3.
// r<7: M1 channels 2r,2r+1 (bf16 emb, K=200 pad 224, 7 ksteps)
// r>=7: M2 channels (ctxA bf16 x candh bf16, K=50 pad 64, 2 ksteps)
// ---------------------------------------------------------------------------
__global__ __launch_bounds__(256) void k_matchconv(
    const u16* __restrict__ embh, const int* __restrict__ ctx_idx,
    const int* __restrict__ cand_idx, const float* __restrict__ ctxA,
    const u16* __restrict__ candh_h, const float* __restrict__ conv_w,
    float* __restrict__ feats, int b0)
{
    __shared__ float Msh[2][1056];
    __shared__ float wL[144];
    __shared__ s16 pool16[21504];     // M1: ctxL[28*32][8] + canL[28*64][8]
    __shared__ int ci[32], qi[2][32];
    const int t = threadIdx.x;
    const int nl = blockIdx.x;
    const int bl = nl / 14, r = nl % 14;
    const int b = b0 + bl;
    const int w = t >> 6, l = t & 63, lg = l >> 4, lr = l & 15;

    if (t < 144) wL[t] = conv_w[t];

    if (r < 7) {
        const int c0 = 2 * r;
        if (t < 32) ci[t] = ctx_idx[b * 32 + t];
        else if (t < 96)
            qi[(t - 32) >> 5][t & 31] =
                cand_idx[((long)b * 14 + c0 + ((t - 32) >> 5)) * 32 + (t & 31)];
        __syncthreads();
        s16* ctxL = pool16;           // [kc28][row32][e8]
        s16* canL = pool16 + 7168;    // [kc28][col64][e8]
        for (int it = t; it < 896; it += 256) {
            int kc = it >> 5, row = it & 31;
            short8v v = {0,0,0,0,0,0,0,0};
            if (kc < 25) v = *(const short8v*)(embh + (size_t)ci[row] * 200 + kc * 8);
            *(short8v*)&ctxL[it * 8] = v;
        }
        for (int it = t; it < 1792; it += 256) {
            int kc = it >> 6, col = it & 63;
            short8v v = {0,0,0,0,0,0,0,0};
            if (kc < 25) v = *(const short8v*)(embh + (size_t)qi[col >> 5][col & 31] * 200 + kc * 8);
            *(short8v*)&canL[it * 8] = v;
        }
        __syncthreads();
#pragma unroll
        for (int jj = 0; jj < 2; ++jj) {
            int job = w * 2 + jj;
            int ch = job >> 2, rt = (job >> 1) & 1, ct = job & 1;
            f32x4 c = {0,0,0,0};
            for (int s = 0; s < 7; ++s) {
                short8v a  = *(short8v*)&ctxL[((s * 4 + lg) * 32 + rt * 16 + lr) * 8];
                short8v bv = *(short8v*)&canL[((s * 4 + lg) * 64 + ch * 32 + ct * 16 + lr) * 8];
                c = __builtin_amdgcn_mfma_f32_16x16x32_bf16(a, bv, c, 0, 0, 0);
            }
#pragma unroll
            for (int rr = 0; rr < 4; ++rr)
                Msh[ch][(rt * 16 + lg * 4 + rr) * 33 + ct * 16 + lr] = c[rr];
        }
    } else {
        const int c0 = 2 * (r - 7);
        s16* aL = pool16;             // [kc8][row32][e8]
        s16* cL = pool16 + 2048;      // [kc8][col64][e8]
        for (int it = t; it < 256; it += 256) {
            int kc = it >> 5, row = it & 31;
            const float* src = ctxA + ((long)b * 32 + row) * 50;
            short8v v = {0,0,0,0,0,0,0,0};
#pragma unroll
            for (int e = 0; e < 8; ++e) {
                int k = kc * 8 + e;
                if (k < 50) v[e] = (s16)f2b(src[k]);
            }
            *(short8v*)&aL[it * 8] = v;
        }
        for (int it = t; it < 512; it += 256) {
            int kc = it >> 6, col = it & 63;
            long row = ((long)bl * 14 + c0 + (col >> 5)) * 32 + (col & 31);
            short8v v = {0,0,0,0,0,0,0,0};
            if (kc < 7) {
                v = *(const short8v*)(candh_h + (size_t)row * 56 + kc * 8);
                if (kc == 6) { v[2] = 0; v[3] = 0; v[4] = 0; v[5] = 0; v[6] = 0; v[7] = 0; }
            }
            *(short8v*)&cL[it * 8] = v;
        }
        __syncthreads();
#pragma unroll
        for (int jj = 0; jj < 2; ++jj) {
            int job = w * 2 + jj;
            int ch = job >> 2, rt = (job >> 1) & 1, ct = job & 1;
            f32x4 c = {0,0,0,0};
            for (int s = 0; s < 2; ++s) {
                short8v a  = *(short8v*)&aL[((s * 4 + lg) * 32 + rt * 16 + lr) * 8];
                short8v bv = *(short8v*)&cL[((s * 4 + lg) * 64 + ch * 32 + ct * 16 + lr) * 8];
                c = __builtin_amdgcn_mfma_f32_16x16x32_bf16(a, bv, c, 0, 0, 0);
            }
#pragma unroll
            for (int rr = 0; rr < 4; ++rr)
                Msh[ch][(rt * 16 + lg * 4 + rr) * 33 + ct * 16 + lr] = c[rr];
        }
    }
    __syncthreads();

    for (int item = t; item < 800; item += 256) {
        int oc = item / 100, rem = item % 100, py = rem / 10, px = rem % 10;
        float pv[2][5][5];
#pragma unroll
        for (int ch = 0; ch < 2; ++ch)
#pragma unroll
            for (int dy = 0; dy < 5; ++dy)
#pragma unroll
                for (int dx = 0; dx < 5; ++dx)
                    pv[ch][dy][dx] = Msh[ch][(3 * py + dy) * 33 + (3 * px + dx)];
        float m = -1e30f;
#pragma unroll
        for (int dy0 = 0; dy0 < 3; ++dy0)
#pragma unroll
            for (int dx0 = 0; dx0 < 3; ++dx0) {
                float sacc = 0.f;
#pragma unroll
                for (int ch = 0; ch < 2; ++ch)
#pragma unroll
                    for (int ky = 0; ky < 3; ++ky)
#pragma unroll
                        for (int kx = 0; kx < 3; ++kx)
                            sacc += pv[ch][dy0 + ky][dx0 + kx] * wL[(oc * 2 + ch) * 9 + ky * 3 + kx];
                m = fmaxf(m, sacc);
            }
        feats[(long)nl * 800 + item] = m;
    }
}

// ---------------------------------------------------------------------------
__global__ __launch_bounds__(128) void k_fc1(
    const float* __restrict__ Hs, const float* __restrict__ w,
    const float* __restrict__ bias, float* __restrict__ hid)
{
    __shared__ float hr[700];
    const int t = threadIdx.x;
    const long b = blockIdx.x;
    for (int e = t; e < 700; e += 128) hr[e] = Hs[b * 700 + e];
    __syncthreads();
    if (t < 100) {
        float acc = bias[t];
        const float4* wp = (const float4*)(w + (size_t)t * 700);
        for (int k4 = 0; k4 < 175; ++k4) {
            float4 wv = wp[k4];
            float4 hv = *(float4*)&hr[k4 * 4];
            acc += wv.x * hv.x + wv.y * hv.y + wv.z * hv.z + wv.w * hv.w;
        }
        hid[b * 100 + t] = fmaxf(acc, 0.f);
    }
}

__global__ __launch_bounds__(64) void k_final(
    const float* __restrict__ hid, const float* __restrict__ w2,
    const float* __restrict__ b2, const float* __restrict__ y,
    float* __restrict__ partial)
{
    __shared__ float hL[100];
    const int t = threadIdx.x;
    const long b = blockIdx.x;
    for (int e = t; e < 100; e += 64) hL[e] = hid[b * 100 + e];
    __syncthreads();
    float logit = -1e30f;
    if (t < 14) {
        logit = b2[t];
        for (int k = 0; k < 100; ++k) logit += hL[k] * w2[t * 100 + k];
    }
    float m = logit;
    for (int off = 8; off; off >>= 1) m = fmaxf(m, __shfl_xor(m, off, 16));
    float ex = (t < 14) ? __expf(logit - m) : 0.f;
    float se = ex;
    for (int off = 8; off; off >>= 1) se += __shfl_xor(se, off, 16);
    float kl = 0.f;
    if (t < 14) {
        float lp = logit - m - __logf(se);
        float yv = y[b * 14 + t];
        kl = (yv > 0.f) ? yv * (__logf(yv) - lp) : 0.f;
    }
    for (int off = 8; off; off >>= 1) kl += __shfl_xor(kl, off, 16);
    if (t == 0) partial[b] = kl;
}

__global__ __launch_bounds__(256) void k_reduce(
    const float* __restrict__ partial, float* __restrict__ out)
{
    __shared__ float sm[256];
    const int t = threadIdx.x;
    sm[t] = partial[t] + partial[t + 256] + partial[t + 512] + partial[t + 768];
    __syncthreads();
    for (int off = 128; off; off >>= 1) {
        if (t < off) sm[t] += sm[t + off];
        __syncthreads();
    }
    if (t == 0) out[0] = sm[0] * (1.f / 14336.f);
}

// ---------------------------------------------------------------------------
extern "C" void kernel_launch(void* const* d_in, const int* in_sizes, int n_in,
                              void* d_out, int out_size, void* d_ws, size_t ws_size,
                              hipStream_t stream)
{
    const int*   ctx_idx  = (const int*)d_in[0];
    const int*   cand_idx = (const int*)d_in[1];
    const float* y_dev    = (const float*)d_in[2];
    const float* emb      = (const float*)d_in[3];
    const float* A        = (const float*)d_in[4];
    const float* Wih_c    = (const float*)d_in[5];
    const float* Whh_c    = (const float*)d_in[6];
    const float* bih_c    = (const float*)d_in[7];
    const float* bhh_c    = (const float*)d_in[8];
    const float* Wih_r    = (const float*)d_in[9];
    const float* Whh_r    = (const float*)d_in[10];
    const float* bih_r    = (const float*)d_in[11];
    const float* bhh_r    = (const float*)d_in[12];
    const float* conv_w   = (const float*)d_in[13];
    const float* Wih2     = (const float*)d_in[14];
    const float* Whh2     = (const float*)d_in[15];
    const float* bih2     = (const float*)d_in[16];
    const float* bhh2     = (const float*)d_in[17];
    const float* fc1_w    = (const float*)d_in[18];
    const float* fc1_b    = (const float*)d_in[19];
    const float* fc2_w    = (const float*)d_in[20];
    const float* fc2_b    = (const float*)d_in[21];

    float* ws = (float*)d_ws;
    // Arena (float slots), total ~37.5M f = 150.1 MB
    u16*   embh    = (u16*)ws;               // [21128][200] bf16 = 2,112,800 f
    float* proj_c  = ws + 2112800;           // [21184][152] f32  = 3,219,968 f
    u16*   proj_rh = (u16*)(ws + 5332768);   // [21184][152] bf16 = 1,609,984 f
    float* ctx_h   = ws + 6942752;           // 1,638,400
    float* ctxA    = ws + 8581152;           // 1,638,400
    u16*   candh_h = (u16*)(ws + 10219552);  // [458752][56] bf16 = 12,845,056 f
    float* feats   = ws + 23064608;          // 11,468,800
    float* xp2     = ws + 34533408;          // [14336][152] = 2,179,072
    float* hs2     = ws + 36712480;          // 716,800
    float* hid     = ws + 37429280;          // 102,400
    float* part    = ws + 37531680;          // 1,024

    // 0. bf16 emb table
    k_cvt      <<<4127, 256, 0, stream>>>(emb, embh, 1056400);
    // 1. vocab projections (bih folded)
    k_proj     <<<331, 256, 0, stream>>>(Wih_c, bih_c, emb, proj_c, 200, 21128);
    k_proj_b16 <<<331, 256, 0, stream>>>(Wih_r, bih_r, emb, proj_rh, 200, 21128);
    // 2. GRU scans (MFMA GEMV, gather from proj tables)
    k_gru_scan<1><<<128,  256, 0, stream>>>(proj_c, ctx_idx,  Whh_c, bhh_c, ctx_h, 32);
    k_gru_scan<2><<<1792, 256, 0, stream>>>(proj_rh, cand_idx, Whh_r, bhh_r, candh_h, 32);
    k_matA     <<<1024, 256, 0, stream>>>(ctx_h, A, ctxA);
    // 3. match (MFMA) + conv + pool
    k_matchconv<<<14336, 256, 0, stream>>>(embh, ctx_idx, cand_idx, ctxA, candh_h,
                                           conv_w, feats, 0);
    // 4. accumulation GRU + head
    k_gemm150  <<<224, 256, 0, stream>>>(Wih2, bih2, feats, xp2, 800);
    k_gru_scan<0><<<128, 256, 0, stream>>>(xp2, nullptr, Whh2, bhh2, hs2, 14);
    k_fc1      <<<1024, 128, 0, stream>>>(hs2, fc1_w, fc1_b, hid);
    k_final    <<<1024, 64, 0, stream>>>(hid, fc2_w, fc2_b, y_dev, part);
    k_reduce   <<<1, 256, 0, stream>>>(part, (float*)d_out);
}

// Round 7
// 665.800 us; speedup vs baseline: 2.0640x; 1.2975x over previous
//
#include <hip/hip_runtime.h>
#include <math.h>

typedef unsigned short u16;
typedef short s16;
typedef u16 u16x8 __attribute__((ext_vector_type(8)));
typedef s16 short8v __attribute__((ext_vector_type(8)));
typedef float f32x4 __attribute__((ext_vector_type(4)));

__device__ __forceinline__ float b2f(u16 u) {
    return __uint_as_float(((unsigned)u) << 16);
}
__device__ __forceinline__ u16 f2b(float f) {        // RNE
    unsigned u = __float_as_uint(f);
    unsigned r = (u + 0x7FFFu + ((u >> 16) & 1u)) >> 16;
    return (u16)r;
}

// ---------------------------------------------------------------------------
// fp32 -> bf16 table conversion
// ---------------------------------------------------------------------------
__global__ __launch_bounds__(256) void k_cvt(
    const float* __restrict__ in, u16* __restrict__ out, int n4)
{
    int i = blockIdx.x * 256 + threadIdx.x;
    if (i < n4) {
        float4 v = ((const float4*)in)[i];
        *(ushort4*)(out + (size_t)i * 4) =
            make_ushort4(f2b(v.x), f2b(v.y), f2b(v.z), f2b(v.w));
    }
}

// ---------------------------------------------------------------------------
// Vocab projection fp32: out[v][j] = dot(emb[v], W[j]) + bias[j], stride 152.
// ---------------------------------------------------------------------------
__global__ __launch_bounds__(256) void k_proj(
    const float* __restrict__ W, const float* __restrict__ bias,
    const float* __restrict__ emb, float* __restrict__ out, int K, int V)
{
    __shared__ float smem[9728];
    __shared__ const float* rptr[64];
    float* eT = smem;
    float* wT = smem + 64 * 44;
    const int t = threadIdx.x;
    const long blockR = (long)blockIdx.x * 64;

    if (t < 64) {
        long gr = blockR + t;
        if (gr >= V) gr = V - 1;
        rptr[t] = emb + (size_t)gr * (size_t)K;
    }
    const int r0 = t & 31, r1 = r0 + 32, jg = t >> 5;

    float acc0[19], acc1[19];
#pragma unroll
    for (int i = 0; i < 19; ++i) {
        int j = jg + 8 * i;
        float b = (j < 150) ? bias[j] : 0.f;
        acc0[i] = b; acc1[i] = b;
    }
    const int nch = K / 40;
    for (int c = 0; c < nch; ++c) {
        const int k0 = c * 40;
        __syncthreads();
        for (int fid = t; fid < 640; fid += 256) {
            int r = fid / 10, ko = (fid % 10) * 4;
            *(float4*)&eT[r * 44 + ko] = *(const float4*)(rptr[r] + k0 + ko);
        }
        for (int fid = t; fid < 1500; fid += 256) {
            int r = fid / 10, ko = (fid % 10) * 4;
            *(float4*)&wT[r * 44 + ko] = *(const float4*)(W + (size_t)r * K + k0 + ko);
        }
        __syncthreads();
#pragma unroll
        for (int kk = 0; kk < 40; kk += 4) {
            float4 a0 = *(float4*)&eT[r0 * 44 + kk];
            float4 a1 = *(float4*)&eT[r1 * 44 + kk];
#pragma unroll
            for (int i = 0; i < 19; ++i) {
                int j = jg + 8 * i;
                float4 w = *(float4*)&wT[j * 44 + kk];
                acc0[i] += a0.x * w.x + a0.y * w.y + a0.z * w.z + a0.w * w.w;
                acc1[i] += a1.x * w.x + a1.y * w.y + a1.z * w.z + a1.w * w.w;
            }
        }
    }
    __syncthreads();
#pragma unroll
    for (int i = 0; i < 19; ++i) {
        int j = jg + 8 * i;
        if (j < 150) { smem[r0 * 152 + j] = acc0[i]; smem[r1 * 152 + j] = acc1[i]; }
    }
    __syncthreads();
    float4* og = (float4*)(out + blockR * 152);
    for (int fid = t; fid < 2432; fid += 256)
        og[fid] = *(float4*)&smem[fid * 4];
}

// ---------------------------------------------------------------------------
// Vocab projection, bf16-packed output (stride 152 shorts).
// ---------------------------------------------------------------------------
__global__ __launch_bounds__(256) void k_proj_b16(
    const float* __restrict__ W, const float* __restrict__ bias,
    const float* __restrict__ emb, u16* __restrict__ out, int K, int V)
{
    __shared__ float smem[9728];
    __shared__ const float* rptr[64];
    float* eT = smem;
    float* wT = smem + 64 * 44;
    const int t = threadIdx.x;
    const long blockR = (long)blockIdx.x * 64;

    if (t < 64) {
        long gr = blockR + t;
        if (gr >= V) gr = V - 1;
        rptr[t] = emb + (size_t)gr * (size_t)K;
    }
    const int r0 = t & 31, r1 = r0 + 32, jg = t >> 5;

    float acc0[19], acc1[19];
#pragma unroll
    for (int i = 0; i < 19; ++i) {
        int j = jg + 8 * i;
        float b = (j < 150) ? bias[j] : 0.f;
        acc0[i] = b; acc1[i] = b;
    }
    const int nch = K / 40;
    for (int c = 0; c < nch; ++c) {
        const int k0 = c * 40;
        __syncthreads();
        for (int fid = t; fid < 640; fid += 256) {
            int r = fid / 10, ko = (fid % 10) * 4;
            *(float4*)&eT[r * 44 + ko] = *(const float4*)(rptr[r] + k0 + ko);
        }
        for (int fid = t; fid < 1500; fid += 256) {
            int r = fid / 10, ko = (fid % 10) * 4;
            *(float4*)&wT[r * 44 + ko] = *(const float4*)(W + (size_t)r * K + k0 + ko);
        }
        __syncthreads();
#pragma unroll
        for (int kk = 0; kk < 40; kk += 4) {
            float4 a0 = *(float4*)&eT[r0 * 44 + kk];
            float4 a1 = *(float4*)&eT[r1 * 44 + kk];
#pragma unroll
            for (int i = 0; i < 19; ++i) {
                int j = jg + 8 * i;
                float4 w = *(float4*)&wT[j * 44 + kk];
                acc0[i] += a0.x * w.x + a0.y * w.y + a0.z * w.z + a0.w * w.w;
                acc1[i] += a1.x * w.x + a1.y * w.y + a1.z * w.z + a1.w * w.w;
            }
        }
    }
    __syncthreads();
#pragma unroll
    for (int i = 0; i < 19; ++i) {
        int j = jg + 8 * i;
        if (j < 150) { smem[r0 * 152 + j] = acc0[i]; smem[r1 * 152 + j] = acc1[i]; }
    }
    __syncthreads();
    u16* og = out + blockR * 152;
    for (int fid = t; fid < 1216; fid += 256) {
        float4 a = *(float4*)&smem[fid * 8];
        float4 b = *(float4*)&smem[fid * 8 + 4];
        u16x8 v = { f2b(a.x), f2b(a.y), f2b(a.z), f2b(a.w),
                    f2b(b.x), f2b(b.y), f2b(b.z), f2b(b.w) };
        *(u16x8*)(og + fid * 8) = v;
    }
}

// ---------------------------------------------------------------------------
// GRU scan with MFMA GEMV. MODE 0: direct fp32 xp (stride 152), fp32 hs (50).
// MODE 1: gather fp32 xp via idx, fp32 hs (50). MODE 2: gather bf16 xp,
// bf16 hs (stride 56).
// ---------------------------------------------------------------------------
template<int MODE>
__global__ __launch_bounds__(256) void k_gru_scan(
    const void* __restrict__ xp_, const int* __restrict__ idx,
    const float* __restrict__ Whh, const float* __restrict__ bhh,
    void* __restrict__ hs_, int T)
{
    __shared__ s16  wfrag[10240];      // [kc8][col160][e8] bf16
    __shared__ s16  hbuf[1024];        // [kc8][row16][e8]
    __shared__ float ghL[8 * 160];
    __shared__ float hL[8 * 52];
    __shared__ float bhL[152];
    __shared__ float xbuf[2][8 * 152];
    const int t = threadIdx.x;
    const int w = t >> 6, l = t & 63, lg = l >> 4, lr = l & 15;
    constexpr int HST = (MODE == 2) ? 56 : 50;

    for (int li = t; li < 1280; li += 256) {
        int col = li % 160, kc = li / 160;
        short8v v = {0,0,0,0,0,0,0,0};
#pragma unroll
        for (int e = 0; e < 8; ++e) {
            int k = kc * 8 + e;
            if (col < 150 && k < 50) v[e] = (s16)f2b(Whh[col * 50 + k]);
        }
        *(short8v*)&wfrag[li * 8] = v;
    }
    for (int li = t; li < 1024; li += 256) hbuf[li] = 0;
    for (int e = t; e < 416; e += 256) hL[e] = 0.f;
    if (t < 152) bhL[t] = (t < 150) ? bhh[t] : 0.f;

    const long seqbase = (long)blockIdx.x * 8;
    const float* xpf = (const float*)xp_;
    const u16*   xph = (const u16*)xp_;
    float* hsf = (float*)hs_;
    u16*   hsh = (u16*)hs_;

    const int rA = (MODE == 2) ? t / 19 : t / 38;
    const int oA = (MODE == 2) ? (t % 19) * 8 : (t % 38) * 4;
    const int rB = (t + 256) / 38, oB = ((t + 256) % 38) * 4;
    const bool actA = (MODE == 2) ? (t < 152) : true;
    const bool hasB = (MODE == 2) ? false : (t < 48);

    auto rowbase = [&](int rr, int stp) -> size_t {
        long r = seqbase + rr;
        long src = (MODE == 0) ? (r * T + stp) : (long)idx[r * T + stp];
        return (size_t)src * 152;
    };

    if (MODE == 2) {
        if (actA) {
            u16x8 v = *(const u16x8*)(xph + rowbase(rA, 0) + oA);
            float4 lo = { b2f(v[0]), b2f(v[1]), b2f(v[2]), b2f(v[3]) };
            float4 hi = { b2f(v[4]), b2f(v[5]), b2f(v[6]), b2f(v[7]) };
            *(float4*)&xbuf[0][rA * 152 + oA] = lo;
            *(float4*)&xbuf[0][rA * 152 + oA + 4] = hi;
        }
    } else {
        *(float4*)&xbuf[0][rA * 152 + oA] = *(const float4*)(xpf + rowbase(rA, 0) + oA);
        if (hasB)
            *(float4*)&xbuf[0][rB * 152 + oB] = *(const float4*)(xpf + rowbase(rB, 0) + oB);
    }
    __syncthreads();

    const int tt0 = w * 3;
    const int te0 = (tt0     > 9) ? 9 : tt0;
    const int te1 = (tt0 + 1 > 9) ? 9 : tt0 + 1;
    const int te2 = (tt0 + 2 > 9) ? 9 : tt0 + 2;

    for (int st = 0; st < T; ++st) {
        const int cur = st & 1;
        u16x8 pfh;
        float4 pf0, pf1;
        if (st + 1 < T) {
            if (MODE == 2) {
                if (actA) pfh = *(const u16x8*)(xph + rowbase(rA, st + 1) + oA);
            } else {
                pf0 = *(const float4*)(xpf + rowbase(rA, st + 1) + oA);
                if (hasB) pf1 = *(const float4*)(xpf + rowbase(rB, st + 1) + oB);
            }
        }
        short8v a0 = *(short8v*)&hbuf[((0 + lg) * 16 + lr) * 8];
        short8v a1 = *(short8v*)&hbuf[((4 + lg) * 16 + lr) * 8];
        f32x4 c0 = {0,0,0,0}, c1 = {0,0,0,0}, c2 = {0,0,0,0};
        {
            short8v b0 = *(short8v*)&wfrag[((0 + lg) * 160 + te0 * 16 + lr) * 8];
            short8v b1 = *(short8v*)&wfrag[((4 + lg) * 160 + te0 * 16 + lr) * 8];
            c0 = __builtin_amdgcn_mfma_f32_16x16x32_bf16(a0, b0, c0, 0, 0, 0);
            c0 = __builtin_amdgcn_mfma_f32_16x16x32_bf16(a1, b1, c0, 0, 0, 0);
        }
        {
            short8v b0 = *(short8v*)&wfrag[((0 + lg) * 160 + te1 * 16 + lr) * 8];
            short8v b1 = *(short8v*)&wfrag[((4 + lg) * 160 + te1 * 16 + lr) * 8];
            c1 = __builtin_amdgcn_mfma_f32_16x16x32_bf16(a0, b0, c1, 0, 0, 0);
            c1 = __builtin_amdgcn_mfma_f32_16x16x32_bf16(a1, b1, c1, 0, 0, 0);
        }
        {
            short8v b0 = *(short8v*)&wfrag[((0 + lg) * 160 + te2 * 16 + lr) * 8];
            short8v b1 = *(short8v*)&wfrag[((4 + lg) * 160 + te2 * 16 + lr) * 8];
            c2 = __builtin_amdgcn_mfma_f32_16x16x32_bf16(a0, b0, c2, 0, 0, 0);
            c2 = __builtin_amdgcn_mfma_f32_16x16x32_bf16(a1, b1, c2, 0, 0, 0);
        }
        if (lg < 2) {
            int col0 = te0 * 16 + lr, col1 = te1 * 16 + lr, col2 = te2 * 16 + lr;
            if (col0 < 150) {
#pragma unroll
                for (int r = 0; r < 4; ++r) ghL[(lg * 4 + r) * 160 + col0] = c0[r] + bhL[col0];
            }
            if (col1 < 150) {
#pragma unroll
                for (int r = 0; r < 4; ++r) ghL[(lg * 4 + r) * 160 + col1] = c1[r] + bhL[col1];
            }
            if (col2 < 150) {
#pragma unroll
                for (int r = 0; r < 4; ++r) ghL[(lg * 4 + r) * 160 + col2] = c2[r] + bhL[col2];
            }
        }
        __syncthreads();
        if (st + 1 < T) {
            if (MODE == 2) {
                if (actA) {
                    float4 lo = { b2f(pfh[0]), b2f(pfh[1]), b2f(pfh[2]), b2f(pfh[3]) };
                    float4 hi = { b2f(pfh[4]), b2f(pfh[5]), b2f(pfh[6]), b2f(pfh[7]) };
                    *(float4*)&xbuf[cur ^ 1][rA * 152 + oA] = lo;
                    *(float4*)&xbuf[cur ^ 1][rA * 152 + oA + 4] = hi;
                }
            } else {
                *(float4*)&xbuf[cur ^ 1][rA * 152 + oA] = pf0;
                if (hasB) *(float4*)&xbuf[cur ^ 1][rB * 152 + oB] = pf1;
            }
        }
        for (int item = t; item < 400; item += 256) {
            int ss = item / 50, hh = item % 50;
            const float* xr = &xbuf[cur][ss * 152];
            float vr  = xr[hh]       + ghL[ss * 160 + hh];
            float vz  = xr[50 + hh]  + ghL[ss * 160 + 50 + hh];
            float ghn = ghL[ss * 160 + 100 + hh];
            float rg = 1.f / (1.f + __expf(-vr));
            float zg = 1.f / (1.f + __expf(-vz));
            float a = xr[100 + hh] + rg * ghn;
            a = fminf(fmaxf(a, -15.f), 15.f);
            float e2 = __expf(-2.f * a);
            float nn2 = (1.f - e2) / (1.f + e2);
            float hn = (1.f - zg) * nn2 + zg * hL[ss * 52 + hh];
            hL[ss * 52 + hh] = hn;
            hbuf[((hh >> 3) * 16 + ss) * 8 + (hh & 7)] = (s16)f2b(hn);
            size_t ofs = ((size_t)(seqbase + ss) * T + st) * HST + hh;
            if (MODE == 2) hsh[ofs] = f2b(hn); else hsf[ofs] = hn;
        }
        __syncthreads();
    }
}

// ---------------------------------------------------------------------------
// ctx_hA[r][k] = sum_j ctx_h[r][j] * A[j][k]
// ---------------------------------------------------------------------------
__global__ __launch_bounds__(256) void k_matA(
    const float* __restrict__ inp, const float* __restrict__ A,
    float* __restrict__ outp)
{
    __shared__ float AL[50 * 52];
    __shared__ float inL[32 * 52];
    const int t = threadIdx.x;
    for (int e = t; e < 2500; e += 256) AL[(e / 50) * 52 + (e % 50)] = A[e];
    const long rbase = (long)blockIdx.x * 32;
    for (int e = t; e < 1600; e += 256) {
        int r = e / 50, j = e % 50;
        inL[r * 52 + j] = inp[(rbase + r) * 50 + j];
    }
    __syncthreads();
    for (int item = t; item < 1600; item += 256) {
        int r = item / 50, kk = item % 50;
        float acc = 0.f;
#pragma unroll 10
        for (int j = 0; j < 50; ++j)
            acc += inL[r * 52 + j] * AL[j * 52 + kk];
        outp[(rbase + r) * 50 + kk] = acc;
    }
}

// ---------------------------------------------------------------------------
// Fused match (MFMA) + conv3x3 + maxpool3x3/3. feats written bf16.
// ---------------------------------------------------------------------------
__global__ __launch_bounds__(256) void k_matchconv(
    const u16* __restrict__ embh, const int* __restrict__ ctx_idx,
    const int* __restrict__ cand_idx, const float* __restrict__ ctxA,
    const u16* __restrict__ candh_h, const float* __restrict__ conv_w,
    u16* __restrict__ feats, int b0)
{
    __shared__ float Msh[2][1056];
    __shared__ float wL[144];
    __shared__ s16 pool16[21504];
    __shared__ int ci[32], qi[2][32];
    const int t = threadIdx.x;
    const int nl = blockIdx.x;
    const int bl = nl / 14, r = nl % 14;
    const int b = b0 + bl;
    const int w = t >> 6, l = t & 63, lg = l >> 4, lr = l & 15;

    if (t < 144) wL[t] = conv_w[t];

    if (r < 7) {
        const int c0 = 2 * r;
        if (t < 32) ci[t] = ctx_idx[b * 32 + t];
        else if (t < 96)
            qi[(t - 32) >> 5][t & 31] =
                cand_idx[((long)b * 14 + c0 + ((t - 32) >> 5)) * 32 + (t & 31)];
        __syncthreads();
        s16* ctxL = pool16;           // [kc28][row32][e8]
        s16* canL = pool16 + 7168;    // [kc28][col64][e8]
        for (int it = t; it < 896; it += 256) {
            int kc = it >> 5, row = it & 31;
            short8v v = {0,0,0,0,0,0,0,0};
            if (kc < 25) v = *(const short8v*)(embh + (size_t)ci[row] * 200 + kc * 8);
            *(short8v*)&ctxL[it * 8] = v;
        }
        for (int it = t; it < 1792; it += 256) {
            int kc = it >> 6, col = it & 63;
            short8v v = {0,0,0,0,0,0,0,0};
            if (kc < 25) v = *(const short8v*)(embh + (size_t)qi[col >> 5][col & 31] * 200 + kc * 8);
            *(short8v*)&canL[it * 8] = v;
        }
        __syncthreads();
#pragma unroll
        for (int jj = 0; jj < 2; ++jj) {
            int job = w * 2 + jj;
            int ch = job >> 2, rt = (job >> 1) & 1, ct = job & 1;
            f32x4 c = {0,0,0,0};
            for (int s = 0; s < 7; ++s) {
                short8v a  = *(short8v*)&ctxL[((s * 4 + lg) * 32 + rt * 16 + lr) * 8];
                short8v bv = *(short8v*)&canL[((s * 4 + lg) * 64 + ch * 32 + ct * 16 + lr) * 8];
                c = __builtin_amdgcn_mfma_f32_16x16x32_bf16(a, bv, c, 0, 0, 0);
            }
#pragma unroll
            for (int rr = 0; rr < 4; ++rr)
                Msh[ch][(rt * 16 + lg * 4 + rr) * 33 + ct * 16 + lr] = c[rr];
        }
    } else {
        const int c0 = 2 * (r - 7);
        s16* aL = pool16;             // [kc8][row32][e8]
        s16* cL = pool16 + 2048;      // [kc8][col64][e8]
        for (int it = t; it < 256; it += 256) {
            int kc = it >> 5, row = it & 31;
            const float* src = ctxA + ((long)b * 32 + row) * 50;
            short8v v = {0,0,0,0,0,0,0,0};
#pragma unroll
            for (int e = 0; e < 8; ++e) {
                int k = kc * 8 + e;
                if (k < 50) v[e] = (s16)f2b(src[k]);
            }
            *(short8v*)&aL[it * 8] = v;
        }
        for (int it = t; it < 512; it += 256) {
            int kc = it >> 6, col = it & 63;
            long row = ((long)bl * 14 + c0 + (col >> 5)) * 32 + (col & 31);
            short8v v = {0,0,0,0,0,0,0,0};
            if (kc < 7) {
                v = *(const short8v*)(candh_h + (size_t)row * 56 + kc * 8);
                if (kc == 6) { v[2] = 0; v[3] = 0; v[4] = 0; v[5] = 0; v[6] = 0; v[7] = 0; }
            }
            *(short8v*)&cL[it * 8] = v;
        }
        __syncthreads();
#pragma unroll
        for (int jj = 0; jj < 2; ++jj) {
            int job = w * 2 + jj;
            int ch = job >> 2, rt = (job >> 1) & 1, ct = job & 1;
            f32x4 c = {0,0,0,0};
            for (int s = 0; s < 2; ++s) {
                short8v a  = *(short8v*)&aL[((s * 4 + lg) * 32 + rt * 16 + lr) * 8];
                short8v bv = *(short8v*)&cL[((s * 4 + lg) * 64 + ch * 32 + ct * 16 + lr) * 8];
                c = __builtin_amdgcn_mfma_f32_16x16x32_bf16(a, bv, c, 0, 0, 0);
            }
#pragma unroll
            for (int rr = 0; rr < 4; ++rr)
                Msh[ch][(rt * 16 + lg * 4 + rr) * 33 + ct * 16 + lr] = c[rr];
        }
    }
    __syncthreads();

    for (int item = t; item < 800; item += 256) {
        int oc = item / 100, rem = item % 100, py = rem / 10, px = rem % 10;
        float pv[2][5][5];
#pragma unroll
        for (int ch = 0; ch < 2; ++ch)
#pragma unroll
            for (int dy = 0; dy < 5; ++dy)
#pragma unroll
                for (int dx = 0; dx < 5; ++dx)
                    pv[ch][dy][dx] = Msh[ch][(3 * py + dy) * 33 + (3 * px + dx)];
        float m = -1e30f;
#pragma unroll
        for (int dy0 = 0; dy0 < 3; ++dy0)
#pragma unroll
            for (int dx0 = 0; dx0 < 3; ++dx0) {
                float sacc = 0.f;
#pragma unroll
                for (int ch = 0; ch < 2; ++ch)
#pragma unroll
                    for (int ky = 0; ky < 3; ++ky)
#pragma unroll
                        for (int kx = 0; kx < 3; ++kx)
                            sacc += pv[ch][dy0 + ky][dx0 + kx] * wL[(oc * 2 + ch) * 9 + ky * 3 + kx];
                m = fmaxf(m, sacc);
            }
        feats[(long)nl * 800 + item] = f2b(m);
    }
}

// ---------------------------------------------------------------------------
// xp2 MFMA GEMM: out[r][j] (fp32, stride 152) = dot(feats[r], W2[j]) + bih2[j]
// M=14336, N=150(pad 160, split 2x80), K=800 (25 chunks of 32).
// Grid 448 = 224 row-blocks x 2 col-halves. 4 waves x 16 rows x 80 cols.
// ---------------------------------------------------------------------------
__global__ __launch_bounds__(256) void k_xp2mm(
    const u16* __restrict__ feats, const u16* __restrict__ w2h,
    const float* __restrict__ bih2, float* __restrict__ out)
{
    __shared__ s16 Ab[2048];      // [kc4][row64][e8]
    __shared__ s16 Bb[2560];      // [kc4][col80][e8]
    __shared__ float bhL[160];
    const int t = threadIdx.x;
    const int w = t >> 6, l = t & 63, lg = l >> 4, lr = l & 15;
    const int mb = blockIdx.x >> 1, nb = blockIdx.x & 1;
    const long rowbase = (long)mb * 64;
    const int colbase = nb * 80;
    if (t < 160) bhL[t] = (t < 150) ? bih2[t] : 0.f;

    f32x4 acc[5];
#pragma unroll
    for (int i = 0; i < 5; ++i) acc[i] = (f32x4){0,0,0,0};

    for (int ch = 0; ch < 25; ++ch) {
        __syncthreads();
        {   // A tile: 64 rows x 32 k  (item t = kc*64+row)
            int kc = t >> 6, row = t & 63;
            *(short8v*)&Ab[t * 8] =
                *(const short8v*)(feats + (rowbase + row) * 800 + ch * 32 + kc * 8);
        }
        for (int it = t; it < 320; it += 256) {   // B tile: 80 cols x 32 k
            int kc = it / 80, col = it % 80;
            int gcol = colbase + col;
            short8v v = {0,0,0,0,0,0,0,0};
            if (gcol < 150)
                v = *(const short8v*)(w2h + (size_t)gcol * 800 + ch * 32 + kc * 8);
            *(short8v*)&Bb[it * 8] = v;
        }
        __syncthreads();
        short8v a = *(short8v*)&Ab[(lg * 64 + w * 16 + lr) * 8];
#pragma unroll
        for (int ct = 0; ct < 5; ++ct) {
            short8v bv = *(short8v*)&Bb[(lg * 80 + ct * 16 + lr) * 8];
            acc[ct] = __builtin_amdgcn_mfma_f32_16x16x32_bf16(a, bv, acc[ct], 0, 0, 0);
        }
    }
#pragma unroll
    for (int ct = 0; ct < 5; ++ct) {
        int gcol = colbase + ct * 16 + lr;
        if (gcol < 150) {
#pragma unroll
            for (int rr = 0; rr < 4; ++rr) {
                long row = rowbase + w * 16 + lg * 4 + rr;
                out[row * 152 + gcol] = acc[ct][rr] + bhL[gcol];
            }
        }
    }
}

// ---------------------------------------------------------------------------
__global__ __launch_bounds__(128) void k_fc1(
    const float* __restrict__ Hs, const float* __restrict__ w,
    const float* __restrict__ bias, float* __restrict__ hid)
{
    __shared__ float hr[700];
    const int t = threadIdx.x;
    const long b = blockIdx.x;
    for (int e = t; e < 700; e += 128) hr[e] = Hs[b * 700 + e];
    __syncthreads();
    if (t < 100) {
        float acc = bias[t];
        const float4* wp = (const float4*)(w + (size_t)t * 700);
        for (int k4 = 0; k4 < 175; ++k4) {
            float4 wv = wp[k4];
            float4 hv = *(float4*)&hr[k4 * 4];
            acc += wv.x * hv.x + wv.y * hv.y + wv.z * hv.z + wv.w * hv.w;
        }
        hid[b * 100 + t] = fmaxf(acc, 0.f);
    }
}

__global__ __launch_bounds__(64) void k_final(
    const float* __restrict__ hid, const float* __restrict__ w2,
    const float* __restrict__ b2, const float* __restrict__ y,
    float* __restrict__ partial)
{
    __shared__ float hL[100];
    const int t = threadIdx.x;
    const long b = blockIdx.x;
    for (int e = t; e < 100; e += 64) hL[e] = hid[b * 100 + e];
    __syncthreads();
    float logit = -1e30f;
    if (t < 14) {
        logit = b2[t];
        for (int k = 0; k < 100; ++k) logit += hL[k] * w2[t * 100 + k];
    }
    float m = logit;
    for (int off = 8; off; off >>= 1) m = fmaxf(m, __shfl_xor(m, off, 16));
    float ex = (t < 14) ? __expf(logit - m) : 0.f;
    float se = ex;
    for (int off = 8; off; off >>= 1) se += __shfl_xor(se, off, 16);
    float kl = 0.f;
    if (t < 14) {
        float lp = logit - m - __logf(se);
        float yv = y[b * 14 + t];
        kl = (yv > 0.f) ? yv * (__logf(yv) - lp) : 0.f;
    }
    for (int off = 8; off; off >>= 1) kl += __shfl_xor(kl, off, 16);
    if (t == 0) partial[b] = kl;
}

__global__ __launch_bounds__(256) void k_reduce(
    const float* __restrict__ partial, float* __restrict__ out)
{
    __shared__ float sm[256];
    const int t = threadIdx.x;
    sm[t] = partial[t] + partial[t + 256] + partial[t + 512] + partial[t + 768];
    __syncthreads();
    for (int off = 128; off; off >>= 1) {
        if (t < off) sm[t] += sm[t + off];
        __syncthreads();
    }
    if (t == 0) out[0] = sm[0] * (1.f / 14336.f);
}

// ---------------------------------------------------------------------------
extern "C" void kernel_launch(void* const* d_in, const int* in_sizes, int n_in,
                              void* d_out, int out_size, void* d_ws, size_t ws_size,
                              hipStream_t stream)
{
    const int*   ctx_idx  = (const int*)d_in[0];
    const int*   cand_idx = (const int*)d_in[1];
    const float* y_dev    = (const float*)d_in[2];
    const float* emb      = (const float*)d_in[3];
    const float* A        = (const float*)d_in[4];
    const float* Wih_c    = (const float*)d_in[5];
    const float* Whh_c    = (const float*)d_in[6];
    const float* bih_c    = (const float*)d_in[7];
    const float* bhh_c    = (const float*)d_in[8];
    const float* Wih_r    = (const float*)d_in[9];
    const float* Whh_r    = (const float*)d_in[10];
    const float* bih_r    = (const float*)d_in[11];
    const float* bhh_r    = (const float*)d_in[12];
    const float* conv_w   = (const float*)d_in[13];
    const float* Wih2     = (const float*)d_in[14];
    const float* Whh2     = (const float*)d_in[15];
    const float* bih2     = (const float*)d_in[16];
    const float* bhh2     = (const float*)d_in[17];
    const float* fc1_w    = (const float*)d_in[18];
    const float* fc1_b    = (const float*)d_in[19];
    const float* fc2_w    = (const float*)d_in[20];
    const float* fc2_b    = (const float*)d_in[21];

    float* ws = (float*)d_ws;
    // Arena (float slots), total ~31.9M f = 127.4 MB
    u16*   embh    = (u16*)ws;               // [21128][200] bf16 = 2,112,800 f
    float* proj_c  = ws + 2112800;           // [21184][152] f32  = 3,219,968 f
    u16*   proj_rh = (u16*)(ws + 5332768);   // [21184][152] bf16 = 1,609,984 f
    float* ctx_h   = ws + 6942752;           // 1,638,400
    float* ctxA    = ws + 8581152;           // 1,638,400
    u16*   candh_h = (u16*)(ws + 10219552);  // [458752][56] bf16 = 12,845,056 f
    u16*   feats_h = (u16*)(ws + 23064608);  // [14336][800] bf16 = 5,734,400 f
    u16*   w2h     = (u16*)(ws + 28799008);  // [150][800] bf16 = 60,000 f
    float* xp2     = ws + 28859008;          // [14336][152] = 2,179,072
    float* hs2     = ws + 31038080;          // 716,800
    float* hid     = ws + 31754880;          // 102,400
    float* part    = ws + 31857280;          // 1,024

    // 0. bf16 tables
    k_cvt      <<<4127, 256, 0, stream>>>(emb, embh, 1056400);
    k_cvt      <<<118, 256, 0, stream>>>(Wih2, w2h, 30000);
    // 1. vocab projections (bih folded)
    k_proj     <<<331, 256, 0, stream>>>(Wih_c, bih_c, emb, proj_c, 200, 21128);
    k_proj_b16 <<<331, 256, 0, stream>>>(Wih_r, bih_r, emb, proj_rh, 200, 21128);
    // 2. GRU scans (MFMA GEMV, gather from proj tables)
    k_gru_scan<1><<<128,  256, 0, stream>>>(proj_c, ctx_idx,  Whh_c, bhh_c, ctx_h, 32);
    k_gru_scan<2><<<1792, 256, 0, stream>>>(proj_rh, cand_idx, Whh_r, bhh_r, candh_h, 32);
    k_matA     <<<1024, 256, 0, stream>>>(ctx_h, A, ctxA);
    // 3. match (MFMA) + conv + pool -> bf16 feats
    k_matchconv<<<14336, 256, 0, stream>>>(embh, ctx_idx, cand_idx, ctxA, candh_h,
                                           conv_w, feats_h, 0);
    // 4. accumulation GRU (MFMA xp2 GEMM) + head
    k_xp2mm    <<<448, 256, 0, stream>>>(feats_h, w2h, bih2, xp2);
    k_gru_scan<0><<<128, 256, 0, stream>>>(xp2, nullptr, Whh2, bhh2, hs2, 14);
    k_fc1      <<<1024, 128, 0, stream>>>(hs2, fc1_w, fc1_b, hid);
    k_final    <<<1024, 64, 0, stream>>>(hid, fc2_w, fc2_b, y_dev, part);
    k_reduce   <<<1, 256, 0, stream>>>(part, (float*)d_out);
}

// Round 8
// 601.300 us; speedup vs baseline: 2.2854x; 1.1073x over previous
//
#include <hip/hip_runtime.h>
#include <math.h>

typedef unsigned short u16;
typedef short s16;
typedef u16 u16x8 __attribute__((ext_vector_type(8)));
typedef s16 short8v __attribute__((ext_vector_type(8)));
typedef float f32x4 __attribute__((ext_vector_type(4)));

__device__ __forceinline__ float b2f(u16 u) {
    return __uint_as_float(((unsigned)u) << 16);
}
__device__ __forceinline__ u16 f2b(float f) {        // RNE
    unsigned u = __float_as_uint(f);
    unsigned r = (u + 0x7FFFu + ((u >> 16) & 1u)) >> 16;
    return (u16)r;
}

// ---------------------------------------------------------------------------
// fp32 -> bf16 table conversion
// ---------------------------------------------------------------------------
__global__ __launch_bounds__(256) void k_cvt(
    const float* __restrict__ in, u16* __restrict__ out, int n4)
{
    int i = blockIdx.x * 256 + threadIdx.x;
    if (i < n4) {
        float4 v = ((const float4*)in)[i];
        *(ushort4*)(out + (size_t)i * 4) =
            make_ushort4(f2b(v.x), f2b(v.y), f2b(v.z), f2b(v.w));
    }
}

// ---------------------------------------------------------------------------
// Vocab projection fp32: out[v][j] = dot(emb[v], W[j]) + bias[j], stride 152.
// ---------------------------------------------------------------------------
__global__ __launch_bounds__(256) void k_proj(
    const float* __restrict__ W, const float* __restrict__ bias,
    const float* __restrict__ emb, float* __restrict__ out, int K, int V)
{
    __shared__ float smem[9728];
    __shared__ const float* rptr[64];
    float* eT = smem;
    float* wT = smem + 64 * 44;
    const int t = threadIdx.x;
    const long blockR = (long)blockIdx.x * 64;

    if (t < 64) {
        long gr = blockR + t;
        if (gr >= V) gr = V - 1;
        rptr[t] = emb + (size_t)gr * (size_t)K;
    }
    const int r0 = t & 31, r1 = r0 + 32, jg = t >> 5;

    float acc0[19], acc1[19];
#pragma unroll
    for (int i = 0; i < 19; ++i) {
        int j = jg + 8 * i;
        float b = (j < 150) ? bias[j] : 0.f;
        acc0[i] = b; acc1[i] = b;
    }
    const int nch = K / 40;
    for (int c = 0; c < nch; ++c) {
        const int k0 = c * 40;
        __syncthreads();
        for (int fid = t; fid < 640; fid += 256) {
            int r = fid / 10, ko = (fid % 10) * 4;
            *(float4*)&eT[r * 44 + ko] = *(const float4*)(rptr[r] + k0 + ko);
        }
        for (int fid = t; fid < 1500; fid += 256) {
            int r = fid / 10, ko = (fid % 10) * 4;
            *(float4*)&wT[r * 44 + ko] = *(const float4*)(W + (size_t)r * K + k0 + ko);
        }
        __syncthreads();
#pragma unroll
        for (int kk = 0; kk < 40; kk += 4) {
            float4 a0 = *(float4*)&eT[r0 * 44 + kk];
            float4 a1 = *(float4*)&eT[r1 * 44 + kk];
#pragma unroll
            for (int i = 0; i < 19; ++i) {
                int j = jg + 8 * i;
                float4 w = *(float4*)&wT[j * 44 + kk];
                acc0[i] += a0.x * w.x + a0.y * w.y + a0.z * w.z + a0.w * w.w;
                acc1[i] += a1.x * w.x + a1.y * w.y + a1.z * w.z + a1.w * w.w;
            }
        }
    }
    __syncthreads();
#pragma unroll
    for (int i = 0; i < 19; ++i) {
        int j = jg + 8 * i;
        if (j < 150) { smem[r0 * 152 + j] = acc0[i]; smem[r1 * 152 + j] = acc1[i]; }
    }
    __syncthreads();
    float4* og = (float4*)(out + blockR * 152);
    for (int fid = t; fid < 2432; fid += 256)
        og[fid] = *(float4*)&smem[fid * 4];
}

// ---------------------------------------------------------------------------
// Vocab projection, bf16-packed output (stride 152 shorts).
// ---------------------------------------------------------------------------
__global__ __launch_bounds__(256) void k_proj_b16(
    const float* __restrict__ W, const float* __restrict__ bias,
    const float* __restrict__ emb, u16* __restrict__ out, int K, int V)
{
    __shared__ float smem[9728];
    __shared__ const float* rptr[64];
    float* eT = smem;
    float* wT = smem + 64 * 44;
    const int t = threadIdx.x;
    const long blockR = (long)blockIdx.x * 64;

    if (t < 64) {
        long gr = blockR + t;
        if (gr >= V) gr = V - 1;
        rptr[t] = emb + (size_t)gr * (size_t)K;
    }
    const int r0 = t & 31, r1 = r0 + 32, jg = t >> 5;

    float acc0[19], acc1[19];
#pragma unroll
    for (int i = 0; i < 19; ++i) {
        int j = jg + 8 * i;
        float b = (j < 150) ? bias[j] : 0.f;
        acc0[i] = b; acc1[i] = b;
    }
    const int nch = K / 40;
    for (int c = 0; c < nch; ++c) {
        const int k0 = c * 40;
        __syncthreads();
        for (int fid = t; fid < 640; fid += 256) {
            int r = fid / 10, ko = (fid % 10) * 4;
            *(float4*)&eT[r * 44 + ko] = *(const float4*)(rptr[r] + k0 + ko);
        }
        for (int fid = t; fid < 1500; fid += 256) {
            int r = fid / 10, ko = (fid % 10) * 4;
            *(float4*)&wT[r * 44 + ko] = *(const float4*)(W + (size_t)r * K + k0 + ko);
        }
        __syncthreads();
#pragma unroll
        for (int kk = 0; kk < 40; kk += 4) {
            float4 a0 = *(float4*)&eT[r0 * 44 + kk];
            float4 a1 = *(float4*)&eT[r1 * 44 + kk];
#pragma unroll
            for (int i = 0; i < 19; ++i) {
                int j = jg + 8 * i;
                float4 w = *(float4*)&wT[j * 44 + kk];
                acc0[i] += a0.x * w.x + a0.y * w.y + a0.z * w.z + a0.w * w.w;
                acc1[i] += a1.x * w.x + a1.y * w.y + a1.z * w.z + a1.w * w.w;
            }
        }
    }
    __syncthreads();
#pragma unroll
    for (int i = 0; i < 19; ++i) {
        int j = jg + 8 * i;
        if (j < 150) { smem[r0 * 152 + j] = acc0[i]; smem[r1 * 152 + j] = acc1[i]; }
    }
    __syncthreads();
    u16* og = out + blockR * 152;
    for (int fid = t; fid < 1216; fid += 256) {
        float4 a = *(float4*)&smem[fid * 8];
        float4 b = *(float4*)&smem[fid * 8 + 4];
        u16x8 v = { f2b(a.x), f2b(a.y), f2b(a.z), f2b(a.w),
                    f2b(b.x), f2b(b.y), f2b(b.z), f2b(b.w) };
        *(u16x8*)(og + fid * 8) = v;
    }
}

// ---------------------------------------------------------------------------
// GRU scan with MFMA GEMV; Whh B-fragments held in REGISTERS (no wfrag LDS).
// MODE 0: direct fp32 xp (stride 152), fp32 hs (50).
// MODE 1: gather fp32 xp via idx, fp32 hs (50).
// MODE 2: gather bf16 xp via idx, bf16 hs (stride 56).
// ---------------------------------------------------------------------------
template<int MODE>
__global__ __launch_bounds__(256) void k_gru_scan(
    const void* __restrict__ xp_, const int* __restrict__ idx,
    const float* __restrict__ Whh, const float* __restrict__ bhh,
    void* __restrict__ hs_, int T)
{
    __shared__ s16  hbuf[1024];        // [kc8][row16][e8]
    __shared__ float ghL[8 * 160];
    __shared__ float hL[8 * 52];
    __shared__ float bhL[152];
    __shared__ float xbuf[2][8 * 152];
    const int t = threadIdx.x;
    const int w = t >> 6, l = t & 63, lg = l >> 4, lr = l & 15;
    constexpr int HST = (MODE == 2) ? 56 : 50;

    for (int li = t; li < 1024; li += 256) hbuf[li] = 0;
    for (int e = t; e < 416; e += 256) hL[e] = 0.f;
    if (t < 152) bhL[t] = (t < 150) ? bhh[t] : 0.f;

    // B fragments in registers: frag(te, s)[e] = bf16(Whh[te*16+lr][(s*4+lg)*8+e])
    const int te_0 = (w * 3     > 9) ? 9 : w * 3;
    const int te_1 = (w * 3 + 1 > 9) ? 9 : w * 3 + 1;
    const int te_2 = (w * 3 + 2 > 9) ? 9 : w * 3 + 2;
    short8v B00 = {0,0,0,0,0,0,0,0}, B01 = B00, B10 = B00, B11 = B00, B20 = B00, B21 = B00;
    {
        int cols[3] = { te_0 * 16 + lr, te_1 * 16 + lr, te_2 * 16 + lr };
        short8v* frg[6] = { &B00, &B01, &B10, &B11, &B20, &B21 };
#pragma unroll
        for (int ti = 0; ti < 3; ++ti) {
            int col = cols[ti];
            if (col < 150) {
#pragma unroll
                for (int s = 0; s < 2; ++s) {
                    short8v v = {0,0,0,0,0,0,0,0};
#pragma unroll
                    for (int e = 0; e < 8; ++e) {
                        int k = (s * 4 + lg) * 8 + e;
                        if (k < 50) v[e] = (s16)f2b(Whh[col * 50 + k]);
                    }
                    *frg[ti * 2 + s] = v;
                }
            }
        }
    }

    const long seqbase = (long)blockIdx.x * 8;
    const float* xpf = (const float*)xp_;
    const u16*   xph = (const u16*)xp_;
    float* hsf = (float*)hs_;
    u16*   hsh = (u16*)hs_;

    const int rA = (MODE == 2) ? t / 19 : t / 38;
    const int oA = (MODE == 2) ? (t % 19) * 8 : (t % 38) * 4;
    const int rB = (t + 256) / 38, oB = ((t + 256) % 38) * 4;
    const bool actA = (MODE == 2) ? (t < 152) : true;
    const bool hasB = (MODE == 2) ? false : (t < 48);

    auto rowbase = [&](int rr, int stp) -> size_t {
        long r = seqbase + rr;
        long src = (MODE == 0) ? (r * T + stp) : (long)idx[r * T + stp];
        return (size_t)src * 152;
    };

    if (MODE == 2) {
        if (actA) {
            u16x8 v = *(const u16x8*)(xph + rowbase(rA, 0) + oA);
            float4 lo = { b2f(v[0]), b2f(v[1]), b2f(v[2]), b2f(v[3]) };
            float4 hi = { b2f(v[4]), b2f(v[5]), b2f(v[6]), b2f(v[7]) };
            *(float4*)&xbuf[0][rA * 152 + oA] = lo;
            *(float4*)&xbuf[0][rA * 152 + oA + 4] = hi;
        }
    } else {
        *(float4*)&xbuf[0][rA * 152 + oA] = *(const float4*)(xpf + rowbase(rA, 0) + oA);
        if (hasB)
            *(float4*)&xbuf[0][rB * 152 + oB] = *(const float4*)(xpf + rowbase(rB, 0) + oB);
    }
    __syncthreads();

    for (int st = 0; st < T; ++st) {
        const int cur = st & 1;
        u16x8 pfh;
        float4 pf0, pf1;
        if (st + 1 < T) {
            if (MODE == 2) {
                if (actA) pfh = *(const u16x8*)(xph + rowbase(rA, st + 1) + oA);
            } else {
                pf0 = *(const float4*)(xpf + rowbase(rA, st + 1) + oA);
                if (hasB) pf1 = *(const float4*)(xpf + rowbase(rB, st + 1) + oB);
            }
        }
        short8v a0 = *(short8v*)&hbuf[((0 + lg) * 16 + lr) * 8];
        short8v a1 = *(short8v*)&hbuf[((4 + lg) * 16 + lr) * 8];
        f32x4 c0 = {0,0,0,0}, c1 = {0,0,0,0}, c2 = {0,0,0,0};
        c0 = __builtin_amdgcn_mfma_f32_16x16x32_bf16(a0, B00, c0, 0, 0, 0);
        c0 = __builtin_amdgcn_mfma_f32_16x16x32_bf16(a1, B01, c0, 0, 0, 0);
        c1 = __builtin_amdgcn_mfma_f32_16x16x32_bf16(a0, B10, c1, 0, 0, 0);
        c1 = __builtin_amdgcn_mfma_f32_16x16x32_bf16(a1, B11, c1, 0, 0, 0);
        c2 = __builtin_amdgcn_mfma_f32_16x16x32_bf16(a0, B20, c2, 0, 0, 0);
        c2 = __builtin_amdgcn_mfma_f32_16x16x32_bf16(a1, B21, c2, 0, 0, 0);
        if (lg < 2) {
            int col0 = te_0 * 16 + lr, col1 = te_1 * 16 + lr, col2 = te_2 * 16 + lr;
            if (col0 < 150) {
#pragma unroll
                for (int r = 0; r < 4; ++r) ghL[(lg * 4 + r) * 160 + col0] = c0[r] + bhL[col0];
            }
            if (col1 < 150) {
#pragma unroll
                for (int r = 0; r < 4; ++r) ghL[(lg * 4 + r) * 160 + col1] = c1[r] + bhL[col1];
            }
            if (col2 < 150) {
#pragma unroll
                for (int r = 0; r < 4; ++r) ghL[(lg * 4 + r) * 160 + col2] = c2[r] + bhL[col2];
            }
        }
        __syncthreads();
        if (st + 1 < T) {
            if (MODE == 2) {
                if (actA) {
                    float4 lo = { b2f(pfh[0]), b2f(pfh[1]), b2f(pfh[2]), b2f(pfh[3]) };
                    float4 hi = { b2f(pfh[4]), b2f(pfh[5]), b2f(pfh[6]), b2f(pfh[7]) };
                    *(float4*)&xbuf[cur ^ 1][rA * 152 + oA] = lo;
                    *(float4*)&xbuf[cur ^ 1][rA * 152 + oA + 4] = hi;
                }
            } else {
                *(float4*)&xbuf[cur ^ 1][rA * 152 + oA] = pf0;
                if (hasB) *(float4*)&xbuf[cur ^ 1][rB * 152 + oB] = pf1;
            }
        }
        for (int item = t; item < 400; item += 256) {
            int ss = item / 50, hh = item % 50;
            const float* xr = &xbuf[cur][ss * 152];
            float vr  = xr[hh]       + ghL[ss * 160 + hh];
            float vz  = xr[50 + hh]  + ghL[ss * 160 + 50 + hh];
            float ghn = ghL[ss * 160 + 100 + hh];
            float rg = 1.f / (1.f + __expf(-vr));
            float zg = 1.f / (1.f + __expf(-vz));
            float a = xr[100 + hh] + rg * ghn;
            a = fminf(fmaxf(a, -15.f), 15.f);
            float e2 = __expf(-2.f * a);
            float nn2 = (1.f - e2) / (1.f + e2);
            float hn = (1.f - zg) * nn2 + zg * hL[ss * 52 + hh];
            hL[ss * 52 + hh] = hn;
            hbuf[((hh >> 3) * 16 + ss) * 8 + (hh & 7)] = (s16)f2b(hn);
            size_t ofs = ((size_t)(seqbase + ss) * T + st) * HST + hh;
            if (MODE == 2) hsh[ofs] = f2b(hn); else hsf[ofs] = hn;
        }
        __syncthreads();
    }
}

// ---------------------------------------------------------------------------
// ctx_hA[r][k] = sum_j ctx_h[r][j] * A[j][k]
// ---------------------------------------------------------------------------
__global__ __launch_bounds__(256) void k_matA(
    const float* __restrict__ inp, const float* __restrict__ A,
    float* __restrict__ outp)
{
    __shared__ float AL[50 * 52];
    __shared__ float inL[32 * 52];
    const int t = threadIdx.x;
    for (int e = t; e < 2500; e += 256) AL[(e / 50) * 52 + (e % 50)] = A[e];
    const long rbase = (long)blockIdx.x * 32;
    for (int e = t; e < 1600; e += 256) {
        int r = e / 50, j = e % 50;
        inL[r * 52 + j] = inp[(rbase + r) * 50 + j];
    }
    __syncthreads();
    for (int item = t; item < 1600; item += 256) {
        int r = item / 50, kk = item % 50;
        float acc = 0.f;
#pragma unroll 10
        for (int j = 0; j < 50; ++j)
            acc += inL[r * 52 + j] * AL[j * 52 + kk];
        outp[(rbase + r) * 50 + kk] = acc;
    }
}

// ---------------------------------------------------------------------------
// Fused match (MFMA) + conv3x3 + maxpool3x3/3. feats written bf16.
// Grid swizzled: wg = q*8+xcd, b = bq*8+xcd (same-b blocks pinned to one XCD).
// M1 staged in two K-halves (kc 0-15, 16-27) -> 24.6KB pool; Msh aliases pool.
// ---------------------------------------------------------------------------
__global__ __launch_bounds__(256) void k_matchconv(
    const u16* __restrict__ embh, const int* __restrict__ ctx_idx,
    const int* __restrict__ cand_idx, const float* __restrict__ ctxA,
    const u16* __restrict__ candh_h, const float* __restrict__ conv_w,
    u16* __restrict__ feats, int b0)
{
    __shared__ s16 pool16[12288];     // 24.6 KB staging, aliased by Msh in epilogue
    __shared__ float wL[144];
    __shared__ int ci[32], qi[2][32];
    float* Msh = (float*)pool16;      // [2][1056]
    const int t = threadIdx.x;
    const int wg = blockIdx.x;
    const int xcd = wg & 7, q = wg >> 3;
    const int r = q % 14, bq = q / 14;
    const int b = b0 + bq * 8 + xcd;
    const long nl = (long)(bq * 8 + xcd) * 14 + r;
    const int w = t >> 6, l = t & 63, lg = l >> 4, lr = l & 15;

    if (t < 144) wL[t] = conv_w[t];

    f32x4 cacc0 = {0,0,0,0}, cacc1 = {0,0,0,0};
    const int job0 = w * 2, job1 = w * 2 + 1;
    const int ch0 = job0 >> 2, rt0 = (job0 >> 1) & 1, ct0 = job0 & 1;
    const int ch1 = job1 >> 2, rt1 = (job1 >> 1) & 1, ct1 = job1 & 1;

    if (r < 7) {
        const int c0 = 2 * r;
        if (t < 32) ci[t] = ctx_idx[b * 32 + t];
        else if (t < 96)
            qi[(t - 32) >> 5][t & 31] =
                cand_idx[((long)b * 14 + c0 + ((t - 32) >> 5)) * 32 + (t & 31)];
        __syncthreads();
        s16* ctxL = pool16;            // [16][32][8]
        s16* canL = pool16 + 4096;     // [16][64][8]
        // ---- half 0: kc 0..15 (ksteps 0..3) ----
        for (int it = t; it < 512; it += 256) {
            int kc = it >> 5, row = it & 31;
            *(short8v*)&ctxL[it * 8] =
                *(const short8v*)(embh + (size_t)ci[row] * 200 + kc * 8);
        }
        for (int it = t; it < 1024; it += 256) {
            int kc = it >> 6, col = it & 63;
            *(short8v*)&canL[it * 8] =
                *(const short8v*)(embh + (size_t)qi[col >> 5][col & 31] * 200 + kc * 8);
        }
        __syncthreads();
#pragma unroll
        for (int s = 0; s < 4; ++s) {
            int kc = s * 4 + lg;
            short8v a0 = *(short8v*)&ctxL[(kc * 32 + rt0 * 16 + lr) * 8];
            short8v b0 = *(short8v*)&canL[(kc * 64 + ch0 * 32 + ct0 * 16 + lr) * 8];
            short8v b1 = *(short8v*)&canL[(kc * 64 + ch1 * 32 + ct1 * 16 + lr) * 8];
            cacc0 = __builtin_amdgcn_mfma_f32_16x16x32_bf16(a0, b0, cacc0, 0, 0, 0);
            short8v a1 = (rt0 == rt1) ? a0
                       : *(short8v*)&ctxL[(kc * 32 + rt1 * 16 + lr) * 8];
            cacc1 = __builtin_amdgcn_mfma_f32_16x16x32_bf16(a1, b1, cacc1, 0, 0, 0);
        }
        __syncthreads();
        // ---- half 1: kc 16..27 (ksteps 4..6), kc>=25 zero ----
        for (int it = t; it < 384; it += 256) {
            int kcp = it >> 5, row = it & 31;
            int kc = 16 + kcp;
            short8v v = {0,0,0,0,0,0,0,0};
            if (kc < 25) v = *(const short8v*)(embh + (size_t)ci[row] * 200 + kc * 8);
            *(short8v*)&ctxL[it * 8] = v;
        }
        s16* canL1 = pool16 + 3072;    // [12][64][8]
        for (int it = t; it < 768; it += 256) {
            int kcp = it >> 6, col = it & 63;
            int kc = 16 + kcp;
            short8v v = {0,0,0,0,0,0,0,0};
            if (kc < 25)
                v = *(const short8v*)(embh + (size_t)qi[col >> 5][col & 31] * 200 + kc * 8);
            *(short8v*)&canL1[it * 8] = v;
        }
        __syncthreads();
#pragma unroll
        for (int s = 4; s < 7; ++s) {
            int kcp = (s - 4) * 4 + lg;
            short8v a0 = *(short8v*)&ctxL[(kcp * 32 + rt0 * 16 + lr) * 8];
            short8v b0 = *(short8v*)&canL1[(kcp * 64 + ch0 * 32 + ct0 * 16 + lr) * 8];
            short8v b1 = *(short8v*)&canL1[(kcp * 64 + ch1 * 32 + ct1 * 16 + lr) * 8];
            cacc0 = __builtin_amdgcn_mfma_f32_16x16x32_bf16(a0, b0, cacc0, 0, 0, 0);
            short8v a1 = (rt0 == rt1) ? a0
                       : *(short8v*)&ctxL[(kcp * 32 + rt1 * 16 + lr) * 8];
            cacc1 = __builtin_amdgcn_mfma_f32_16x16x32_bf16(a1, b1, cacc1, 0, 0, 0);
        }
    } else {
        const int c0 = 2 * (r - 7);
        s16* aL = pool16;              // [8][32][8]
        s16* cL = pool16 + 2048;       // [8][64][8]
        for (int it = t; it < 256; it += 256) {
            int kc = it >> 5, row = it & 31;
            const float* src = ctxA + ((long)b * 32 + row) * 50;
            short8v v = {0,0,0,0,0,0,0,0};
#pragma unroll
            for (int e = 0; e < 8; ++e) {
                int k = kc * 8 + e;
                if (k < 50) v[e] = (s16)f2b(src[k]);
            }
            *(short8v*)&aL[it * 8] = v;
        }
        for (int it = t; it < 512; it += 256) {
            int kc = it >> 6, col = it & 63;
            long row = ((long)(b - b0) * 14 + c0 + (col >> 5)) * 32 + (col & 31);
            short8v v = {0,0,0,0,0,0,0,0};
            if (kc < 7) {
                v = *(const short8v*)(candh_h + (size_t)row * 56 + kc * 8);
                if (kc == 6) { v[2] = 0; v[3] = 0; v[4] = 0; v[5] = 0; v[6] = 0; v[7] = 0; }
            }
            *(short8v*)&cL[it * 8] = v;
        }
        __syncthreads();
#pragma unroll
        for (int s = 0; s < 2; ++s) {
            int kc = s * 4 + lg;
            short8v a0 = *(short8v*)&aL[(kc * 32 + rt0 * 16 + lr) * 8];
            short8v b0 = *(short8v*)&cL[(kc * 64 + ch0 * 32 + ct0 * 16 + lr) * 8];
            short8v b1 = *(short8v*)&cL[(kc * 64 + ch1 * 32 + ct1 * 16 + lr) * 8];
            cacc0 = __builtin_amdgcn_mfma_f32_16x16x32_bf16(a0, b0, cacc0, 0, 0, 0);
            short8v a1 = (rt0 == rt1) ? a0
                       : *(short8v*)&aL[(kc * 32 + rt1 * 16 + lr) * 8];
            cacc1 = __builtin_amdgcn_mfma_f32_16x16x32_bf16(a1, b1, cacc1, 0, 0, 0);
        }
    }

    __syncthreads();   // pool16 reads done; safe to alias with Msh
#pragma unroll
    for (int rr = 0; rr < 4; ++rr) {
        Msh[ch0 * 1056 + (rt0 * 16 + lg * 4 + rr) * 33 + ct0 * 16 + lr] = cacc0[rr];
        Msh[ch1 * 1056 + (rt1 * 16 + lg * 4 + rr) * 33 + ct1 * 16 + lr] = cacc1[rr];
    }
    __syncthreads();

    for (int item = t; item < 800; item += 256) {
        int oc = item / 100, rem = item % 100, py = rem / 10, px = rem % 10;
        float pv[2][5][5];
#pragma unroll
        for (int ch = 0; ch < 2; ++ch)
#pragma unroll
            for (int dy = 0; dy < 5; ++dy)
#pragma unroll
                for (int dx = 0; dx < 5; ++dx)
                    pv[ch][dy][dx] = Msh[ch * 1056 + (3 * py + dy) * 33 + (3 * px + dx)];
        float m = -1e30f;
#pragma unroll
        for (int dy0 = 0; dy0 < 3; ++dy0)
#pragma unroll
            for (int dx0 = 0; dx0 < 3; ++dx0) {
                float sacc = 0.f;
#pragma unroll
                for (int ch = 0; ch < 2; ++ch)
#pragma unroll
                    for (int ky = 0; ky < 3; ++ky)
#pragma unroll
                        for (int kx = 0; kx < 3; ++kx)
                            sacc += pv[ch][dy0 + ky][dx0 + kx] * wL[(oc * 2 + ch) * 9 + ky * 3 + kx];
                m = fmaxf(m, sacc);
            }
        feats[nl * 800 + item] = f2b(m);
    }
}

// ---------------------------------------------------------------------------
// xp2 MFMA GEMM: out[r][j] (fp32, stride 152) = dot(feats[r], W2[j]) + bih2[j]
// ---------------------------------------------------------------------------
__global__ __launch_bounds__(256) void k_xp2mm(
    const u16* __restrict__ feats, const u16* __restrict__ w2h,
    const float* __restrict__ bih2, float* __restrict__ out)
{
    __shared__ s16 Ab[2048];      // [kc4][row64][e8]
    __shared__ s16 Bb[2560];      // [kc4][col80][e8]
    __shared__ float bhL[160];
    const int t = threadIdx.x;
    const int w = t >> 6, l = t & 63, lg = l >> 4, lr = l & 15;
    const int mb = blockIdx.x >> 1, nb = blockIdx.x & 1;
    const long rowbase = (long)mb * 64;
    const int colbase = nb * 80;
    if (t < 160) bhL[t] = (t < 150) ? bih2[t] : 0.f;

    f32x4 acc[5];
#pragma unroll
    for (int i = 0; i < 5; ++i) acc[i] = (f32x4){0,0,0,0};

    for (int ch = 0; ch < 25; ++ch) {
        __syncthreads();
        {
            int kc = t >> 6, row = t & 63;
            *(short8v*)&Ab[t * 8] =
                *(const short8v*)(feats + (rowbase + row) * 800 + ch * 32 + kc * 8);
        }
        for (int it = t; it < 320; it += 256) {
            int kc = it / 80, col = it % 80;
            int gcol = colbase + col;
            short8v v = {0,0,0,0,0,0,0,0};
            if (gcol < 150)
                v = *(const short8v*)(w2h + (size_t)gcol * 800 + ch * 32 + kc * 8);
            *(short8v*)&Bb[it * 8] = v;
        }
        __syncthreads();
        short8v a = *(short8v*)&Ab[(lg * 64 + w * 16 + lr) * 8];
#pragma unroll
        for (int ct = 0; ct < 5; ++ct) {
            short8v bv = *(short8v*)&Bb[(lg * 80 + ct * 16 + lr) * 8];
            acc[ct] = __builtin_amdgcn_mfma_f32_16x16x32_bf16(a, bv, acc[ct], 0, 0, 0);
        }
    }
#pragma unroll
    for (int ct = 0; ct < 5; ++ct) {
        int gcol = colbase + ct * 16 + lr;
        if (gcol < 150) {
#pragma unroll
            for (int rr = 0; rr < 4; ++rr) {
                long row = rowbase + w * 16 + lg * 4 + rr;
                out[row * 152 + gcol] = acc[ct][rr] + bhL[gcol];
            }
        }
    }
}

// ---------------------------------------------------------------------------
__global__ __launch_bounds__(128) void k_fc1(
    const float* __restrict__ Hs, const float* __restrict__ w,
    const float* __restrict__ bias, float* __restrict__ hid)
{
    __shared__ float hr[700];
    const int t = threadIdx.x;
    const long b = blockIdx.x;
    for (int e = t; e < 700; e += 128) hr[e] = Hs[b * 700 + e];
    __syncthreads();
    if (t < 100) {
        float acc = bias[t];
        const float4* wp = (const float4*)(w + (size_t)t * 700);
        for (int k4 = 0; k4 < 175; ++k4) {
            float4 wv = wp[k4];
            float4 hv = *(float4*)&hr[k4 * 4];
            acc += wv.x * hv.x + wv.y * hv.y + wv.z * hv.z + wv.w * hv.w;
        }
        hid[b * 100 + t] = fmaxf(acc, 0.f);
    }
}

__global__ __launch_bounds__(64) void k_final(
    const float* __restrict__ hid, const float* __restrict__ w2,
    const float* __restrict__ b2, const float* __restrict__ y,
    float* __restrict__ partial)
{
    __shared__ float hL[100];
    const int t = threadIdx.x;
    const long b = blockIdx.x;
    for (int e = t; e < 100; e += 64) hL[e] = hid[b * 100 + e];
    __syncthreads();
    float logit = -1e30f;
    if (t < 14) {
        logit = b2[t];
        for (int k = 0; k < 100; ++k) logit += hL[k] * w2[t * 100 + k];
    }
    float m = logit;
    for (int off = 8; off; off >>= 1) m = fmaxf(m, __shfl_xor(m, off, 16));
    float ex = (t < 14) ? __expf(logit - m) : 0.f;
    float se = ex;
    for (int off = 8; off; off >>= 1) se += __shfl_xor(se, off, 16);
    float kl = 0.f;
    if (t < 14) {
        float lp = logit - m - __logf(se);
        float yv = y[b * 14 + t];
        kl = (yv > 0.f) ? yv * (__logf(yv) - lp) : 0.f;
    }
    for (int off = 8; off; off >>= 1) kl += __shfl_xor(kl, off, 16);
    if (t == 0) partial[b] = kl;
}

__global__ __launch_bounds__(256) void k_reduce(
    const float* __restrict__ partial, float* __restrict__ out)
{
    __shared__ float sm[256];
    const int t = threadIdx.x;
    sm[t] = partial[t] + partial[t + 256] + partial[t + 512] + partial[t + 768];
    __syncthreads();
    for (int off = 128; off; off >>= 1) {
        if (t < off) sm[t] += sm[t + off];
        __syncthreads();
    }
    if (t == 0) out[0] = sm[0] * (1.f / 14336.f);
}

// ---------------------------------------------------------------------------
extern "C" void kernel_launch(void* const* d_in, const int* in_sizes, int n_in,
                              void* d_out, int out_size, void* d_ws, size_t ws_size,
                              hipStream_t stream)
{
    const int*   ctx_idx  = (const int*)d_in[0];
    const int*   cand_idx = (const int*)d_in[1];
    const float* y_dev    = (const float*)d_in[2];
    const float* emb      = (const float*)d_in[3];
    const float* A        = (const float*)d_in[4];
    const float* Wih_c    = (const float*)d_in[5];
    const float* Whh_c    = (const float*)d_in[6];
    const float* bih_c    = (const float*)d_in[7];
    const float* bhh_c    = (const float*)d_in[8];
    const float* Wih_r    = (const float*)d_in[9];
    const float* Whh_r    = (const float*)d_in[10];
    const float* bih_r    = (const float*)d_in[11];
    const float* bhh_r    = (const float*)d_in[12];
    const float* conv_w   = (const float*)d_in[13];
    const float* Wih2     = (const float*)d_in[14];
    const float* Whh2     = (const float*)d_in[15];
    const float* bih2     = (const float*)d_in[16];
    const float* bhh2     = (const float*)d_in[17];
    const float* fc1_w    = (const float*)d_in[18];
    const float* fc1_b    = (const float*)d_in[19];
    const float* fc2_w    = (const float*)d_in[20];
    const float* fc2_b    = (const float*)d_in[21];

    float* ws = (float*)d_ws;
    // Arena (float slots), total ~31.9M f = 127.4 MB
    u16*   embh    = (u16*)ws;               // [21128][200] bf16 = 2,112,800 f
    float* proj_c  = ws + 2112800;           // [21184][152] f32  = 3,219,968 f
    u16*   proj_rh = (u16*)(ws + 5332768);   // [21184][152] bf16 = 1,609,984 f
    float* ctx_h   = ws + 6942752;           // 1,638,400
    float* ctxA    = ws + 8581152;           // 1,638,400
    u16*   candh_h = (u16*)(ws + 10219552);  // [458752][56] bf16 = 12,845,056 f
    u16*   feats_h = (u16*)(ws + 23064608);  // [14336][800] bf16 = 5,734,400 f
    u16*   w2h     = (u16*)(ws + 28799008);  // [150][800] bf16 = 60,000 f
    float* xp2     = ws + 28859008;          // [14336][152] = 2,179,072
    float* hs2     = ws + 31038080;          // 716,800
    float* hid     = ws + 31754880;          // 102,400
    float* part    = ws + 31857280;          // 1,024

    // 0. bf16 tables
    k_cvt      <<<4127, 256, 0, stream>>>(emb, embh, 1056400);
    k_cvt      <<<118, 256, 0, stream>>>(Wih2, w2h, 30000);
    // 1. vocab projections (bih folded)
    k_proj     <<<331, 256, 0, stream>>>(Wih_c, bih_c, emb, proj_c, 200, 21128);
    k_proj_b16 <<<331, 256, 0, stream>>>(Wih_r, bih_r, emb, proj_rh, 200, 21128);
    // 2. GRU scans (MFMA GEMV, Whh in registers)
    k_gru_scan<1><<<128,  256, 0, stream>>>(proj_c, ctx_idx,  Whh_c, bhh_c, ctx_h, 32);
    k_gru_scan<2><<<1792, 256, 0, stream>>>(proj_rh, cand_idx, Whh_r, bhh_r, candh_h, 32);
    k_matA     <<<1024, 256, 0, stream>>>(ctx_h, A, ctxA);
    // 3. match (MFMA, XCD-pinned swizzle, 2-half staging) + conv + pool
    k_matchconv<<<14336, 256, 0, stream>>>(embh, ctx_idx, cand_idx, ctxA, candh_h,
                                           conv_w, feats_h, 0);
    // 4. accumulation GRU (MFMA xp2 GEMM) + head
    k_xp2mm    <<<448, 256, 0, stream>>>(feats_h, w2h, bih2, xp2);
    k_gru_scan<0><<<128, 256, 0, stream>>>(xp2, nullptr, Whh2, bhh2, hs2, 14);
    k_fc1      <<<1024, 128, 0, stream>>>(hs2, fc1_w, fc1_b, hid);
    k_final    <<<1024, 64, 0, stream>>>(hid, fc2_w, fc2_b, y_dev, part);
    k_reduce   <<<1, 256, 0, stream>>>(part, (float*)d_out);
}

// Round 9
// 398.291 us; speedup vs baseline: 3.4502x; 1.5097x over previous
//
#include <hip/hip_runtime.h>
#include <math.h>

typedef unsigned short u16;
typedef short s16;
typedef u16 u16x8 __attribute__((ext_vector_type(8)));
typedef s16 short8v __attribute__((ext_vector_type(8)));
typedef float f32x4 __attribute__((ext_vector_type(4)));

__device__ __forceinline__ float b2f(u16 u) {
    return __uint_as_float(((unsigned)u) << 16);
}
__device__ __forceinline__ u16 f2b(float f) {        // RNE
    unsigned u = __float_as_uint(f);
    unsigned r = (u + 0x7FFFu + ((u >> 16) & 1u)) >> 16;
    return (u16)r;
}

// ---------------------------------------------------------------------------
// fp32 -> bf16 table conversion
// ---------------------------------------------------------------------------
__global__ __launch_bounds__(256) void k_cvt(
    const float* __restrict__ in, u16* __restrict__ out, int n4)
{
    int i = blockIdx.x * 256 + threadIdx.x;
    if (i < n4) {
        float4 v = ((const float4*)in)[i];
        *(ushort4*)(out + (size_t)i * 4) =
            make_ushort4(f2b(v.x), f2b(v.y), f2b(v.z), f2b(v.w));
    }
}

// ---------------------------------------------------------------------------
// Vocab projection via MFMA: out[v][j] (stride 152) = dot(embh[v], wh[j]) + bias[j]
// M=21184 (331 row-blocks of 64), N=150 (2 col-halves of 80), K=200 (7 chunks).
// OUTB16: 0 -> fp32 out, 1 -> bf16 out.
// ---------------------------------------------------------------------------
template<int OUTB16>
__global__ __launch_bounds__(256) void k_projmm(
    const u16* __restrict__ embh, const u16* __restrict__ wh,
    const float* __restrict__ bias, void* __restrict__ out, int V)
{
    __shared__ s16 Ab[2048];      // [kc4][row64][e8]
    __shared__ s16 Bb[2560];      // [kc4][col80][e8]
    __shared__ float bhL[160];
    const int t = threadIdx.x;
    const int w = t >> 6, l = t & 63, lg = l >> 4, lr = l & 15;
    const int mb = blockIdx.x >> 1, nb = blockIdx.x & 1;
    const long rowbase = (long)mb * 64;
    const int colbase = nb * 80;
    if (t < 160) bhL[t] = (t < 150) ? bias[t] : 0.f;

    f32x4 acc[5];
#pragma unroll
    for (int i = 0; i < 5; ++i) acc[i] = (f32x4){0,0,0,0};

    for (int ch = 0; ch < 7; ++ch) {
        __syncthreads();
        {
            int kc = t >> 6, row = t & 63;
            long grow = rowbase + row; if (grow >= V) grow = V - 1;
            int k0 = ch * 32 + kc * 8;
            short8v v = {0,0,0,0,0,0,0,0};
            if (k0 < 200) v = *(const short8v*)(embh + grow * 200 + k0);
            *(short8v*)&Ab[t * 8] = v;
        }
        for (int it = t; it < 320; it += 256) {
            int kc = it / 80, col = it % 80;
            int gcol = colbase + col;
            int k0 = ch * 32 + kc * 8;
            short8v v = {0,0,0,0,0,0,0,0};
            if (gcol < 150 && k0 < 200)
                v = *(const short8v*)(wh + (size_t)gcol * 200 + k0);
            *(short8v*)&Bb[it * 8] = v;
        }
        __syncthreads();
        short8v a = *(short8v*)&Ab[(lg * 64 + w * 16 + lr) * 8];
#pragma unroll
        for (int ct = 0; ct < 5; ++ct) {
            short8v bv = *(short8v*)&Bb[(lg * 80 + ct * 16 + lr) * 8];
            acc[ct] = __builtin_amdgcn_mfma_f32_16x16x32_bf16(a, bv, acc[ct], 0, 0, 0);
        }
    }
#pragma unroll
    for (int ct = 0; ct < 5; ++ct) {
        int gcol = colbase + ct * 16 + lr;
        if (gcol < 150) {
#pragma unroll
            for (int rr = 0; rr < 4; ++rr) {
                long row = rowbase + w * 16 + lg * 4 + rr;
                float vv = acc[ct][rr] + bhL[gcol];
                if (OUTB16) ((u16*)out)[row * 152 + gcol] = f2b(vv);
                else        ((float*)out)[row * 152 + gcol] = vv;
            }
        }
    }
}

// ---------------------------------------------------------------------------
// GRU scan with MFMA GEMV; Whh B-fragments held in REGISTERS.
// MODE 0: direct fp32 xp (stride 152), fp32 hs (50).
// MODE 1: gather fp32 xp via idx, fp32 hs (50).
// MODE 2: gather bf16 xp via idx, bf16 hs (stride 56).
// ---------------------------------------------------------------------------
template<int MODE>
__global__ __launch_bounds__(256) void k_gru_scan(
    const void* __restrict__ xp_, const int* __restrict__ idx,
    const float* __restrict__ Whh, const float* __restrict__ bhh,
    void* __restrict__ hs_, int T)
{
    __shared__ s16  hbuf[1024];        // [kc8][row16][e8]
    __shared__ float ghL[8 * 160];
    __shared__ float hL[8 * 52];
    __shared__ float bhL[152];
    __shared__ float xbuf[2][8 * 152];
    const int t = threadIdx.x;
    const int w = t >> 6, l = t & 63, lg = l >> 4, lr = l & 15;
    constexpr int HST = (MODE == 2) ? 56 : 50;

    for (int li = t; li < 1024; li += 256) hbuf[li] = 0;
    for (int e = t; e < 416; e += 256) hL[e] = 0.f;
    if (t < 152) bhL[t] = (t < 150) ? bhh[t] : 0.f;

    const int te_0 = (w * 3     > 9) ? 9 : w * 3;
    const int te_1 = (w * 3 + 1 > 9) ? 9 : w * 3 + 1;
    const int te_2 = (w * 3 + 2 > 9) ? 9 : w * 3 + 2;
    short8v B00 = {0,0,0,0,0,0,0,0}, B01 = B00, B10 = B00, B11 = B00, B20 = B00, B21 = B00;
    {
        int cols[3] = { te_0 * 16 + lr, te_1 * 16 + lr, te_2 * 16 + lr };
        short8v* frg[6] = { &B00, &B01, &B10, &B11, &B20, &B21 };
#pragma unroll
        for (int ti = 0; ti < 3; ++ti) {
            int col = cols[ti];
            if (col < 150) {
#pragma unroll
                for (int s = 0; s < 2; ++s) {
                    short8v v = {0,0,0,0,0,0,0,0};
#pragma unroll
                    for (int e = 0; e < 8; ++e) {
                        int k = (s * 4 + lg) * 8 + e;
                        if (k < 50) v[e] = (s16)f2b(Whh[col * 50 + k]);
                    }
                    *frg[ti * 2 + s] = v;
                }
            }
        }
    }

    const long seqbase = (long)blockIdx.x * 8;
    const float* xpf = (const float*)xp_;
    const u16*   xph = (const u16*)xp_;
    float* hsf = (float*)hs_;
    u16*   hsh = (u16*)hs_;

    const int rA = (MODE == 2) ? t / 19 : t / 38;
    const int oA = (MODE == 2) ? (t % 19) * 8 : (t % 38) * 4;
    const int rB = (t + 256) / 38, oB = ((t + 256) % 38) * 4;
    const bool actA = (MODE == 2) ? (t < 152) : true;
    const bool hasB = (MODE == 2) ? false : (t < 48);

    auto rowbase = [&](int rr, int stp) -> size_t {
        long r = seqbase + rr;
        long src = (MODE == 0) ? (r * T + stp) : (long)idx[r * T + stp];
        return (size_t)src * 152;
    };

    if (MODE == 2) {
        if (actA) {
            u16x8 v = *(const u16x8*)(xph + rowbase(rA, 0) + oA);
            float4 lo = { b2f(v[0]), b2f(v[1]), b2f(v[2]), b2f(v[3]) };
            float4 hi = { b2f(v[4]), b2f(v[5]), b2f(v[6]), b2f(v[7]) };
            *(float4*)&xbuf[0][rA * 152 + oA] = lo;
            *(float4*)&xbuf[0][rA * 152 + oA + 4] = hi;
        }
    } else {
        *(float4*)&xbuf[0][rA * 152 + oA] = *(const float4*)(xpf + rowbase(rA, 0) + oA);
        if (hasB)
            *(float4*)&xbuf[0][rB * 152 + oB] = *(const float4*)(xpf + rowbase(rB, 0) + oB);
    }
    __syncthreads();

    for (int st = 0; st < T; ++st) {
        const int cur = st & 1;
        u16x8 pfh;
        float4 pf0, pf1;
        if (st + 1 < T) {
            if (MODE == 2) {
                if (actA) pfh = *(const u16x8*)(xph + rowbase(rA, st + 1) + oA);
            } else {
                pf0 = *(const float4*)(xpf + rowbase(rA, st + 1) + oA);
                if (hasB) pf1 = *(const float4*)(xpf + rowbase(rB, st + 1) + oB);
            }
        }
        short8v a0 = *(short8v*)&hbuf[((0 + lg) * 16 + lr) * 8];
        short8v a1 = *(short8v*)&hbuf[((4 + lg) * 16 + lr) * 8];
        f32x4 c0 = {0,0,0,0}, c1 = {0,0,0,0}, c2 = {0,0,0,0};
        c0 = __builtin_amdgcn_mfma_f32_16x16x32_bf16(a0, B00, c0, 0, 0, 0);
        c0 = __builtin_amdgcn_mfma_f32_16x16x32_bf16(a1, B01, c0, 0, 0, 0);
        c1 = __builtin_amdgcn_mfma_f32_16x16x32_bf16(a0, B10, c1, 0, 0, 0);
        c1 = __builtin_amdgcn_mfma_f32_16x16x32_bf16(a1, B11, c1, 0, 0, 0);
        c2 = __builtin_amdgcn_mfma_f32_16x16x32_bf16(a0, B20, c2, 0, 0, 0);
        c2 = __builtin_amdgcn_mfma_f32_16x16x32_bf16(a1, B21, c2, 0, 0, 0);
        if (lg < 2) {
            int col0 = te_0 * 16 + lr, col1 = te_1 * 16 + lr, col2 = te_2 * 16 + lr;
            if (col0 < 150) {
#pragma unroll
                for (int r = 0; r < 4; ++r) ghL[(lg * 4 + r) * 160 + col0] = c0[r] + bhL[col0];
            }
            if (col1 < 150) {
#pragma unroll
                for (int r = 0; r < 4; ++r) ghL[(lg * 4 + r) * 160 + col1] = c1[r] + bhL[col1];
            }
            if (col2 < 150) {
#pragma unroll
                for (int r = 0; r < 4; ++r) ghL[(lg * 4 + r) * 160 + col2] = c2[r] + bhL[col2];
            }
        }
        __syncthreads();
        if (st + 1 < T) {
            if (MODE == 2) {
                if (actA) {
                    float4 lo = { b2f(pfh[0]), b2f(pfh[1]), b2f(pfh[2]), b2f(pfh[3]) };
                    float4 hi = { b2f(pfh[4]), b2f(pfh[5]), b2f(pfh[6]), b2f(pfh[7]) };
                    *(float4*)&xbuf[cur ^ 1][rA * 152 + oA] = lo;
                    *(float4*)&xbuf[cur ^ 1][rA * 152 + oA + 4] = hi;
                }
            } else {
                *(float4*)&xbuf[cur ^ 1][rA * 152 + oA] = pf0;
                if (hasB) *(float4*)&xbuf[cur ^ 1][rB * 152 + oB] = pf1;
            }
        }
        for (int item = t; item < 400; item += 256) {
            int ss = item / 50, hh = item % 50;
            const float* xr = &xbuf[cur][ss * 152];
            float vr  = xr[hh]       + ghL[ss * 160 + hh];
            float vz  = xr[50 + hh]  + ghL[ss * 160 + 50 + hh];
            float ghn = ghL[ss * 160 + 100 + hh];
            float rg = 1.f / (1.f + __expf(-vr));
            float zg = 1.f / (1.f + __expf(-vz));
            float a = xr[100 + hh] + rg * ghn;
            a = fminf(fmaxf(a, -15.f), 15.f);
            float e2 = __expf(-2.f * a);
            float nn2 = (1.f - e2) / (1.f + e2);
            float hn = (1.f - zg) * nn2 + zg * hL[ss * 52 + hh];
            hL[ss * 52 + hh] = hn;
            hbuf[((hh >> 3) * 16 + ss) * 8 + (hh & 7)] = (s16)f2b(hn);
            size_t ofs = ((size_t)(seqbase + ss) * T + st) * HST + hh;
            if (MODE == 2) hsh[ofs] = f2b(hn); else hsf[ofs] = hn;
        }
        __syncthreads();
    }
}

// ---------------------------------------------------------------------------
// ctx_hA[r][k] = sum_j ctx_h[r][j] * A[j][k]
// ---------------------------------------------------------------------------
__global__ __launch_bounds__(256) void k_matA(
    const float* __restrict__ inp, const float* __restrict__ A,
    float* __restrict__ outp)
{
    __shared__ float AL[50 * 52];
    __shared__ float inL[32 * 52];
    const int t = threadIdx.x;
    for (int e = t; e < 2500; e += 256) AL[(e / 50) * 52 + (e % 50)] = A[e];
    const long rbase = (long)blockIdx.x * 32;
    for (int e = t; e < 1600; e += 256) {
        int r = e / 50, j = e % 50;
        inL[r * 52 + j] = inp[(rbase + r) * 50 + j];
    }
    __syncthreads();
    for (int item = t; item < 1600; item += 256) {
        int r = item / 50, kk = item % 50;
        float acc = 0.f;
#pragma unroll 10
        for (int j = 0; j < 50; ++j)
            acc += inL[r * 52 + j] * AL[j * 52 + kk];
        outp[(rbase + r) * 50 + kk] = acc;
    }
}

// ---------------------------------------------------------------------------
// Fused match (MFMA) + conv3x3 via MFMA implicit-GEMM + maxpool3x3/3.
// Match output Mb bf16 [2][1092] (stride 33); conv C -> convL bf16 [912][10];
// pool -> feats bf16. All buffers alias the 24KB staging pool.
// ---------------------------------------------------------------------------
__global__ __launch_bounds__(256) void k_matchconv(
    const u16* __restrict__ embh, const int* __restrict__ ctx_idx,
    const int* __restrict__ cand_idx, const float* __restrict__ ctxA,
    const u16* __restrict__ candh_h, const float* __restrict__ conv_w,
    u16* __restrict__ feats, int b0)
{
    __shared__ s16 pool16[12288];     // 24 KB: staging | Mb+convL
    __shared__ float wL[144];
    __shared__ int ci[32], qi[2][32];
    u16* Mb    = (u16*)pool16;        // [2][1092]
    u16* convL = (u16*)pool16 + 2184; // [912][10]
    const int t = threadIdx.x;
    const int wg = blockIdx.x;
    const int xcd = wg & 7, q = wg >> 3;
    const int r = q % 14, bq = q / 14;
    const int b = b0 + bq * 8 + xcd;
    const long nl = (long)(bq * 8 + xcd) * 14 + r;
    const int w = t >> 6, l = t & 63, lg = l >> 4, lr = l & 15;

    if (t < 144) wL[t] = conv_w[t];

    f32x4 cacc0 = {0,0,0,0}, cacc1 = {0,0,0,0};
    const int job0 = w * 2, job1 = w * 2 + 1;
    const int ch0 = job0 >> 2, rt0 = (job0 >> 1) & 1, ct0 = job0 & 1;
    const int ch1 = job1 >> 2, rt1 = (job1 >> 1) & 1, ct1 = job1 & 1;

    if (r < 7) {
        const int c0 = 2 * r;
        if (t < 32) ci[t] = ctx_idx[b * 32 + t];
        else if (t < 96)
            qi[(t - 32) >> 5][t & 31] =
                cand_idx[((long)b * 14 + c0 + ((t - 32) >> 5)) * 32 + (t & 31)];
        __syncthreads();
        s16* ctxL = pool16;            // [16][32][8]
        s16* canL = pool16 + 4096;     // [16][64][8]
        for (int it = t; it < 512; it += 256) {
            int kc = it >> 5, row = it & 31;
            *(short8v*)&ctxL[it * 8] =
                *(const short8v*)(embh + (size_t)ci[row] * 200 + kc * 8);
        }
        for (int it = t; it < 1024; it += 256) {
            int kc = it >> 6, col = it & 63;
            *(short8v*)&canL[it * 8] =
                *(const short8v*)(embh + (size_t)qi[col >> 5][col & 31] * 200 + kc * 8);
        }
        __syncthreads();
#pragma unroll
        for (int s = 0; s < 4; ++s) {
            int kc = s * 4 + lg;
            short8v a0 = *(short8v*)&ctxL[(kc * 32 + rt0 * 16 + lr) * 8];
            short8v b0 = *(short8v*)&canL[(kc * 64 + ch0 * 32 + ct0 * 16 + lr) * 8];
            short8v b1 = *(short8v*)&canL[(kc * 64 + ch1 * 32 + ct1 * 16 + lr) * 8];
            cacc0 = __builtin_amdgcn_mfma_f32_16x16x32_bf16(a0, b0, cacc0, 0, 0, 0);
            short8v a1 = (rt0 == rt1) ? a0
                       : *(short8v*)&ctxL[(kc * 32 + rt1 * 16 + lr) * 8];
            cacc1 = __builtin_amdgcn_mfma_f32_16x16x32_bf16(a1, b1, cacc1, 0, 0, 0);
        }
        __syncthreads();
        for (int it = t; it < 384; it += 256) {
            int kcp = it >> 5, row = it & 31;
            int kc = 16 + kcp;
            short8v v = {0,0,0,0,0,0,0,0};
            if (kc < 25) v = *(const short8v*)(embh + (size_t)ci[row] * 200 + kc * 8);
            *(short8v*)&ctxL[it * 8] = v;
        }
        s16* canL1 = pool16 + 3072;    // [12][64][8]
        for (int it = t; it < 768; it += 256) {
            int kcp = it >> 6, col = it & 63;
            int kc = 16 + kcp;
            short8v v = {0,0,0,0,0,0,0,0};
            if (kc < 25)
                v = *(const short8v*)(embh + (size_t)qi[col >> 5][col & 31] * 200 + kc * 8);
            *(short8v*)&canL1[it * 8] = v;
        }
        __syncthreads();
#pragma unroll
        for (int s = 4; s < 7; ++s) {
            int kcp = (s - 4) * 4 + lg;
            short8v a0 = *(short8v*)&ctxL[(kcp * 32 + rt0 * 16 + lr) * 8];
            short8v b0 = *(short8v*)&canL1[(kcp * 64 + ch0 * 32 + ct0 * 16 + lr) * 8];
            short8v b1 = *(short8v*)&canL1[(kcp * 64 + ch1 * 32 + ct1 * 16 + lr) * 8];
            cacc0 = __builtin_amdgcn_mfma_f32_16x16x32_bf16(a0, b0, cacc0, 0, 0, 0);
            short8v a1 = (rt0 == rt1) ? a0
                       : *(short8v*)&ctxL[(kcp * 32 + rt1 * 16 + lr) * 8];
            cacc1 = __builtin_amdgcn_mfma_f32_16x16x32_bf16(a1, b1, cacc1, 0, 0, 0);
        }
    } else {
        const int c0 = 2 * (r - 7);
        s16* aL = pool16;              // [8][32][8]
        s16* cL = pool16 + 2048;       // [8][64][8]
        for (int it = t; it < 256; it += 256) {
            int kc = it >> 5, row = it & 31;
            const float* src = ctxA + ((long)b * 32 + row) * 50;
            short8v v = {0,0,0,0,0,0,0,0};
#pragma unroll
            for (int e = 0; e < 8; ++e) {
                int k = kc * 8 + e;
                if (k < 50) v[e] = (s16)f2b(src[k]);
            }
            *(short8v*)&aL[it * 8] = v;
        }
        for (int it = t; it < 512; it += 256) {
            int kc = it >> 6, col = it & 63;
            long row = ((long)(b - b0) * 14 + c0 + (col >> 5)) * 32 + (col & 31);
            short8v v = {0,0,0,0,0,0,0,0};
            if (kc < 7) {
                v = *(const short8v*)(candh_h + (size_t)row * 56 + kc * 8);
                if (kc == 6) { v[2] = 0; v[3] = 0; v[4] = 0; v[5] = 0; v[6] = 0; v[7] = 0; }
            }
            *(short8v*)&cL[it * 8] = v;
        }
        __syncthreads();
#pragma unroll
        for (int s = 0; s < 2; ++s) {
            int kc = s * 4 + lg;
            short8v a0 = *(short8v*)&aL[(kc * 32 + rt0 * 16 + lr) * 8];
            short8v b0 = *(short8v*)&cL[(kc * 64 + ch0 * 32 + ct0 * 16 + lr) * 8];
            short8v b1 = *(short8v*)&cL[(kc * 64 + ch1 * 32 + ct1 * 16 + lr) * 8];
            cacc0 = __builtin_amdgcn_mfma_f32_16x16x32_bf16(a0, b0, cacc0, 0, 0, 0);
            short8v a1 = (rt0 == rt1) ? a0
                       : *(short8v*)&aL[(kc * 32 + rt1 * 16 + lr) * 8];
            cacc1 = __builtin_amdgcn_mfma_f32_16x16x32_bf16(a1, b1, cacc1, 0, 0, 0);
        }
    }

    // ---- write match result (bf16) into Mb ----
    __syncthreads();   // staging reads done
#pragma unroll
    for (int rr = 0; rr < 4; ++rr) {
        Mb[ch0 * 1092 + (rt0 * 16 + lg * 4 + rr) * 33 + ct0 * 16 + lr] = f2b(cacc0[rr]);
        Mb[ch1 * 1092 + (rt1 * 16 + lg * 4 + rr) * 33 + ct1 * 16 + lr] = f2b(cacc1[rr]);
    }

    // conv B-fragment (from wL) + per-lane A address deltas (k = ch*9+ky*3+kx)
    short8v Bc = {0,0,0,0,0,0,0,0};
    int dlt[8];
#pragma unroll
    for (int e = 0; e < 8; ++e) {
        int s = lg * 8 + e;
        if (s < 18) {
            int ch = s / 9, r9 = s % 9, ky = r9 / 3, kx = r9 % 3;
            dlt[e] = ch * 1092 + ky * 33 + kx;
            if (lr < 8) Bc[e] = (s16)f2b(wL[lr * 18 + s]);
        } else dlt[e] = 0;
    }
    __syncthreads();   // Mb visible

    // ---- conv via MFMA: C[m=cy*30+cx][oc], 57 tiles of 16 rows ----
    for (int tile = w; tile < 57; tile += 4) {
        int m = tile * 16 + lr;
        int cy = m / 30, cx = m - cy * 30;
        int base = cy * 33 + cx;
        short8v a;
#pragma unroll
        for (int e = 0; e < 8; ++e) a[e] = (s16)Mb[base + dlt[e]];
        f32x4 c = {0,0,0,0};
        c = __builtin_amdgcn_mfma_f32_16x16x32_bf16(a, Bc, c, 0, 0, 0);
        if (lr < 8) {
#pragma unroll
            for (int rr = 0; rr < 4; ++rr)
                convL[(tile * 16 + lg * 4 + rr) * 10 + lr] = f2b(c[rr]);
        }
    }
    __syncthreads();

    // ---- maxpool 3x3 stride 3 -> feats ----
    for (int item = t; item < 800; item += 256) {
        int oc = item / 100, rem = item % 100, py = rem / 10, px = rem % 10;
        int m0 = (3 * py) * 30 + 3 * px;
        float mx = -1e30f;
#pragma unroll
        for (int dy = 0; dy < 3; ++dy)
#pragma unroll
            for (int dx = 0; dx < 3; ++dx)
                mx = fmaxf(mx, b2f(convL[(m0 + dy * 30 + dx) * 10 + oc]));
        feats[nl * 800 + item] = f2b(mx);
    }
}

// ---------------------------------------------------------------------------
// xp2 MFMA GEMM: out[r][j] (fp32, stride 152) = dot(feats[r], W2[j]) + bih2[j]
// ---------------------------------------------------------------------------
__global__ __launch_bounds__(256) void k_xp2mm(
    const u16* __restrict__ feats, const u16* __restrict__ w2h,
    const float* __restrict__ bih2, float* __restrict__ out)
{
    __shared__ s16 Ab[2048];      // [kc4][row64][e8]
    __shared__ s16 Bb[2560];      // [kc4][col80][e8]
    __shared__ float bhL[160];
    const int t = threadIdx.x;
    const int w = t >> 6, l = t & 63, lg = l >> 4, lr = l & 15;
    const int mb = blockIdx.x >> 1, nb = blockIdx.x & 1;
    const long rowbase = (long)mb * 64;
    const int colbase = nb * 80;
    if (t < 160) bhL[t] = (t < 150) ? bih2[t] : 0.f;

    f32x4 acc[5];
#pragma unroll
    for (int i = 0; i < 5; ++i) acc[i] = (f32x4){0,0,0,0};

    for (int ch = 0; ch < 25; ++ch) {
        __syncthreads();
        {
            int kc = t >> 6, row = t & 63;
            *(short8v*)&Ab[t * 8] =
                *(const short8v*)(feats + (rowbase + row) * 800 + ch * 32 + kc * 8);
        }
        for (int it = t; it < 320; it += 256) {
            int kc = it / 80, col = it % 80;
            int gcol = colbase + col;
            short8v v = {0,0,0,0,0,0,0,0};
            if (gcol < 150)
                v = *(const short8v*)(w2h + (size_t)gcol * 800 + ch * 32 + kc * 8);
            *(short8v*)&Bb[it * 8] = v;
        }
        __syncthreads();
        short8v a = *(short8v*)&Ab[(lg * 64 + w * 16 + lr) * 8];
#pragma unroll
        for (int ct = 0; ct < 5; ++ct) {
            short8v bv = *(short8v*)&Bb[(lg * 80 + ct * 16 + lr) * 8];
            acc[ct] = __builtin_amdgcn_mfma_f32_16x16x32_bf16(a, bv, acc[ct], 0, 0, 0);
        }
    }
#pragma unroll
    for (int ct = 0; ct < 5; ++ct) {
        int gcol = colbase + ct * 16 + lr;
        if (gcol < 150) {
#pragma unroll
            for (int rr = 0; rr < 4; ++rr) {
                long row = rowbase + w * 16 + lg * 4 + rr;
                out[row * 152 + gcol] = acc[ct][rr] + bhL[gcol];
            }
        }
    }
}

// ---------------------------------------------------------------------------
__global__ __launch_bounds__(128) void k_fc1(
    const float* __restrict__ Hs, const float* __restrict__ w,
    const float* __restrict__ bias, float* __restrict__ hid)
{
    __shared__ float hr[700];
    const int t = threadIdx.x;
    const long b = blockIdx.x;
    for (int e = t; e < 700; e += 128) hr[e] = Hs[b * 700 + e];
    __syncthreads();
    if (t < 100) {
        float acc = bias[t];
        const float4* wp = (const float4*)(w + (size_t)t * 700);
        for (int k4 = 0; k4 < 175; ++k4) {
            float4 wv = wp[k4];
            float4 hv = *(float4*)&hr[k4 * 4];
            acc += wv.x * hv.x + wv.y * hv.y + wv.z * hv.z + wv.w * hv.w;
        }
        hid[b * 100 + t] = fmaxf(acc, 0.f);
    }
}

__global__ __launch_bounds__(64) void k_final(
    const float* __restrict__ hid, const float* __restrict__ w2,
    const float* __restrict__ b2, const float* __restrict__ y,
    float* __restrict__ partial)
{
    __shared__ float hL[100];
    const int t = threadIdx.x;
    const long b = blockIdx.x;
    for (int e = t; e < 100; e += 64) hL[e] = hid[b * 100 + e];
    __syncthreads();
    float logit = -1e30f;
    if (t < 14) {
        logit = b2[t];
        for (int k = 0; k < 100; ++k) logit += hL[k] * w2[t * 100 + k];
    }
    float m = logit;
    for (int off = 8; off; off >>= 1) m = fmaxf(m, __shfl_xor(m, off, 16));
    float ex = (t < 14) ? __expf(logit - m) : 0.f;
    float se = ex;
    for (int off = 8; off; off >>= 1) se += __shfl_xor(se, off, 16);
    float kl = 0.f;
    if (t < 14) {
        float lp = logit - m - __logf(se);
        float yv = y[b * 14 + t];
        kl = (yv > 0.f) ? yv * (__logf(yv) - lp) : 0.f;
    }
    for (int off = 8; off; off >>= 1) kl += __shfl_xor(kl, off, 16);
    if (t == 0) partial[b] = kl;
}

__global__ __launch_bounds__(256) void k_reduce(
    const float* __restrict__ partial, float* __restrict__ out)
{
    __shared__ float sm[256];
    const int t = threadIdx.x;
    sm[t] = partial[t] + partial[t + 256] + partial[t + 512] + partial[t + 768];
    __syncthreads();
    for (int off = 128; off; off >>= 1) {
        if (t < off) sm[t] += sm[t + off];
        __syncthreads();
    }
    if (t == 0) out[0] = sm[0] * (1.f / 14336.f);
}

// ---------------------------------------------------------------------------
extern "C" void kernel_launch(void* const* d_in, const int* in_sizes, int n_in,
                              void* d_out, int out_size, void* d_ws, size_t ws_size,
                              hipStream_t stream)
{
    const int*   ctx_idx  = (const int*)d_in[0];
    const int*   cand_idx = (const int*)d_in[1];
    const float* y_dev    = (const float*)d_in[2];
    const float* emb      = (const float*)d_in[3];
    const float* A        = (const float*)d_in[4];
    const float* Wih_c    = (const float*)d_in[5];
    const float* Whh_c    = (const float*)d_in[6];
    const float* bih_c    = (const float*)d_in[7];
    const float* bhh_c    = (const float*)d_in[8];
    const float* Wih_r    = (const float*)d_in[9];
    const float* Whh_r    = (const float*)d_in[10];
    const float* bih_r    = (const float*)d_in[11];
    const float* bhh_r    = (const float*)d_in[12];
    const float* conv_w   = (const float*)d_in[13];
    const float* Wih2     = (const float*)d_in[14];
    const float* Whh2     = (const float*)d_in[15];
    const float* bih2     = (const float*)d_in[16];
    const float* bhh2     = (const float*)d_in[17];
    const float* fc1_w    = (const float*)d_in[18];
    const float* fc1_b    = (const float*)d_in[19];
    const float* fc2_w    = (const float*)d_in[20];
    const float* fc2_b    = (const float*)d_in[21];

    float* ws = (float*)d_ws;
    // Arena (float slots), total ~31.9M f = 127.6 MB
    u16*   embh    = (u16*)ws;               // [21128][200] bf16 = 2,112,800 f
    float* proj_c  = ws + 2112800;           // [21184][152] f32  = 3,219,968 f
    u16*   proj_rh = (u16*)(ws + 5332768);   // [21184][152] bf16 = 1,609,984 f
    float* ctx_h   = ws + 6942752;           // 1,638,400
    float* ctxA    = ws + 8581152;           // 1,638,400
    u16*   candh_h = (u16*)(ws + 10219552);  // [458752][56] bf16 = 12,845,056 f
    u16*   feats_h = (u16*)(ws + 23064608);  // [14336][800] bf16 = 5,734,400 f
    u16*   w2h     = (u16*)(ws + 28799008);  // [150][800] bf16 = 60,000 f
    u16*   wch     = (u16*)(ws + 28859008);  // [150][200] bf16 = 15,000 f
    u16*   wrh     = (u16*)(ws + 28874008);  // [150][200] bf16 = 15,000 f
    float* xp2     = ws + 28889008;          // [14336][152] = 2,179,072
    float* hs2     = ws + 31068080;          // 716,800
    float* hid     = ws + 31784880;          // 102,400
    float* part    = ws + 31887280;          // 1,024

    // 0. bf16 tables
    k_cvt       <<<4127, 256, 0, stream>>>(emb, embh, 1056400);
    k_cvt       <<<118, 256, 0, stream>>>(Wih2, w2h, 30000);
    k_cvt       <<<30, 256, 0, stream>>>(Wih_c, wch, 7500);
    k_cvt       <<<30, 256, 0, stream>>>(Wih_r, wrh, 7500);
    // 1. vocab projections via MFMA (bih folded)
    k_projmm<0> <<<662, 256, 0, stream>>>(embh, wch, bih_c, proj_c, 21128);
    k_projmm<1> <<<662, 256, 0, stream>>>(embh, wrh, bih_r, proj_rh, 21128);
    // 2. GRU scans (MFMA GEMV, Whh in registers)
    k_gru_scan<1><<<128,  256, 0, stream>>>(proj_c, ctx_idx,  Whh_c, bhh_c, ctx_h, 32);
    k_gru_scan<2><<<1792, 256, 0, stream>>>(proj_rh, cand_idx, Whh_r, bhh_r, candh_h, 32);
    k_matA      <<<1024, 256, 0, stream>>>(ctx_h, A, ctxA);
    // 3. match (MFMA) + conv (MFMA implicit-GEMM) + pool
    k_matchconv <<<14336, 256, 0, stream>>>(embh, ctx_idx, cand_idx, ctxA, candh_h,
                                            conv_w, feats_h, 0);
    // 4. accumulation GRU (MFMA xp2 GEMM) + head
    k_xp2mm     <<<448, 256, 0, stream>>>(feats_h, w2h, bih2, xp2);
    k_gru_scan<0><<<128, 256, 0, stream>>>(xp2, nullptr, Whh2, bhh2, hs2, 14);
    k_fc1       <<<1024, 128, 0, stream>>>(hs2, fc1_w, fc1_b, hid);
    k_final     <<<1024, 64, 0, stream>>>(hid, fc2_w, fc2_b, y_dev, part);
    k_reduce    <<<1, 256, 0, stream>>>(part, (float*)d_out);
}

// Round 10
// 379.379 us; speedup vs baseline: 3.6222x; 1.0498x over previous
//
#include <hip/hip_runtime.h>
#include <math.h>

typedef unsigned short u16;
typedef short s16;
typedef u16 u16x8 __attribute__((ext_vector_type(8)));
typedef s16 short8v __attribute__((ext_vector_type(8)));
typedef float f32x4 __attribute__((ext_vector_type(4)));

__device__ __forceinline__ float b2f(u16 u) {
    return __uint_as_float(((unsigned)u) << 16);
}
__device__ __forceinline__ u16 f2b(float f) {        // RNE
    unsigned u = __float_as_uint(f);
    unsigned r = (u + 0x7FFFu + ((u >> 16) & 1u)) >> 16;
    return (u16)r;
}

// ---------------------------------------------------------------------------
// fp32 -> bf16 conversion, 4 tables in one launch
// ---------------------------------------------------------------------------
__global__ __launch_bounds__(256) void k_cvt4(
    const float* __restrict__ s0, u16* __restrict__ d0, long n0,
    const float* __restrict__ s1, u16* __restrict__ d1, long n1,
    const float* __restrict__ s2, u16* __restrict__ d2, long n2,
    const float* __restrict__ s3, u16* __restrict__ d3, long n3)
{
    long j = (long)blockIdx.x * 256 + threadIdx.x;
    const float* s; u16* d;
    if (j < n0) { s = s0; d = d0; }
    else {
        j -= n0;
        if (j < n1) { s = s1; d = d1; }
        else {
            j -= n1;
            if (j < n2) { s = s2; d = d2; }
            else {
                j -= n2;
                if (j < n3) { s = s3; d = d3; }
                else return;
            }
        }
    }
    float4 v = ((const float4*)s)[j];
    *(ushort4*)(d + j * 4) = make_ushort4(f2b(v.x), f2b(v.y), f2b(v.z), f2b(v.w));
}

// ---------------------------------------------------------------------------
// Both vocab projections in one launch. blocks 0..661 -> ctx (fp32 out),
// 662..1323 -> cand (bf16 out). out[v][j] stride 152 = dot(embh[v],wh[j])+b[j].
// ---------------------------------------------------------------------------
__global__ __launch_bounds__(256) void k_projmm2(
    const u16* __restrict__ embh, const u16* __restrict__ wc,
    const u16* __restrict__ wr, const float* __restrict__ bc,
    const float* __restrict__ br, float* __restrict__ outc,
    u16* __restrict__ outr, int V)
{
    __shared__ s16 Ab[2048];      // [kc4][row64][e8]
    __shared__ s16 Bb[2560];      // [kc4][col80][e8]
    __shared__ float bhL[160];
    const int t = threadIdx.x;
    const int w = t >> 6, l = t & 63, lg = l >> 4, lr = l & 15;
    int id = blockIdx.x;
    const int half = (id >= 662) ? 1 : 0;
    id -= half * 662;
    const u16* wh = half ? wr : wc;
    const float* bias = half ? br : bc;
    const int mb = id >> 1, nb = id & 1;
    const long rowbase = (long)mb * 64;
    const int colbase = nb * 80;
    if (t < 160) bhL[t] = (t < 150) ? bias[t] : 0.f;

    f32x4 acc[5];
#pragma unroll
    for (int i = 0; i < 5; ++i) acc[i] = (f32x4){0,0,0,0};

    for (int ch = 0; ch < 7; ++ch) {
        __syncthreads();
        {
            int kc = t >> 6, row = t & 63;
            long grow = rowbase + row; if (grow >= V) grow = V - 1;
            int k0 = ch * 32 + kc * 8;
            short8v v = {0,0,0,0,0,0,0,0};
            if (k0 < 200) v = *(const short8v*)(embh + grow * 200 + k0);
            *(short8v*)&Ab[t * 8] = v;
        }
        for (int it = t; it < 320; it += 256) {
            int kc = it / 80, col = it % 80;
            int gcol = colbase + col;
            int k0 = ch * 32 + kc * 8;
            short8v v = {0,0,0,0,0,0,0,0};
            if (gcol < 150 && k0 < 200)
                v = *(const short8v*)(wh + (size_t)gcol * 200 + k0);
            *(short8v*)&Bb[it * 8] = v;
        }
        __syncthreads();
        short8v a = *(short8v*)&Ab[(lg * 64 + w * 16 + lr) * 8];
#pragma unroll
        for (int ct = 0; ct < 5; ++ct) {
            short8v bv = *(short8v*)&Bb[(lg * 80 + ct * 16 + lr) * 8];
            acc[ct] = __builtin_amdgcn_mfma_f32_16x16x32_bf16(a, bv, acc[ct], 0, 0, 0);
        }
    }
#pragma unroll
    for (int ct = 0; ct < 5; ++ct) {
        int gcol = colbase + ct * 16 + lr;
        if (gcol < 150) {
#pragma unroll
            for (int rr = 0; rr < 4; ++rr) {
                long row = rowbase + w * 16 + lg * 4 + rr;
                float vv = acc[ct][rr] + bhL[gcol];
                if (half) outr[row * 152 + gcol] = f2b(vv);
                else      outc[row * 152 + gcol] = vv;
            }
        }
    }
}

// ---------------------------------------------------------------------------
// GRU scan with MFMA GEMV; Whh B-fragments in registers.
// MODE 0: direct fp32 xp (stride 152), fp32 hs (50).  SEQS=8.
// MODE 1: gather fp32 xp via idx, fp32 hs (50).       SEQS=8.
// MODE 2: gather bf16 xp via idx, bf16 hs (56).       SEQS=16 (full A-tile).
// ---------------------------------------------------------------------------
template<int MODE, int SEQS>
__global__ __launch_bounds__(256) void k_gru_scan(
    const void* __restrict__ xp_, const int* __restrict__ idx,
    const float* __restrict__ Whh, const float* __restrict__ bhh,
    void* __restrict__ hs_, int T)
{
    __shared__ s16  hbuf[1024];            // [kc8][row16][e8]
    __shared__ float ghL[SEQS * 160];
    __shared__ float hL[SEQS * 52];
    __shared__ float bhL[152];
    __shared__ u16 xraw[4864];             // MODE2: u16[2][SEQS*152]; else f32 view
    const int t = threadIdx.x;
    const int w = t >> 6, l = t & 63, lg = l >> 4, lr = l & 15;
    constexpr int HST = (MODE == 2) ? 56 : 50;
    constexpr int XROW = SEQS * 152;
    u16*   xbH = xraw;
    float* xbF = (float*)xraw;

    for (int li = t; li < 1024; li += 256) hbuf[li] = 0;
    for (int e = t; e < SEQS * 52; e += 256) hL[e] = 0.f;
    if (t < 152) bhL[t] = (t < 150) ? bhh[t] : 0.f;

    const int te_0 = (w * 3     > 9) ? 9 : w * 3;
    const int te_1 = (w * 3 + 1 > 9) ? 9 : w * 3 + 1;
    const int te_2 = (w * 3 + 2 > 9) ? 9 : w * 3 + 2;
    short8v B00 = {0,0,0,0,0,0,0,0}, B01 = B00, B10 = B00, B11 = B00, B20 = B00, B21 = B00;
    {
        int cols[3] = { te_0 * 16 + lr, te_1 * 16 + lr, te_2 * 16 + lr };
        short8v* frg[6] = { &B00, &B01, &B10, &B11, &B20, &B21 };
#pragma unroll
        for (int ti = 0; ti < 3; ++ti) {
            int col = cols[ti];
            if (col < 150) {
#pragma unroll
                for (int s = 0; s < 2; ++s) {
                    short8v v = {0,0,0,0,0,0,0,0};
#pragma unroll
                    for (int e = 0; e < 8; ++e) {
                        int k = (s * 4 + lg) * 8 + e;
                        if (k < 50) v[e] = (s16)f2b(Whh[col * 50 + k]);
                    }
                    *frg[ti * 2 + s] = v;
                }
            }
        }
    }

    const long seqbase = (long)blockIdx.x * SEQS;
    const float* xpf = (const float*)xp_;
    const u16*   xph = (const u16*)xp_;
    float* hsf = (float*)hs_;
    u16*   hsh = (u16*)hs_;

    // prefetch item mapping
    const int rA = (MODE == 2) ? t / 19 : t / 38;
    const int oA = (MODE == 2) ? (t % 19) * 8 : (t % 38) * 4;
    const int rB = (MODE == 2) ? (t + 256) / 19 : (t + 256) / 38;
    const int oB = (MODE == 2) ? ((t + 256) % 19) * 8 : ((t + 256) % 38) * 4;
    const bool actA = (MODE == 2) ? (t < SEQS * 19) : true;
    const bool hasB = (MODE == 2) ? (t + 256 < SEQS * 19) : (t + 256 < SEQS * 38);

    auto rowbase = [&](int rr, int stp) -> size_t {
        long r = seqbase + rr;
        long src = (MODE == 0) ? (r * T + stp) : (long)idx[r * T + stp];
        return (size_t)src * 152;
    };

    if (MODE == 2) {
        if (actA) *(u16x8*)&xbH[rA * 152 + oA] = *(const u16x8*)(xph + rowbase(rA, 0) + oA);
        if (hasB) *(u16x8*)&xbH[rB * 152 + oB] = *(const u16x8*)(xph + rowbase(rB, 0) + oB);
    } else {
        *(float4*)&xbF[rA * 152 + oA] = *(const float4*)(xpf + rowbase(rA, 0) + oA);
        if (hasB)
            *(float4*)&xbF[rB * 152 + oB] = *(const float4*)(xpf + rowbase(rB, 0) + oB);
    }
    __syncthreads();

    for (int st = 0; st < T; ++st) {
        const int cur = st & 1;
        u16x8 pfh0, pfh1;
        float4 pf0, pf1;
        if (st + 1 < T) {
            if (MODE == 2) {
                if (actA) pfh0 = *(const u16x8*)(xph + rowbase(rA, st + 1) + oA);
                if (hasB) pfh1 = *(const u16x8*)(xph + rowbase(rB, st + 1) + oB);
            } else {
                pf0 = *(const float4*)(xpf + rowbase(rA, st + 1) + oA);
                if (hasB) pf1 = *(const float4*)(xpf + rowbase(rB, st + 1) + oB);
            }
        }
        short8v a0 = *(short8v*)&hbuf[((0 + lg) * 16 + lr) * 8];
        short8v a1 = *(short8v*)&hbuf[((4 + lg) * 16 + lr) * 8];
        f32x4 c0 = {0,0,0,0}, c1 = {0,0,0,0}, c2 = {0,0,0,0};
        c0 = __builtin_amdgcn_mfma_f32_16x16x32_bf16(a0, B00, c0, 0, 0, 0);
        c0 = __builtin_amdgcn_mfma_f32_16x16x32_bf16(a1, B01, c0, 0, 0, 0);
        c1 = __builtin_amdgcn_mfma_f32_16x16x32_bf16(a0, B10, c1, 0, 0, 0);
        c1 = __builtin_amdgcn_mfma_f32_16x16x32_bf16(a1, B11, c1, 0, 0, 0);
        c2 = __builtin_amdgcn_mfma_f32_16x16x32_bf16(a0, B20, c2, 0, 0, 0);
        c2 = __builtin_amdgcn_mfma_f32_16x16x32_bf16(a1, B21, c2, 0, 0, 0);
        if (lg * 4 < SEQS) {
            int col0 = te_0 * 16 + lr, col1 = te_1 * 16 + lr, col2 = te_2 * 16 + lr;
            if (col0 < 150) {
#pragma unroll
                for (int r = 0; r < 4; ++r) ghL[(lg * 4 + r) * 160 + col0] = c0[r] + bhL[col0];
            }
            if (col1 < 150) {
#pragma unroll
                for (int r = 0; r < 4; ++r) ghL[(lg * 4 + r) * 160 + col1] = c1[r] + bhL[col1];
            }
            if (col2 < 150) {
#pragma unroll
                for (int r = 0; r < 4; ++r) ghL[(lg * 4 + r) * 160 + col2] = c2[r] + bhL[col2];
            }
        }
        __syncthreads();
        if (st + 1 < T) {
            if (MODE == 2) {
                if (actA) *(u16x8*)&xbH[(cur ^ 1) * XROW + rA * 152 + oA] = pfh0;
                if (hasB) *(u16x8*)&xbH[(cur ^ 1) * XROW + rB * 152 + oB] = pfh1;
            } else {
                *(float4*)&xbF[(cur ^ 1) * XROW + rA * 152 + oA] = pf0;
                if (hasB) *(float4*)&xbF[(cur ^ 1) * XROW + rB * 152 + oB] = pf1;
            }
        }
        for (int item = t; item < SEQS * 50; item += 256) {
            int ss = item / 50, hh = item % 50;
            float xv0, xv1, xv2;
            if (MODE == 2) {
                const u16* xr = &xbH[cur * XROW + ss * 152];
                xv0 = b2f(xr[hh]); xv1 = b2f(xr[50 + hh]); xv2 = b2f(xr[100 + hh]);
            } else {
                const float* xr = &xbF[cur * XROW + ss * 152];
                xv0 = xr[hh]; xv1 = xr[50 + hh]; xv2 = xr[100 + hh];
            }
            float vr  = xv0 + ghL[ss * 160 + hh];
            float vz  = xv1 + ghL[ss * 160 + 50 + hh];
            float ghn = ghL[ss * 160 + 100 + hh];
            float rg = 1.f / (1.f + __expf(-vr));
            float zg = 1.f / (1.f + __expf(-vz));
            float a = xv2 + rg * ghn;
            a = fminf(fmaxf(a, -15.f), 15.f);
            float e2 = __expf(-2.f * a);
            float nn2 = (1.f - e2) / (1.f + e2);
            float hn = (1.f - zg) * nn2 + zg * hL[ss * 52 + hh];
            hL[ss * 52 + hh] = hn;
            hbuf[((hh >> 3) * 16 + ss) * 8 + (hh & 7)] = (s16)f2b(hn);
            size_t ofs = ((size_t)(seqbase + ss) * T + st) * HST + hh;
            if (MODE == 2) hsh[ofs] = f2b(hn); else hsf[ofs] = hn;
        }
        __syncthreads();
    }
}

// ---------------------------------------------------------------------------
// ctx_hA[r][k] = sum_j ctx_h[r][j] * A[j][k]
// ---------------------------------------------------------------------------
__global__ __launch_bounds__(256) void k_matA(
    const float* __restrict__ inp, const float* __restrict__ A,
    float* __restrict__ outp)
{
    __shared__ float AL[50 * 52];
    __shared__ float inL[32 * 52];
    const int t = threadIdx.x;
    for (int e = t; e < 2500; e += 256) AL[(e / 50) * 52 + (e % 50)] = A[e];
    const long rbase = (long)blockIdx.x * 32;
    for (int e = t; e < 1600; e += 256) {
        int r = e / 50, j = e % 50;
        inL[r * 52 + j] = inp[(rbase + r) * 50 + j];
    }
    __syncthreads();
    for (int item = t; item < 1600; item += 256) {
        int r = item / 50, kk = item % 50;
        float acc = 0.f;
#pragma unroll 10
        for (int j = 0; j < 50; ++j)
            acc += inL[r * 52 + j] * AL[j * 52 + kk];
        outp[(rbase + r) * 50 + kk] = acc;
    }
}

// ---------------------------------------------------------------------------
// Fused match (MFMA) + conv3x3 via MFMA + maxpool3x3/3. feats bf16.
// M1 staged in thirds (<=12 kc) with padded strides 33/65 (conflict-free b128).
// LDS ~20 KB -> 8 blocks/CU.
// ---------------------------------------------------------------------------
__global__ __launch_bounds__(256) void k_matchconv(
    const u16* __restrict__ embh, const int* __restrict__ ctx_idx,
    const int* __restrict__ cand_idx, const float* __restrict__ ctxA,
    const u16* __restrict__ candh_h, const float* __restrict__ conv_w,
    u16* __restrict__ feats, int b0)
{
    __shared__ s16 pool16[9480];      // 18.96 KB staging / Mb+convL alias
    __shared__ float wL[144];
    __shared__ int ci[32], qi[2][32];
    u16* Mb    = (u16*)pool16;        // [2][1092], row stride 33
    u16* convL = (u16*)pool16 + 2184; // [912][8]
    const int t = threadIdx.x;
    const int wg = blockIdx.x;
    const int xcd = wg & 7, q = wg >> 3;
    const int r = q % 14, bq = q / 14;
    const int b = b0 + bq * 8 + xcd;
    const long nl = (long)(bq * 8 + xcd) * 14 + r;
    const int w = t >> 6, l = t & 63, lg = l >> 4, lr = l & 15;

    if (t < 144) wL[t] = conv_w[t];

    f32x4 cacc0 = {0,0,0,0}, cacc1 = {0,0,0,0};
    const int job0 = w * 2, job1 = w * 2 + 1;
    const int ch0 = job0 >> 2, rt0 = (job0 >> 1) & 1, ct0 = job0 & 1;
    const int ch1 = job1 >> 2, rt1 = (job1 >> 1) & 1, ct1 = job1 & 1;

    if (r < 7) {
        const int c0 = 2 * r;
        if (t < 32) ci[t] = ctx_idx[b * 32 + t];
        else if (t < 96)
            qi[(t - 32) >> 5][t & 31] =
                cand_idx[((long)b * 14 + c0 + ((t - 32) >> 5)) * 32 + (t & 31)];
        __syncthreads();
        s16* ctxL = pool16;            // [kc<=12][33][8]
        s16* canL = pool16 + 3168;     // [kc<=12][65][8]
#pragma unroll
        for (int cnk = 0; cnk < 3; ++cnk) {
            const int kcbase = (cnk == 0) ? 0 : (cnk == 1 ? 12 : 20);
            const int kccnt  = (cnk == 0) ? 12 : 8;
            const int scnt   = (cnk == 0) ? 3 : 2;
            if (cnk) __syncthreads();              // prior MFMA reads done
            for (int it = t; it < kccnt * 32; it += 256) {
                int kcl = it >> 5, row = it & 31;
                int kc = kcbase + kcl;
                short8v v = {0,0,0,0,0,0,0,0};
                if (kc < 25) v = *(const short8v*)(embh + (size_t)ci[row] * 200 + kc * 8);
                *(short8v*)&ctxL[(kcl * 33 + row) * 8] = v;
            }
            for (int it = t; it < kccnt * 64; it += 256) {
                int kcl = it >> 6, col = it & 63;
                int kc = kcbase + kcl;
                short8v v = {0,0,0,0,0,0,0,0};
                if (kc < 25)
                    v = *(const short8v*)(embh + (size_t)qi[col >> 5][col & 31] * 200 + kc * 8);
                *(short8v*)&canL[(kcl * 65 + col) * 8] = v;
            }
            __syncthreads();
            for (int sl = 0; sl < scnt; ++sl) {
                int kcl = sl * 4 + lg;
                short8v a0 = *(short8v*)&ctxL[(kcl * 33 + rt0 * 16 + lr) * 8];
                short8v b0 = *(short8v*)&canL[(kcl * 65 + ch0 * 32 + ct0 * 16 + lr) * 8];
                short8v b1 = *(short8v*)&canL[(kcl * 65 + ch1 * 32 + ct1 * 16 + lr) * 8];
                cacc0 = __builtin_amdgcn_mfma_f32_16x16x32_bf16(a0, b0, cacc0, 0, 0, 0);
                short8v a1 = (rt0 == rt1) ? a0
                           : *(short8v*)&ctxL[(kcl * 33 + rt1 * 16 + lr) * 8];
                cacc1 = __builtin_amdgcn_mfma_f32_16x16x32_bf16(a1, b1, cacc1, 0, 0, 0);
            }
        }
    } else {
        const int c0 = 2 * (r - 7);
        s16* aL = pool16;              // [8][33][8]
        s16* cL = pool16 + 2112;       // [8][65][8]
        for (int it = t; it < 256; it += 256) {
            int kc = it >> 5, row = it & 31;
            const float* src = ctxA + ((long)b * 32 + row) * 50;
            short8v v = {0,0,0,0,0,0,0,0};
#pragma unroll
            for (int e = 0; e < 8; ++e) {
                int k = kc * 8 + e;
                if (k < 50) v[e] = (s16)f2b(src[k]);
            }
            *(short8v*)&aL[(kc * 33 + row) * 8] = v;
        }
        for (int it = t; it < 512; it += 256) {
            int kc = it >> 6, col = it & 63;
            long row = ((long)(b - b0) * 14 + c0 + (col >> 5)) * 32 + (col & 31);
            short8v v = {0,0,0,0,0,0,0,0};
            if (kc < 7) {
                v = *(const short8v*)(candh_h + (size_t)row * 56 + kc * 8);
                if (kc == 6) { v[2] = 0; v[3] = 0; v[4] = 0; v[5] = 0; v[6] = 0; v[7] = 0; }
            }
            *(short8v*)&cL[(kc * 65 + col) * 8] = v;
        }
        __syncthreads();
#pragma unroll
        for (int sl = 0; sl < 2; ++sl) {
            int kcl = sl * 4 + lg;
            short8v a0 = *(short8v*)&aL[(kcl * 33 + rt0 * 16 + lr) * 8];
            short8v b0 = *(short8v*)&cL[(kcl * 65 + ch0 * 32 + ct0 * 16 + lr) * 8];
            short8v b1 = *(short8v*)&cL[(kcl * 65 + ch1 * 32 + ct1 * 16 + lr) * 8];
            cacc0 = __builtin_amdgcn_mfma_f32_16x16x32_bf16(a0, b0, cacc0, 0, 0, 0);
            short8v a1 = (rt0 == rt1) ? a0
                       : *(short8v*)&aL[(kcl * 33 + rt1 * 16 + lr) * 8];
            cacc1 = __builtin_amdgcn_mfma_f32_16x16x32_bf16(a1, b1, cacc1, 0, 0, 0);
        }
    }

    __syncthreads();   // staging reads done; safe to alias with Mb
#pragma unroll
    for (int rr = 0; rr < 4; ++rr) {
        Mb[ch0 * 1092 + (rt0 * 16 + lg * 4 + rr) * 33 + ct0 * 16 + lr] = f2b(cacc0[rr]);
        Mb[ch1 * 1092 + (rt1 * 16 + lg * 4 + rr) * 33 + ct1 * 16 + lr] = f2b(cacc1[rr]);
    }

    // conv B-fragment + per-lane A address deltas (k = ch*9+ky*3+kx)
    short8v Bc = {0,0,0,0,0,0,0,0};
    int dlt[8];
#pragma unroll
    for (int e = 0; e < 8; ++e) {
        int s = lg * 8 + e;
        if (s < 18) {
            int ch = s / 9, r9 = s % 9, ky = r9 / 3, kx = r9 % 3;
            dlt[e] = ch * 1092 + ky * 33 + kx;
            if (lr < 8) Bc[e] = (s16)f2b(wL[lr * 18 + s]);
        } else dlt[e] = 0;
    }
    __syncthreads();   // Mb visible

    // conv via MFMA: C[m=cy*30+cx][oc], 57 tiles of 16 rows
    for (int tile = w; tile < 57; tile += 4) {
        int m = tile * 16 + lr;
        int cy = m / 30, cx = m - cy * 30;
        int base = cy * 33 + cx;
        short8v a;
#pragma unroll
        for (int e = 0; e < 8; ++e) a[e] = (s16)Mb[base + dlt[e]];
        f32x4 c = {0,0,0,0};
        c = __builtin_amdgcn_mfma_f32_16x16x32_bf16(a, Bc, c, 0, 0, 0);
        if (lr < 8) {
#pragma unroll
            for (int rr = 0; rr < 4; ++rr)
                convL[(tile * 16 + lg * 4 + rr) * 8 + lr] = f2b(c[rr]);
        }
    }
    __syncthreads();

    // maxpool 3x3 stride 3 -> feats
    for (int item = t; item < 800; item += 256) {
        int oc = item / 100, rem = item % 100, py = rem / 10, px = rem % 10;
        int m0 = (3 * py) * 30 + 3 * px;
        float mx = -1e30f;
#pragma unroll
        for (int dy = 0; dy < 3; ++dy)
#pragma unroll
            for (int dx = 0; dx < 3; ++dx)
                mx = fmaxf(mx, b2f(convL[(m0 + dy * 30 + dx) * 8 + oc]));
        feats[nl * 800 + item] = f2b(mx);
    }
}

// ---------------------------------------------------------------------------
// xp2 MFMA GEMM: out[r][j] (fp32, stride 152) = dot(feats[r], W2[j]) + bih2[j]
// ---------------------------------------------------------------------------
__global__ __launch_bounds__(256) void k_xp2mm(
    const u16* __restrict__ feats, const u16* __restrict__ w2h,
    const float* __restrict__ bih2, float* __restrict__ out)
{
    __shared__ s16 Ab[2048];      // [kc4][row64][e8]
    __shared__ s16 Bb[2560];      // [kc4][col80][e8]
    __shared__ float bhL[160];
    const int t = threadIdx.x;
    const int w = t >> 6, l = t & 63, lg = l >> 4, lr = l & 15;
    const int mb = blockIdx.x >> 1, nb = blockIdx.x & 1;
    const long rowbase = (long)mb * 64;
    const int colbase = nb * 80;
    if (t < 160) bhL[t] = (t < 150) ? bih2[t] : 0.f;

    f32x4 acc[5];
#pragma unroll
    for (int i = 0; i < 5; ++i) acc[i] = (f32x4){0,0,0,0};

    for (int ch = 0; ch < 25; ++ch) {
        __syncthreads();
        {
            int kc = t >> 6, row = t & 63;
            *(short8v*)&Ab[t * 8] =
                *(const short8v*)(feats + (rowbase + row) * 800 + ch * 32 + kc * 8);
        }
        for (int it = t; it < 320; it += 256) {
            int kc = it / 80, col = it % 80;
            int gcol = colbase + col;
            short8v v = {0,0,0,0,0,0,0,0};
            if (gcol < 150)
                v = *(const short8v*)(w2h + (size_t)gcol * 800 + ch * 32 + kc * 8);
            *(short8v*)&Bb[it * 8] = v;
        }
        __syncthreads();
        short8v a = *(short8v*)&Ab[(lg * 64 + w * 16 + lr) * 8];
#pragma unroll
        for (int ct = 0; ct < 5; ++ct) {
            short8v bv = *(short8v*)&Bb[(lg * 80 + ct * 16 + lr) * 8];
            acc[ct] = __builtin_amdgcn_mfma_f32_16x16x32_bf16(a, bv, acc[ct], 0, 0, 0);
        }
    }
#pragma unroll
    for (int ct = 0; ct < 5; ++ct) {
        int gcol = colbase + ct * 16 + lr;
        if (gcol < 150) {
#pragma unroll
            for (int rr = 0; rr < 4; ++rr) {
                long row = rowbase + w * 16 + lg * 4 + rr;
                out[row * 152 + gcol] = acc[ct][rr] + bhL[gcol];
            }
        }
    }
}

// ---------------------------------------------------------------------------
// fc1 + fc2 + log_softmax + KL fused: one block per b.
// ---------------------------------------------------------------------------
__global__ __launch_bounds__(128) void k_head(
    const float* __restrict__ Hs, const float* __restrict__ w1,
    const float* __restrict__ b1, const float* __restrict__ w2,
    const float* __restrict__ b2, const float* __restrict__ y,
    float* __restrict__ partial)
{
    __shared__ float hr[700];
    __shared__ float hidL[100];
    const int t = threadIdx.x;
    const long b = blockIdx.x;
    for (int e = t; e < 700; e += 128) hr[e] = Hs[b * 700 + e];
    __syncthreads();
    if (t < 100) {
        float acc = b1[t];
        const float4* wp = (const float4*)(w1 + (size_t)t * 700);
        for (int k4 = 0; k4 < 175; ++k4) {
            float4 wv = wp[k4];
            float4 hv = *(float4*)&hr[k4 * 4];
            acc += wv.x * hv.x + wv.y * hv.y + wv.z * hv.z + wv.w * hv.w;
        }
        hidL[t] = fmaxf(acc, 0.f);
    }
    __syncthreads();
    if (t < 64) {
        float logit = -1e30f;
        if (t < 14) {
            logit = b2[t];
            for (int k = 0; k < 100; ++k) logit += hidL[k] * w2[t * 100 + k];
        }
        float m = logit;
        for (int off = 8; off; off >>= 1) m = fmaxf(m, __shfl_xor(m, off, 16));
        float ex = (t < 14) ? __expf(logit - m) : 0.f;
        float se = ex;
        for (int off = 8; off; off >>= 1) se += __shfl_xor(se, off, 16);
        float kl = 0.f;
        if (t < 14) {
            float lp = logit - m - __logf(se);
            float yv = y[b * 14 + t];
            kl = (yv > 0.f) ? yv * (__logf(yv) - lp) : 0.f;
        }
        for (int off = 8; off; off >>= 1) kl += __shfl_xor(kl, off, 16);
        if (t == 0) partial[b] = kl;
    }
}

__global__ __launch_bounds__(256) void k_reduce(
    const float* __restrict__ partial, float* __restrict__ out)
{
    __shared__ float sm[256];
    const int t = threadIdx.x;
    sm[t] = partial[t] + partial[t + 256] + partial[t + 512] + partial[t + 768];
    __syncthreads();
    for (int off = 128; off; off >>= 1) {
        if (t < off) sm[t] += sm[t + off];
        __syncthreads();
    }
    if (t == 0) out[0] = sm[0] * (1.f / 14336.f);
}

// ---------------------------------------------------------------------------
extern "C" void kernel_launch(void* const* d_in, const int* in_sizes, int n_in,
                              void* d_out, int out_size, void* d_ws, size_t ws_size,
                              hipStream_t stream)
{
    const int*   ctx_idx  = (const int*)d_in[0];
    const int*   cand_idx = (const int*)d_in[1];
    const float* y_dev    = (const float*)d_in[2];
    const float* emb      = (const float*)d_in[3];
    const float* A        = (const float*)d_in[4];
    const float* Wih_c    = (const float*)d_in[5];
    const float* Whh_c    = (const float*)d_in[6];
    const float* bih_c    = (const float*)d_in[7];
    const float* bhh_c    = (const float*)d_in[8];
    const float* Wih_r    = (const float*)d_in[9];
    const float* Whh_r    = (const float*)d_in[10];
    const float* bih_r    = (const float*)d_in[11];
    const float* bhh_r    = (const float*)d_in[12];
    const float* conv_w   = (const float*)d_in[13];
    const float* Wih2     = (const float*)d_in[14];
    const float* Whh2     = (const float*)d_in[15];
    const float* bih2     = (const float*)d_in[16];
    const float* bhh2     = (const float*)d_in[17];
    const float* fc1_w    = (const float*)d_in[18];
    const float* fc1_b    = (const float*)d_in[19];
    const float* fc2_w    = (const float*)d_in[20];
    const float* fc2_b    = (const float*)d_in[21];

    float* ws = (float*)d_ws;
    // Arena (float slots), total ~31.9M f = 127.6 MB
    u16*   embh    = (u16*)ws;               // [21128][200] bf16 = 2,112,800 f
    float* proj_c  = ws + 2112800;           // [21184][152] f32  = 3,219,968 f
    u16*   proj_rh = (u16*)(ws + 5332768);   // [21184][152] bf16 = 1,609,984 f
    float* ctx_h   = ws + 6942752;           // 1,638,400
    float* ctxA    = ws + 8581152;           // 1,638,400
    u16*   candh_h = (u16*)(ws + 10219552);  // [458752][56] bf16 = 12,845,056 f
    u16*   feats_h = (u16*)(ws + 23064608);  // [14336][800] bf16 = 5,734,400 f
    u16*   w2h     = (u16*)(ws + 28799008);  // [150][800] bf16 = 60,000 f
    u16*   wch     = (u16*)(ws + 28859008);  // [150][200] bf16 = 15,000 f
    u16*   wrh     = (u16*)(ws + 28874008);  // [150][200] bf16 = 15,000 f
    float* xp2     = ws + 28889008;          // [14336][152] = 2,179,072
    float* hs2     = ws + 31068080;          // 716,800
    float* part    = ws + 31784880;          // 1,024

    // 0. bf16 tables (one launch)
    k_cvt4 <<<4303, 256, 0, stream>>>(emb, embh, 1056400,
                                      Wih2, w2h, 30000,
                                      Wih_c, wch, 7500,
                                      Wih_r, wrh, 7500);
    // 1. both vocab projections (one launch, bih folded)
    k_projmm2 <<<1324, 256, 0, stream>>>(embh, wch, wrh, bih_c, bih_r,
                                         proj_c, proj_rh, 21128);
    // 2. GRU scans (MFMA GEMV, Whh in registers; cand = 16 seqs/block)
    k_gru_scan<1, 8> <<<128, 256, 0, stream>>>(proj_c, ctx_idx,  Whh_c, bhh_c, ctx_h, 32);
    k_gru_scan<2, 16><<<896, 256, 0, stream>>>(proj_rh, cand_idx, Whh_r, bhh_r, candh_h, 32);
    k_matA <<<1024, 256, 0, stream>>>(ctx_h, A, ctxA);
    // 3. match (MFMA) + conv (MFMA) + pool
    k_matchconv <<<14336, 256, 0, stream>>>(embh, ctx_idx, cand_idx, ctxA, candh_h,
                                            conv_w, feats_h, 0);
    // 4. accumulation GRU + fused head
    k_xp2mm <<<448, 256, 0, stream>>>(feats_h, w2h, bih2, xp2);
    k_gru_scan<0, 8> <<<128, 256, 0, stream>>>(xp2, nullptr, Whh2, bhh2, hs2, 14);
    k_head <<<1024, 128, 0, stream>>>(hs2, fc1_w, fc1_b, fc2_w, fc2_b, y_dev, part);
    k_reduce <<<1, 256, 0, stream>>>(part, (float*)d_out);
}

// Round 12
// 330.586 us; speedup vs baseline: 4.1568x; 1.1476x over previous
//
#include <hip/hip_runtime.h>
#include <math.h>

typedef unsigned short u16;
typedef short s16;
typedef u16 u16x8 __attribute__((ext_vector_type(8)));
typedef s16 short8v __attribute__((ext_vector_type(8)));
typedef float f32x4 __attribute__((ext_vector_type(4)));

__device__ __forceinline__ float b2f(u16 u) {
    return __uint_as_float(((unsigned)u) << 16);
}
__device__ __forceinline__ u16 f2b(float f) {        // RNE
    unsigned u = __float_as_uint(f);
    unsigned r = (u + 0x7FFFu + ((u >> 16) & 1u)) >> 16;
    return (u16)r;
}

// ---------------------------------------------------------------------------
// fp32 -> bf16 conversion, 4 tables in one launch (destinations DISJOINT)
// ---------------------------------------------------------------------------
__global__ __launch_bounds__(256) void k_cvt4(
    const float* __restrict__ s0, u16* __restrict__ d0, long n0,
    const float* __restrict__ s1, u16* __restrict__ d1, long n1,
    const float* __restrict__ s2, u16* __restrict__ d2, long n2,
    const float* __restrict__ s3, u16* __restrict__ d3, long n3)
{
    long j = (long)blockIdx.x * 256 + threadIdx.x;
    const float* s; u16* d;
    if (j < n0) { s = s0; d = d0; }
    else {
        j -= n0;
        if (j < n1) { s = s1; d = d1; }
        else {
            j -= n1;
            if (j < n2) { s = s2; d = d2; }
            else {
                j -= n2;
                if (j < n3) { s = s3; d = d3; }
                else return;
            }
        }
    }
    float4 v = ((const float4*)s)[j];
    *(ushort4*)(d + j * 4) = make_ushort4(f2b(v.x), f2b(v.y), f2b(v.z), f2b(v.w));
}

// ---------------------------------------------------------------------------
// Both vocab projections in one launch; both outputs bf16 (stride 152 shorts).
// blocks 0..661 -> ctx table, 662..1323 -> cand table.
// ---------------------------------------------------------------------------
__global__ __launch_bounds__(256) void k_projmm2(
    const u16* __restrict__ embh, const u16* __restrict__ wc,
    const u16* __restrict__ wr, const float* __restrict__ bc,
    const float* __restrict__ br, u16* __restrict__ outc,
    u16* __restrict__ outr, int V)
{
    __shared__ s16 Ab[2048];      // [kc4][row64][e8]
    __shared__ s16 Bb[2560];      // [kc4][col80][e8]
    __shared__ float bhL[160];
    const int t = threadIdx.x;
    const int w = t >> 6, l = t & 63, lg = l >> 4, lr = l & 15;
    int id = blockIdx.x;
    const int half = (id >= 662) ? 1 : 0;
    id -= half * 662;
    const u16* wh = half ? wr : wc;
    const float* bias = half ? br : bc;
    u16* outp = half ? outr : outc;
    const int mb = id >> 1, nb = id & 1;
    const long rowbase = (long)mb * 64;
    const int colbase = nb * 80;
    if (t < 160) bhL[t] = (t < 150) ? bias[t] : 0.f;

    f32x4 acc[5];
#pragma unroll
    for (int i = 0; i < 5; ++i) acc[i] = (f32x4){0,0,0,0};

    for (int ch = 0; ch < 7; ++ch) {
        __syncthreads();
        {
            int kc = t >> 6, row = t & 63;
            long grow = rowbase + row; if (grow >= V) grow = V - 1;
            int k0 = ch * 32 + kc * 8;
            short8v v = {0,0,0,0,0,0,0,0};
            if (k0 < 200) v = *(const short8v*)(embh + grow * 200 + k0);
            *(short8v*)&Ab[t * 8] = v;
        }
        for (int it = t; it < 320; it += 256) {
            int kc = it / 80, col = it % 80;
            int gcol = colbase + col;
            int k0 = ch * 32 + kc * 8;
            short8v v = {0,0,0,0,0,0,0,0};
            if (gcol < 150 && k0 < 200)
                v = *(const short8v*)(wh + (size_t)gcol * 200 + k0);
            *(short8v*)&Bb[it * 8] = v;
        }
        __syncthreads();
        short8v a = *(short8v*)&Ab[(lg * 64 + w * 16 + lr) * 8];
#pragma unroll
        for (int ct = 0; ct < 5; ++ct) {
            short8v bv = *(short8v*)&Bb[(lg * 80 + ct * 16 + lr) * 8];
            acc[ct] = __builtin_amdgcn_mfma_f32_16x16x32_bf16(a, bv, acc[ct], 0, 0, 0);
        }
    }
#pragma unroll
    for (int ct = 0; ct < 5; ++ct) {
        int gcol = colbase + ct * 16 + lr;
        if (gcol < 150) {
#pragma unroll
            for (int rr = 0; rr < 4; ++rr) {
                long row = rowbase + w * 16 + lg * 4 + rr;
                outp[row * 152 + gcol] = f2b(acc[ct][rr] + bhL[gcol]);
            }
        }
    }
}

// ---------------------------------------------------------------------------
// GRU scan body (device template). MFMA GEMV; Whh B-fragments in registers.
// MODE 0: direct fp32 xp (stride 152), fp32 hs (50).
// MODE 2: gather bf16 xp via idx (stride 152), bf16 hs (stride 56).
// ---------------------------------------------------------------------------
template<int MODE, int SEQS>
__device__ __forceinline__ void gru_body(
    const void* __restrict__ xp_, const int* __restrict__ idx,
    const float* __restrict__ Whh, const float* __restrict__ bhh,
    void* __restrict__ hs_, int T, long blk)
{
    __shared__ s16  hbuf[1024];            // [kc8][row16][e8]
    __shared__ float ghL[SEQS * 160];
    __shared__ float hL[SEQS * 52];
    __shared__ float bhL[152];
    __shared__ u16 xraw[4864];             // MODE2: u16[2][SEQS*152]; MODE0: f32 view
    const int t = threadIdx.x;
    const int w = t >> 6, l = t & 63, lg = l >> 4, lr = l & 15;
    constexpr int HST = (MODE == 2) ? 56 : 50;
    constexpr int XROW = SEQS * 152;
    u16*   xbH = xraw;
    float* xbF = (float*)xraw;

    for (int li = t; li < 1024; li += 256) hbuf[li] = 0;
    for (int e = t; e < SEQS * 52; e += 256) hL[e] = 0.f;
    if (t < 152) bhL[t] = (t < 150) ? bhh[t] : 0.f;

    const int te_0 = (w * 3     > 9) ? 9 : w * 3;
    const int te_1 = (w * 3 + 1 > 9) ? 9 : w * 3 + 1;
    const int te_2 = (w * 3 + 2 > 9) ? 9 : w * 3 + 2;
    short8v B00 = {0,0,0,0,0,0,0,0}, B01 = B00, B10 = B00, B11 = B00, B20 = B00, B21 = B00;
    {
        int cols[3] = { te_0 * 16 + lr, te_1 * 16 + lr, te_2 * 16 + lr };
        short8v* frg[6] = { &B00, &B01, &B10, &B11, &B20, &B21 };
#pragma unroll
        for (int ti = 0; ti < 3; ++ti) {
            int col = cols[ti];
            if (col < 150) {
#pragma unroll
                for (int s = 0; s < 2; ++s) {
                    short8v v = {0,0,0,0,0,0,0,0};
#pragma unroll
                    for (int e = 0; e < 8; ++e) {
                        int k = (s * 4 + lg) * 8 + e;
                        if (k < 50) v[e] = (s16)f2b(Whh[col * 50 + k]);
                    }
                    *frg[ti * 2 + s] = v;
                }
            }
        }
    }

    const long seqbase = blk * SEQS;
    const float* xpf = (const float*)xp_;
    const u16*   xph = (const u16*)xp_;
    float* hsf = (float*)hs_;
    u16*   hsh = (u16*)hs_;

    const int rA = (MODE == 2) ? t / 19 : t / 38;
    const int oA = (MODE == 2) ? (t % 19) * 8 : (t % 38) * 4;
    const int rB = (MODE == 2) ? (t + 256) / 19 : (t + 256) / 38;
    const int oB = (MODE == 2) ? ((t + 256) % 19) * 8 : ((t + 256) % 38) * 4;
    const bool actA = (MODE == 2) ? (t < SEQS * 19) : true;
    const bool hasB = (MODE == 2) ? (t + 256 < SEQS * 19) : (t + 256 < SEQS * 38);

    auto rowbase = [&](int rr, int stp) -> size_t {
        long r = seqbase + rr;
        long src = (MODE == 0) ? (r * T + stp) : (long)idx[r * T + stp];
        return (size_t)src * 152;
    };

    if (MODE == 2) {
        if (actA) *(u16x8*)&xbH[rA * 152 + oA] = *(const u16x8*)(xph + rowbase(rA, 0) + oA);
        if (hasB) *(u16x8*)&xbH[rB * 152 + oB] = *(const u16x8*)(xph + rowbase(rB, 0) + oB);
    } else {
        *(float4*)&xbF[rA * 152 + oA] = *(const float4*)(xpf + rowbase(rA, 0) + oA);
        if (hasB)
            *(float4*)&xbF[rB * 152 + oB] = *(const float4*)(xpf + rowbase(rB, 0) + oB);
    }
    __syncthreads();

    for (int st = 0; st < T; ++st) {
        const int cur = st & 1;
        u16x8 pfh0, pfh1;
        float4 pf0, pf1;
        if (st + 1 < T) {
            if (MODE == 2) {
                if (actA) pfh0 = *(const u16x8*)(xph + rowbase(rA, st + 1) + oA);
                if (hasB) pfh1 = *(const u16x8*)(xph + rowbase(rB, st + 1) + oB);
            } else {
                pf0 = *(const float4*)(xpf + rowbase(rA, st + 1) + oA);
                if (hasB) pf1 = *(const float4*)(xpf + rowbase(rB, st + 1) + oB);
            }
        }
        short8v a0 = *(short8v*)&hbuf[((0 + lg) * 16 + lr) * 8];
        short8v a1 = *(short8v*)&hbuf[((4 + lg) * 16 + lr) * 8];
        f32x4 c0 = {0,0,0,0}, c1 = {0,0,0,0}, c2 = {0,0,0,0};
        c0 = __builtin_amdgcn_mfma_f32_16x16x32_bf16(a0, B00, c0, 0, 0, 0);
        c0 = __builtin_amdgcn_mfma_f32_16x16x32_bf16(a1, B01, c0, 0, 0, 0);
        c1 = __builtin_amdgcn_mfma_f32_16x16x32_bf16(a0, B10, c1, 0, 0, 0);
        c1 = __builtin_amdgcn_mfma_f32_16x16x32_bf16(a1, B11, c1, 0, 0, 0);
        c2 = __builtin_amdgcn_mfma_f32_16x16x32_bf16(a0, B20, c2, 0, 0, 0);
        c2 = __builtin_amdgcn_mfma_f32_16x16x32_bf16(a1, B21, c2, 0, 0, 0);
        if (lg * 4 < SEQS) {
            int col0 = te_0 * 16 + lr, col1 = te_1 * 16 + lr, col2 = te_2 * 16 + lr;
            if (col0 < 150) {
#pragma unroll
                for (int r = 0; r < 4; ++r) ghL[(lg * 4 + r) * 160 + col0] = c0[r] + bhL[col0];
            }
            if (col1 < 150) {
#pragma unroll
                for (int r = 0; r < 4; ++r) ghL[(lg * 4 + r) * 160 + col1] = c1[r] + bhL[col1];
            }
            if (col2 < 150) {
#pragma unroll
                for (int r = 0; r < 4; ++r) ghL[(lg * 4 + r) * 160 + col2] = c2[r] + bhL[col2];
            }
        }
        __syncthreads();
        if (st + 1 < T) {
            if (MODE == 2) {
                if (actA) *(u16x8*)&xbH[(cur ^ 1) * XROW + rA * 152 + oA] = pfh0;
                if (hasB) *(u16x8*)&xbH[(cur ^ 1) * XROW + rB * 152 + oB] = pfh1;
            } else {
                *(float4*)&xbF[(cur ^ 1) * XROW + rA * 152 + oA] = pf0;
                if (hasB) *(float4*)&xbF[(cur ^ 1) * XROW + rB * 152 + oB] = pf1;
            }
        }
        for (int item = t; item < SEQS * 50; item += 256) {
            int ss = item / 50, hh = item % 50;
            float xv0, xv1, xv2;
            if (MODE == 2) {
                const u16* xr = &xbH[cur * XROW + ss * 152];
                xv0 = b2f(xr[hh]); xv1 = b2f(xr[50 + hh]); xv2 = b2f(xr[100 + hh]);
            } else {
                const float* xr = &xbF[cur * XROW + ss * 152];
                xv0 = xr[hh]; xv1 = xr[50 + hh]; xv2 = xr[100 + hh];
            }
            float vr  = xv0 + ghL[ss * 160 + hh];
            float vz  = xv1 + ghL[ss * 160 + 50 + hh];
            float ghn = ghL[ss * 160 + 100 + hh];
            float rg = 1.f / (1.f + __expf(-vr));
            float zg = 1.f / (1.f + __expf(-vz));
            float a = xv2 + rg * ghn;
            a = fminf(fmaxf(a, -15.f), 15.f);
            float e2 = __expf(-2.f * a);
            float nn2 = (1.f - e2) / (1.f + e2);
            float hn = (1.f - zg) * nn2 + zg * hL[ss * 52 + hh];
            hL[ss * 52 + hh] = hn;
            hbuf[((hh >> 3) * 16 + ss) * 8 + (hh & 7)] = (s16)f2b(hn);
            size_t ofs = ((size_t)(seqbase + ss) * T + st) * HST + hh;
            if (MODE == 2) hsh[ofs] = f2b(hn); else hsf[ofs] = hn;
        }
        __syncthreads();
    }
}

// Merged scan: blocks 0..895 cand (16 seqs each), 896..959 ctx (16 seqs each).
__global__ __launch_bounds__(256) void k_scan_all(
    const u16* __restrict__ proj_ch, const u16* __restrict__ proj_rh,
    const int* __restrict__ ctx_idx, const int* __restrict__ cand_idx,
    const float* __restrict__ Whh_c, const float* __restrict__ Whh_r,
    const float* __restrict__ bhh_c, const float* __restrict__ bhh_r,
    u16* __restrict__ ctx_hh, u16* __restrict__ candh_h)
{
    const long bid = blockIdx.x;
    const bool cand = (bid < 896);
    gru_body<2, 16>(cand ? (const void*)proj_rh : (const void*)proj_ch,
                    cand ? cand_idx : ctx_idx,
                    cand ? Whh_r : Whh_c,
                    cand ? bhh_r : bhh_c,
                    cand ? (void*)candh_h : (void*)ctx_hh,
                    32, cand ? bid : bid - 896);
}

// GRU2 scan: direct fp32 xp2, fp32 hs2.
__global__ __launch_bounds__(256) void k_scan2(
    const float* __restrict__ xp2, const float* __restrict__ Whh2,
    const float* __restrict__ bhh2, float* __restrict__ hs2)
{
    gru_body<0, 8>(xp2, nullptr, Whh2, bhh2, hs2, 14, (long)blockIdx.x);
}

// ---------------------------------------------------------------------------
// ctxA[r][k] (bf16, stride 56) = sum_j b2f(ctx_hh[r][j]) * A[j][k]
// ---------------------------------------------------------------------------
__global__ __launch_bounds__(256) void k_matA(
    const u16* __restrict__ inh, const float* __restrict__ A,
    u16* __restrict__ outh)
{
    __shared__ float AL[50 * 52];
    __shared__ float inL[32 * 52];
    const int t = threadIdx.x;
    for (int e = t; e < 2500; e += 256) AL[(e / 50) * 52 + (e % 50)] = A[e];
    const long rbase = (long)blockIdx.x * 32;
    for (int e = t; e < 1600; e += 256) {
        int r = e / 50, j = e % 50;
        inL[r * 52 + j] = b2f(inh[(rbase + r) * 56 + j]);
    }
    __syncthreads();
    for (int item = t; item < 1600; item += 256) {
        int r = item / 50, kk = item % 50;
        float acc = 0.f;
#pragma unroll 10
        for (int j = 0; j < 50; ++j)
            acc += inL[r * 52 + j] * AL[j * 52 + kk];
        outh[(rbase + r) * 56 + kk] = f2b(acc);
    }
}

// ---------------------------------------------------------------------------
// Fused match (MFMA) + conv3x3 via MFMA + maxpool3x3/3. feats bf16.
// ---------------------------------------------------------------------------
__global__ __launch_bounds__(256) void k_matchconv(
    const u16* __restrict__ embh, const int* __restrict__ ctx_idx,
    const int* __restrict__ cand_idx, const u16* __restrict__ ctxA_h,
    const u16* __restrict__ candh_h, const float* __restrict__ conv_w,
    u16* __restrict__ feats, int b0)
{
    __shared__ s16 pool16[9480];      // staging / Mb+convL alias
    __shared__ float wL[144];
    __shared__ int ci[32], qi[2][32];
    u16* Mb    = (u16*)pool16;        // [2][1092], row stride 33
    u16* convL = (u16*)pool16 + 2184; // [912][8]
    const int t = threadIdx.x;
    const int wg = blockIdx.x;
    const int xcd = wg & 7, q = wg >> 3;
    const int r = q % 14, bq = q / 14;
    const int b = b0 + bq * 8 + xcd;
    const long nl = (long)(bq * 8 + xcd) * 14 + r;
    const int w = t >> 6, l = t & 63, lg = l >> 4, lr = l & 15;

    if (t < 144) wL[t] = conv_w[t];

    f32x4 cacc0 = {0,0,0,0}, cacc1 = {0,0,0,0};
    const int job0 = w * 2, job1 = w * 2 + 1;
    const int ch0 = job0 >> 2, rt0 = (job0 >> 1) & 1, ct0 = job0 & 1;
    const int ch1 = job1 >> 2, rt1 = (job1 >> 1) & 1, ct1 = job1 & 1;

    if (r < 7) {
        const int c0 = 2 * r;
        if (t < 32) ci[t] = ctx_idx[b * 32 + t];
        else if (t < 96)
            qi[(t - 32) >> 5][t & 31] =
                cand_idx[((long)b * 14 + c0 + ((t - 32) >> 5)) * 32 + (t & 31)];
        __syncthreads();
        s16* ctxL = pool16;            // [kc<=12][33][8]
        s16* canL = pool16 + 3168;     // [kc<=12][65][8]
#pragma unroll
        for (int cnk = 0; cnk < 3; ++cnk) {
            const int kcbase = (cnk == 0) ? 0 : (cnk == 1 ? 12 : 20);
            const int kccnt  = (cnk == 0) ? 12 : 8;
            const int scnt   = (cnk == 0) ? 3 : 2;
            if (cnk) __syncthreads();
            for (int it = t; it < kccnt * 32; it += 256) {
                int kcl = it >> 5, row = it & 31;
                int kc = kcbase + kcl;
                short8v v = {0,0,0,0,0,0,0,0};
                if (kc < 25) v = *(const short8v*)(embh + (size_t)ci[row] * 200 + kc * 8);
                *(short8v*)&ctxL[(kcl * 33 + row) * 8] = v;
            }
            for (int it = t; it < kccnt * 64; it += 256) {
                int kcl = it >> 6, col = it & 63;
                int kc = kcbase + kcl;
                short8v v = {0,0,0,0,0,0,0,0};
                if (kc < 25)
                    v = *(const short8v*)(embh + (size_t)qi[col >> 5][col & 31] * 200 + kc * 8);
                *(short8v*)&canL[(kcl * 65 + col) * 8] = v;
            }
            __syncthreads();
            for (int sl = 0; sl < scnt; ++sl) {
                int kcl = sl * 4 + lg;
                short8v a0 = *(short8v*)&ctxL[(kcl * 33 + rt0 * 16 + lr) * 8];
                short8v b0 = *(short8v*)&canL[(kcl * 65 + ch0 * 32 + ct0 * 16 + lr) * 8];
                short8v b1 = *(short8v*)&canL[(kcl * 65 + ch1 * 32 + ct1 * 16 + lr) * 8];
                cacc0 = __builtin_amdgcn_mfma_f32_16x16x32_bf16(a0, b0, cacc0, 0, 0, 0);
                short8v a1 = (rt0 == rt1) ? a0
                           : *(short8v*)&ctxL[(kcl * 33 + rt1 * 16 + lr) * 8];
                cacc1 = __builtin_amdgcn_mfma_f32_16x16x32_bf16(a1, b1, cacc1, 0, 0, 0);
            }
        }
    } else {
        const int c0 = 2 * (r - 7);
        s16* aL = pool16;              // [8][33][8]
        s16* cL = pool16 + 2112;       // [8][65][8]
        for (int it = t; it < 256; it += 256) {
            int kc = it >> 5, row = it & 31;
            short8v v = {0,0,0,0,0,0,0,0};
            if (kc < 7) {
                v = *(const short8v*)(ctxA_h + (size_t)(b * 32 + row) * 56 + kc * 8);
                if (kc == 6) { v[2] = 0; v[3] = 0; v[4] = 0; v[5] = 0; v[6] = 0; v[7] = 0; }
            }
            *(short8v*)&aL[(kc * 33 + row) * 8] = v;
        }
        for (int it = t; it < 512; it += 256) {
            int kc = it >> 6, col = it & 63;
            long row = ((long)(b - b0) * 14 + c0 + (col >> 5)) * 32 + (col & 31);
            short8v v = {0,0,0,0,0,0,0,0};
            if (kc < 7) {
                v = *(const short8v*)(candh_h + (size_t)row * 56 + kc * 8);
                if (kc == 6) { v[2] = 0; v[3] = 0; v[4] = 0; v[5] = 0; v[6] = 0; v[7] = 0; }
            }
            *(short8v*)&cL[(kc * 65 + col) * 8] = v;
        }
        __syncthreads();
#pragma unroll
        for (int sl = 0; sl < 2; ++sl) {
            int kcl = sl * 4 + lg;
            short8v a0 = *(short8v*)&aL[(kcl * 33 + rt0 * 16 + lr) * 8];
            short8v b0 = *(short8v*)&cL[(kcl * 65 + ch0 * 32 + ct0 * 16 + lr) * 8];
            short8v b1 = *(short8v*)&cL[(kcl * 65 + ch1 * 32 + ct1 * 16 + lr) * 8];
            cacc0 = __builtin_amdgcn_mfma_f32_16x16x32_bf16(a0, b0, cacc0, 0, 0, 0);
            short8v a1 = (rt0 == rt1) ? a0
                       : *(short8v*)&aL[(kcl * 33 + rt1 * 16 + lr) * 8];
            cacc1 = __builtin_amdgcn_mfma_f32_16x16x32_bf16(a1, b1, cacc1, 0, 0, 0);
        }
    }

    __syncthreads();   // staging reads done; safe to alias with Mb
#pragma unroll
    for (int rr = 0; rr < 4; ++rr) {
        Mb[ch0 * 1092 + (rt0 * 16 + lg * 4 + rr) * 33 + ct0 * 16 + lr] = f2b(cacc0[rr]);
        Mb[ch1 * 1092 + (rt1 * 16 + lg * 4 + rr) * 33 + ct1 * 16 + lr] = f2b(cacc1[rr]);
    }

    short8v Bc = {0,0,0,0,0,0,0,0};
    int dlt[8];
#pragma unroll
    for (int e = 0; e < 8; ++e) {
        int s = lg * 8 + e;
        if (s < 18) {
            int ch = s / 9, r9 = s % 9, ky = r9 / 3, kx = r9 % 3;
            dlt[e] = ch * 1092 + ky * 33 + kx;
            if (lr < 8) Bc[e] = (s16)f2b(wL[lr * 18 + s]);
        } else dlt[e] = 0;
    }
    __syncthreads();   // Mb visible

    for (int tile = w; tile < 57; tile += 4) {
        int m = tile * 16 + lr;
        int cy = m / 30, cx = m - cy * 30;
        int base = cy * 33 + cx;
        short8v a;
#pragma unroll
        for (int e = 0; e < 8; ++e) a[e] = (s16)Mb[base + dlt[e]];
        f32x4 c = {0,0,0,0};
        c = __builtin_amdgcn_mfma_f32_16x16x32_bf16(a, Bc, c, 0, 0, 0);
        if (lr < 8) {
#pragma unroll
            for (int rr = 0; rr < 4; ++rr)
                convL[(tile * 16 + lg * 4 + rr) * 8 + lr] = f2b(c[rr]);
        }
    }
    __syncthreads();

    for (int item = t; item < 800; item += 256) {
        int oc = item / 100, rem = item % 100, py = rem / 10, px = rem % 10;
        int m0 = (3 * py) * 30 + 3 * px;
        float mx = -1e30f;
#pragma unroll
        for (int dy = 0; dy < 3; ++dy)
#pragma unroll
            for (int dx = 0; dx < 3; ++dx)
                mx = fmaxf(mx, b2f(convL[(m0 + dy * 30 + dx) * 8 + oc]));
        feats[nl * 800 + item] = f2b(mx);
    }
}

// ---------------------------------------------------------------------------
// xp2 MFMA GEMM: out[r][j] (fp32, stride 152) = dot(feats[r], W2[j]) + bih2[j]
// ---------------------------------------------------------------------------
__global__ __launch_bounds__(256) void k_xp2mm(
    const u16* __restrict__ feats, const u16* __restrict__ w2h,
    const float* __restrict__ bih2, float* __restrict__ out)
{
    __shared__ s16 Ab[2048];      // [kc4][row64][e8]
    __shared__ s16 Bb[2560];      // [kc4][col80][e8]
    __shared__ float bhL[160];
    const int t = threadIdx.x;
    const int w = t >> 6, l = t & 63, lg = l >> 4, lr = l & 15;
    const int mb = blockIdx.x >> 1, nb = blockIdx.x & 1;
    const long rowbase = (long)mb * 64;
    const int colbase = nb * 80;
    if (t < 160) bhL[t] = (t < 150) ? bih2[t] : 0.f;

    f32x4 acc[5];
#pragma unroll
    for (int i = 0; i < 5; ++i) acc[i] = (f32x4){0,0,0,0};

    for (int ch = 0; ch < 25; ++ch) {
        __syncthreads();
        {
            int kc = t >> 6, row = t & 63;
            *(short8v*)&Ab[t * 8] =
                *(const short8v*)(feats + (rowbase + row) * 800 + ch * 32 + kc * 8);
        }
        for (int it = t; it < 320; it += 256) {
            int kc = it / 80, col = it % 80;
            int gcol = colbase + col;
            short8v v = {0,0,0,0,0,0,0,0};
            if (gcol < 150)
                v = *(const short8v*)(w2h + (size_t)gcol * 800 + ch * 32 + kc * 8);
            *(short8v*)&Bb[it * 8] = v;
        }
        __syncthreads();
        short8v a = *(short8v*)&Ab[(lg * 64 + w * 16 + lr) * 8];
#pragma unroll
        for (int ct = 0; ct < 5; ++ct) {
            short8v bv = *(short8v*)&Bb[(lg * 80 + ct * 16 + lr) * 8];
            acc[ct] = __builtin_amdgcn_mfma_f32_16x16x32_bf16(a, bv, acc[ct], 0, 0, 0);
        }
    }
#pragma unroll
    for (int ct = 0; ct < 5; ++ct) {
        int gcol = colbase + ct * 16 + lr;
        if (gcol < 150) {
#pragma unroll
            for (int rr = 0; rr < 4; ++rr) {
                long row = rowbase + w * 16 + lg * 4 + rr;
                out[row * 152 + gcol] = acc[ct][rr] + bhL[gcol];
            }
        }
    }
}

// ---------------------------------------------------------------------------
// fc1 + fc2 + log_softmax + KL fused: one block per b.
// ---------------------------------------------------------------------------
__global__ __launch_bounds__(128) void k_head(
    const float* __restrict__ Hs, const float* __restrict__ w1,
    const float* __restrict__ b1, const float* __restrict__ w2,
    const float* __restrict__ b2, const float* __restrict__ y,
    float* __restrict__ partial)
{
    __shared__ float hr[700];
    __shared__ float hidL[100];
    const int t = threadIdx.x;
    const long b = blockIdx.x;
    for (int e = t; e < 700; e += 128) hr[e] = Hs[b * 700 + e];
    __syncthreads();
    if (t < 100) {
        float acc = b1[t];
        const float4* wp = (const float4*)(w1 + (size_t)t * 700);
        for (int k4 = 0; k4 < 175; ++k4) {
            float4 wv = wp[k4];
            float4 hv = *(float4*)&hr[k4 * 4];
            acc += wv.x * hv.x + wv.y * hv.y + wv.z * hv.z + wv.w * hv.w;
        }
        hidL[t] = fmaxf(acc, 0.f);
    }
    __syncthreads();
    if (t < 64) {
        float logit = -1e30f;
        if (t < 14) {
            logit = b2[t];
            for (int k = 0; k < 100; ++k) logit += hidL[k] * w2[t * 100 + k];
        }
        float m = logit;
        for (int off = 8; off; off >>= 1) m = fmaxf(m, __shfl_xor(m, off, 16));
        float ex = (t < 14) ? __expf(logit - m) : 0.f;
        float se = ex;
        for (int off = 8; off; off >>= 1) se += __shfl_xor(se, off, 16);
        float kl = 0.f;
        if (t < 14) {
            float lp = logit - m - __logf(se);
            float yv = y[b * 14 + t];
            kl = (yv > 0.f) ? yv * (__logf(yv) - lp) : 0.f;
        }
        for (int off = 8; off; off >>= 1) kl += __shfl_xor(kl, off, 16);
        if (t == 0) partial[b] = kl;
    }
}

__global__ __launch_bounds__(256) void k_reduce(
    const float* __restrict__ partial, float* __restrict__ out)
{
    __shared__ float sm[256];
    const int t = threadIdx.x;
    sm[t] = partial[t] + partial[t + 256] + partial[t + 512] + partial[t + 768];
    __syncthreads();
    for (int off = 128; off; off >>= 1) {
        if (t < off) sm[t] += sm[t + off];
        __syncthreads();
    }
    if (t == 0) out[0] = sm[0] * (1.f / 14336.f);
}

// ---------------------------------------------------------------------------
extern "C" void kernel_launch(void* const* d_in, const int* in_sizes, int n_in,
                              void* d_out, int out_size, void* d_ws, size_t ws_size,
                              hipStream_t stream)
{
    const int*   ctx_idx  = (const int*)d_in[0];
    const int*   cand_idx = (const int*)d_in[1];
    const float* y_dev    = (const float*)d_in[2];
    const float* emb      = (const float*)d_in[3];
    const float* A        = (const float*)d_in[4];
    const float* Wih_c    = (const float*)d_in[5];
    const float* Whh_c    = (const float*)d_in[6];
    const float* bih_c    = (const float*)d_in[7];
    const float* bhh_c    = (const float*)d_in[8];
    const float* Wih_r    = (const float*)d_in[9];
    const float* Whh_r    = (const float*)d_in[10];
    const float* bih_r    = (const float*)d_in[11];
    const float* bhh_r    = (const float*)d_in[12];
    const float* conv_w   = (const float*)d_in[13];
    const float* Wih2     = (const float*)d_in[14];
    const float* Whh2     = (const float*)d_in[15];
    const float* bih2     = (const float*)d_in[16];
    const float* bhh2     = (const float*)d_in[17];
    const float* fc1_w    = (const float*)d_in[18];
    const float* fc1_b    = (const float*)d_in[19];
    const float* fc2_w    = (const float*)d_in[20];
    const float* fc2_b    = (const float*)d_in[21];

    float* ws = (float*)d_ws;
    // Arena (float slots), total 28,734,128 f = 114.9 MB. ALL REGIONS DISJOINT
    // (round-11 bug: w2h is 60,000 f, wch/wrh/xp2 were placed inside it).
    u16*   embh    = (u16*)ws;               // [21128][200] bf16 = 2,112,800 f
    u16*   proj_ch = (u16*)(ws + 2112800);   // [21184][152] bf16 = 1,609,984 f
    u16*   proj_rh = (u16*)(ws + 3722784);   // [21184][152] bf16 = 1,609,984 f
    u16*   ctx_hh  = (u16*)(ws + 5332768);   // [32768][56] bf16 = 917,504 f
    u16*   ctxA_h  = (u16*)(ws + 6250272);   // [32768][56] bf16 = 917,504 f
    u16*   candh_h = (u16*)(ws + 7167776);   // [458752][56] bf16 = 12,845,056 f
    u16*   feats_h = (u16*)(ws + 20012832);  // [14336][800] bf16 = 5,734,400 f
    u16*   w2h     = (u16*)(ws + 25747232);  // [150][800] bf16 = 60,000 f
    u16*   wch     = (u16*)(ws + 25807232);  // [150][200] bf16 = 15,000 f
    u16*   wrh     = (u16*)(ws + 25822232);  // [150][200] bf16 = 15,000 f
    float* xp2     = ws + 25837232;          // [14336][152] = 2,179,072
    float* hs2     = ws + 28016304;          // 716,800
    float* part    = ws + 28733104;          // 1,024

    // 0. bf16 tables (one launch)
    k_cvt4 <<<4303, 256, 0, stream>>>(emb, embh, 1056400,
                                      Wih2, w2h, 30000,
                                      Wih_c, wch, 7500,
                                      Wih_r, wrh, 7500);
    // 1. both vocab projections (one launch, bih folded, bf16 out)
    k_projmm2 <<<1324, 256, 0, stream>>>(embh, wch, wrh, bih_c, bih_r,
                                         proj_ch, proj_rh, 21128);
    // 2. merged GRU scans: 896 cand blocks + 64 ctx blocks, all co-resident
    k_scan_all <<<960, 256, 0, stream>>>(proj_ch, proj_rh, ctx_idx, cand_idx,
                                         Whh_c, Whh_r, bhh_c, bhh_r,
                                         ctx_hh, candh_h);
    k_matA <<<1024, 256, 0, stream>>>(ctx_hh, A, ctxA_h);
    // 3. match (MFMA) + conv (MFMA) + pool
    k_matchconv <<<14336, 256, 0, stream>>>(embh, ctx_idx, cand_idx, ctxA_h, candh_h,
                                            conv_w, feats_h, 0);
    // 4. accumulation GRU + fused head
    k_xp2mm <<<448, 256, 0, stream>>>(feats_h, w2h, bih2, xp2);
    k_scan2 <<<128, 256, 0, stream>>>(xp2, Whh2, bhh2, hs2);
    k_head <<<1024, 128, 0, stream>>>(hs2, fc1_w, fc1_b, fc2_w, fc2_b, y_dev, part);
    k_reduce <<<1, 256, 0, stream>>>(part, (float*)d_out);
}

// Round 13
// 303.901 us; speedup vs baseline: 4.5218x; 1.0878x over previous
//
#include <hip/hip_runtime.h>
#include <math.h>

typedef unsigned short u16;
typedef short s16;
typedef u16 u16x8 __attribute__((ext_vector_type(8)));
typedef s16 short8v __attribute__((ext_vector_type(8)));
typedef float f32x4 __attribute__((ext_vector_type(4)));

__device__ __forceinline__ float b2f(u16 u) {
    return __uint_as_float(((unsigned)u) << 16);
}
__device__ __forceinline__ u16 f2b(float f) {        // RNE
    unsigned u = __float_as_uint(f);
    unsigned r = (u + 0x7FFFu + ((u >> 16) & 1u)) >> 16;
    return (u16)r;
}

// ---------------------------------------------------------------------------
// bf16 table conversion: emb/wch/wrh plain (float4-wise) + w2h PERMUTED
// (k' = (py*10+px)*8 + oc  <-  k = oc*100 + py*10+px), one launch.
// ---------------------------------------------------------------------------
__global__ __launch_bounds__(256) void k_cvt_all(
    const float* __restrict__ emb, u16* __restrict__ embh,
    const float* __restrict__ wcf, u16* __restrict__ wch,
    const float* __restrict__ wrf, u16* __restrict__ wrh,
    const float* __restrict__ w2f, u16* __restrict__ w2h)
{
    long j = (long)blockIdx.x * 256 + threadIdx.x;
    if (j < 1056400) {
        float4 v = ((const float4*)emb)[j];
        *(ushort4*)(embh + j * 4) = make_ushort4(f2b(v.x), f2b(v.y), f2b(v.z), f2b(v.w));
        return;
    }
    j -= 1056400;
    if (j < 7500) {
        float4 v = ((const float4*)wcf)[j];
        *(ushort4*)(wch + j * 4) = make_ushort4(f2b(v.x), f2b(v.y), f2b(v.z), f2b(v.w));
        return;
    }
    j -= 7500;
    if (j < 7500) {
        float4 v = ((const float4*)wrf)[j];
        *(ushort4*)(wrh + j * 4) = make_ushort4(f2b(v.x), f2b(v.y), f2b(v.z), f2b(v.w));
        return;
    }
    j -= 7500;
    if (j < 120000) {
        int jj = (int)(j / 800), k = (int)(j % 800);
        int p = k >> 3, oc = k & 7;
        w2h[jj * 800 + k] = f2b(w2f[jj * 800 + oc * 100 + p]);
    }
}

// ---------------------------------------------------------------------------
// Both vocab projections in one launch; both outputs bf16 (stride 152 shorts).
// ---------------------------------------------------------------------------
__global__ __launch_bounds__(256) void k_projmm2(
    const u16* __restrict__ embh, const u16* __restrict__ wc,
    const u16* __restrict__ wr, const float* __restrict__ bc,
    const float* __restrict__ br, u16* __restrict__ outc,
    u16* __restrict__ outr, int V)
{
    __shared__ s16 Ab[2048];      // [kc4][row64][e8]
    __shared__ s16 Bb[2560];      // [kc4][col80][e8]
    __shared__ float bhL[160];
    const int t = threadIdx.x;
    const int w = t >> 6, l = t & 63, lg = l >> 4, lr = l & 15;
    int id = blockIdx.x;
    const int half = (id >= 662) ? 1 : 0;
    id -= half * 662;
    const u16* wh = half ? wr : wc;
    const float* bias = half ? br : bc;
    u16* outp = half ? outr : outc;
    const int mb = id >> 1, nb = id & 1;
    const long rowbase = (long)mb * 64;
    const int colbase = nb * 80;
    if (t < 160) bhL[t] = (t < 150) ? bias[t] : 0.f;

    f32x4 acc[5];
#pragma unroll
    for (int i = 0; i < 5; ++i) acc[i] = (f32x4){0,0,0,0};

    for (int ch = 0; ch < 7; ++ch) {
        __syncthreads();
        {
            int kc = t >> 6, row = t & 63;
            long grow = rowbase + row; if (grow >= V) grow = V - 1;
            int k0 = ch * 32 + kc * 8;
            short8v v = {0,0,0,0,0,0,0,0};
            if (k0 < 200) v = *(const short8v*)(embh + grow * 200 + k0);
            *(short8v*)&Ab[t * 8] = v;
        }
        for (int it = t; it < 320; it += 256) {
            int kc = it / 80, col = it % 80;
            int gcol = colbase + col;
            int k0 = ch * 32 + kc * 8;
            short8v v = {0,0,0,0,0,0,0,0};
            if (gcol < 150 && k0 < 200)
                v = *(const short8v*)(wh + (size_t)gcol * 200 + k0);
            *(short8v*)&Bb[it * 8] = v;
        }
        __syncthreads();
        short8v a = *(short8v*)&Ab[(lg * 64 + w * 16 + lr) * 8];
#pragma unroll
        for (int ct = 0; ct < 5; ++ct) {
            short8v bv = *(short8v*)&Bb[(lg * 80 + ct * 16 + lr) * 8];
            acc[ct] = __builtin_amdgcn_mfma_f32_16x16x32_bf16(a, bv, acc[ct], 0, 0, 0);
        }
    }
#pragma unroll
    for (int ct = 0; ct < 5; ++ct) {
        int gcol = colbase + ct * 16 + lr;
        if (gcol < 150) {
#pragma unroll
            for (int rr = 0; rr < 4; ++rr) {
                long row = rowbase + w * 16 + lg * 4 + rr;
                outp[row * 152 + gcol] = f2b(acc[ct][rr] + bhL[gcol]);
            }
        }
    }
}

// ---------------------------------------------------------------------------
// GRU scan body on caller-provided LDS. MFMA GEMV; Whh B-frags in registers.
// MODE 0: direct fp32 xp (stride 152), fp32 hs (50).
// MODE 2: gather bf16 xp via idx (stride 152), bf16 hs (stride 56).
// LDS bytes: 2048 + SEQS*848 + 608 + 9728.
// ---------------------------------------------------------------------------
template<int MODE, int SEQS>
__device__ __forceinline__ void gru_body(
    char* sm, const void* __restrict__ xp_, const int* __restrict__ idx,
    const float* __restrict__ Whh, const float* __restrict__ bhh,
    void* __restrict__ hs_, int T, long blk)
{
    s16*   hbuf = (s16*)sm;                              // [1024]
    float* ghL  = (float*)(sm + 2048);                   // [SEQS*160]
    float* hL   = (float*)(sm + 2048 + SEQS * 640);      // [SEQS*52]
    float* bhL  = (float*)(sm + 2048 + SEQS * 848);      // [152]
    u16*   xraw = (u16*)(sm + 2048 + SEQS * 848 + 608);  // 9728 B
    const int t = threadIdx.x;
    const int w = t >> 6, l = t & 63, lg = l >> 4, lr = l & 15;
    constexpr int HST = (MODE == 2) ? 56 : 50;
    constexpr int XROW = SEQS * 152;
    u16*   xbH = xraw;
    float* xbF = (float*)xraw;

    for (int li = t; li < 1024; li += 256) hbuf[li] = 0;
    for (int e = t; e < SEQS * 52; e += 256) hL[e] = 0.f;
    if (t < 152) bhL[t] = (t < 150) ? bhh[t] : 0.f;

    const int te_0 = (w * 3     > 9) ? 9 : w * 3;
    const int te_1 = (w * 3 + 1 > 9) ? 9 : w * 3 + 1;
    const int te_2 = (w * 3 + 2 > 9) ? 9 : w * 3 + 2;
    short8v B00 = {0,0,0,0,0,0,0,0}, B01 = B00, B10 = B00, B11 = B00, B20 = B00, B21 = B00;
    {
        int cols[3] = { te_0 * 16 + lr, te_1 * 16 + lr, te_2 * 16 + lr };
        short8v* frg[6] = { &B00, &B01, &B10, &B11, &B20, &B21 };
#pragma unroll
        for (int ti = 0; ti < 3; ++ti) {
            int col = cols[ti];
            if (col < 150) {
#pragma unroll
                for (int s = 0; s < 2; ++s) {
                    short8v v = {0,0,0,0,0,0,0,0};
#pragma unroll
                    for (int e = 0; e < 8; ++e) {
                        int k = (s * 4 + lg) * 8 + e;
                        if (k < 50) v[e] = (s16)f2b(Whh[col * 50 + k]);
                    }
                    *frg[ti * 2 + s] = v;
                }
            }
        }
    }

    const long seqbase = blk * SEQS;
    const float* xpf = (const float*)xp_;
    const u16*   xph = (const u16*)xp_;
    float* hsf = (float*)hs_;
    u16*   hsh = (u16*)hs_;

    const int rA = (MODE == 2) ? t / 19 : t / 38;
    const int oA = (MODE == 2) ? (t % 19) * 8 : (t % 38) * 4;
    const int rB = (MODE == 2) ? (t + 256) / 19 : (t + 256) / 38;
    const int oB = (MODE == 2) ? ((t + 256) % 19) * 8 : ((t + 256) % 38) * 4;
    const bool actA = (MODE == 2) ? (t < SEQS * 19) : true;
    const bool hasB = (MODE == 2) ? (t + 256 < SEQS * 19) : (t + 256 < SEQS * 38);

    auto rowbase = [&](int rr, int stp) -> size_t {
        long r = seqbase + rr;
        long src = (MODE == 0) ? (r * T + stp) : (long)idx[r * T + stp];
        return (size_t)src * 152;
    };

    if (MODE == 2) {
        if (actA) *(u16x8*)&xbH[rA * 152 + oA] = *(const u16x8*)(xph + rowbase(rA, 0) + oA);
        if (hasB) *(u16x8*)&xbH[rB * 152 + oB] = *(const u16x8*)(xph + rowbase(rB, 0) + oB);
    } else {
        *(float4*)&xbF[rA * 152 + oA] = *(const float4*)(xpf + rowbase(rA, 0) + oA);
        if (hasB)
            *(float4*)&xbF[rB * 152 + oB] = *(const float4*)(xpf + rowbase(rB, 0) + oB);
    }
    __syncthreads();

    for (int st = 0; st < T; ++st) {
        const int cur = st & 1;
        u16x8 pfh0, pfh1;
        float4 pf0, pf1;
        if (st + 1 < T) {
            if (MODE == 2) {
                if (actA) pfh0 = *(const u16x8*)(xph + rowbase(rA, st + 1) + oA);
                if (hasB) pfh1 = *(const u16x8*)(xph + rowbase(rB, st + 1) + oB);
            } else {
                pf0 = *(const float4*)(xpf + rowbase(rA, st + 1) + oA);
                if (hasB) pf1 = *(const float4*)(xpf + rowbase(rB, st + 1) + oB);
            }
        }
        short8v a0 = *(short8v*)&hbuf[((0 + lg) * 16 + lr) * 8];
        short8v a1 = *(short8v*)&hbuf[((4 + lg) * 16 + lr) * 8];
        f32x4 c0 = {0,0,0,0}, c1 = {0,0,0,0}, c2 = {0,0,0,0};
        c0 = __builtin_amdgcn_mfma_f32_16x16x32_bf16(a0, B00, c0, 0, 0, 0);
        c0 = __builtin_amdgcn_mfma_f32_16x16x32_bf16(a1, B01, c0, 0, 0, 0);
        c1 = __builtin_amdgcn_mfma_f32_16x16x32_bf16(a0, B10, c1, 0, 0, 0);
        c1 = __builtin_amdgcn_mfma_f32_16x16x32_bf16(a1, B11, c1, 0, 0, 0);
        c2 = __builtin_amdgcn_mfma_f32_16x16x32_bf16(a0, B20, c2, 0, 0, 0);
        c2 = __builtin_amdgcn_mfma_f32_16x16x32_bf16(a1, B21, c2, 0, 0, 0);
        if (lg * 4 < SEQS) {
            int col0 = te_0 * 16 + lr, col1 = te_1 * 16 + lr, col2 = te_2 * 16 + lr;
            if (col0 < 150) {
#pragma unroll
                for (int r = 0; r < 4; ++r) ghL[(lg * 4 + r) * 160 + col0] = c0[r] + bhL[col0];
            }
            if (col1 < 150) {
#pragma unroll
                for (int r = 0; r < 4; ++r) ghL[(lg * 4 + r) * 160 + col1] = c1[r] + bhL[col1];
            }
            if (col2 < 150) {
#pragma unroll
                for (int r = 0; r < 4; ++r) ghL[(lg * 4 + r) * 160 + col2] = c2[r] + bhL[col2];
            }
        }
        __syncthreads();
        if (st + 1 < T) {
            if (MODE == 2) {
                if (actA) *(u16x8*)&xbH[(cur ^ 1) * XROW + rA * 152 + oA] = pfh0;
                if (hasB) *(u16x8*)&xbH[(cur ^ 1) * XROW + rB * 152 + oB] = pfh1;
            } else {
                *(float4*)&xbF[(cur ^ 1) * XROW + rA * 152 + oA] = pf0;
                if (hasB) *(float4*)&xbF[(cur ^ 1) * XROW + rB * 152 + oB] = pf1;
            }
        }
        for (int item = t; item < SEQS * 50; item += 256) {
            int ss = item / 50, hh = item % 50;
            float xv0, xv1, xv2;
            if (MODE == 2) {
                const u16* xr = &xbH[cur * XROW + ss * 152];
                xv0 = b2f(xr[hh]); xv1 = b2f(xr[50 + hh]); xv2 = b2f(xr[100 + hh]);
            } else {
                const float* xr = &xbF[cur * XROW + ss * 152];
                xv0 = xr[hh]; xv1 = xr[50 + hh]; xv2 = xr[100 + hh];
            }
            float vr  = xv0 + ghL[ss * 160 + hh];
            float vz  = xv1 + ghL[ss * 160 + 50 + hh];
            float ghn = ghL[ss * 160 + 100 + hh];
            float rg = 1.f / (1.f + __expf(-vr));
            float zg = 1.f / (1.f + __expf(-vz));
            float a = xv2 + rg * ghn;
            a = fminf(fmaxf(a, -15.f), 15.f);
            float e2 = __expf(-2.f * a);
            float nn2 = (1.f - e2) / (1.f + e2);
            float hn = (1.f - zg) * nn2 + zg * hL[ss * 52 + hh];
            hL[ss * 52 + hh] = hn;
            hbuf[((hh >> 3) * 16 + ss) * 8 + (hh & 7)] = (s16)f2b(hn);
            size_t ofs = ((size_t)(seqbase + ss) * T + st) * HST + hh;
            if (MODE == 2) hsh[ofs] = f2b(hn); else hsf[ofs] = hn;
        }
        __syncthreads();
    }
}

// ---------------------------------------------------------------------------
// Shared conv+pool epilogue on LDS layout: pool16 @0 (9480 s16), wL @18960.
// Pool vectorized: thread t<100 -> (py,px), 9x u16x8 reads, b128 feats write.
// feats k-order: k' = (py*10+px)*8 + oc (matches permuted w2h).
// ---------------------------------------------------------------------------
__device__ __forceinline__ void conv_pool_epi(
    char* sm, u16* __restrict__ feats, long nl, f32x4 cacc0, f32x4 cacc1)
{
    s16* pool16 = (s16*)sm;
    float* wL = (float*)(sm + 18960);
    u16* Mb    = (u16*)pool16;        // [2][1092], row stride 33
    u16* convL = (u16*)pool16 + 2184; // [912][8]
    const int t = threadIdx.x;
    const int w = t >> 6, l = t & 63, lg = l >> 4, lr = l & 15;
    const int job0 = w * 2, job1 = w * 2 + 1;
    const int ch0 = job0 >> 2, rt0 = (job0 >> 1) & 1, ct0 = job0 & 1;
    const int ch1 = job1 >> 2, rt1 = (job1 >> 1) & 1, ct1 = job1 & 1;

    __syncthreads();   // staging reads done; safe to alias with Mb
#pragma unroll
    for (int rr = 0; rr < 4; ++rr) {
        Mb[ch0 * 1092 + (rt0 * 16 + lg * 4 + rr) * 33 + ct0 * 16 + lr] = f2b(cacc0[rr]);
        Mb[ch1 * 1092 + (rt1 * 16 + lg * 4 + rr) * 33 + ct1 * 16 + lr] = f2b(cacc1[rr]);
    }

    short8v Bc = {0,0,0,0,0,0,0,0};
    int dlt[8];
#pragma unroll
    for (int e = 0; e < 8; ++e) {
        int s = lg * 8 + e;
        if (s < 18) {
            int ch = s / 9, r9 = s % 9, ky = r9 / 3, kx = r9 % 3;
            dlt[e] = ch * 1092 + ky * 33 + kx;
            if (lr < 8) Bc[e] = (s16)f2b(wL[lr * 18 + s]);
        } else dlt[e] = 0;
    }
    __syncthreads();   // Mb visible

    for (int tile = w; tile < 57; tile += 4) {
        int m = tile * 16 + lr;
        int cy = m / 30, cx = m - cy * 30;
        int base = cy * 33 + cx;
        short8v a;
#pragma unroll
        for (int e = 0; e < 8; ++e) a[e] = (s16)Mb[base + dlt[e]];
        f32x4 c = {0,0,0,0};
        c = __builtin_amdgcn_mfma_f32_16x16x32_bf16(a, Bc, c, 0, 0, 0);
        if (lr < 8) {
#pragma unroll
            for (int rr = 0; rr < 4; ++rr)
                convL[(tile * 16 + lg * 4 + rr) * 8 + lr] = f2b(c[rr]);
        }
    }
    __syncthreads();

    if (t < 100) {
        int py = t / 10, px = t % 10;
        int m0 = (3 * py) * 30 + 3 * px;
        float mx[8];
#pragma unroll
        for (int c = 0; c < 8; ++c) mx[c] = -1e30f;
#pragma unroll
        for (int dy = 0; dy < 3; ++dy)
#pragma unroll
            for (int dx = 0; dx < 3; ++dx) {
                u16x8 v = *(u16x8*)&convL[(m0 + dy * 30 + dx) * 8];
#pragma unroll
                for (int c = 0; c < 8; ++c) mx[c] = fmaxf(mx[c], b2f(v[c]));
            }
        u16x8 o;
#pragma unroll
        for (int c = 0; c < 8; ++c) o[c] = f2b(mx[c]);
        *(u16x8*)(feats + nl * 800 + t * 8) = o;
    }
}

// ---------------------------------------------------------------------------
// M1 body (slots n = b*14 + r, r<7): match MFMA from embh gathers + epilogue.
// ---------------------------------------------------------------------------
__device__ __forceinline__ void m1_body(
    char* sm, const u16* __restrict__ embh, const int* __restrict__ ctx_idx,
    const int* __restrict__ cand_idx, const float* __restrict__ conv_w,
    u16* __restrict__ feats, int wg)
{
    s16* pool16 = (s16*)sm;
    float* wL = (float*)(sm + 18960);
    int* ci = (int*)(sm + 19536);
    int* qi = (int*)(sm + 19664);     // [2][32]
    const int t = threadIdx.x;
    const int xcd = wg & 7, q = wg >> 3;
    const int r = q % 7, bq = q / 7;
    const int b = bq * 8 + xcd;
    const long nl = (long)b * 14 + r;
    const int w = t >> 6, l = t & 63, lg = l >> 4, lr = l & 15;

    if (t < 144) wL[t] = conv_w[t];

    f32x4 cacc0 = {0,0,0,0}, cacc1 = {0,0,0,0};
    const int job0 = w * 2, job1 = w * 2 + 1;
    const int ch0 = job0 >> 2, rt0 = (job0 >> 1) & 1, ct0 = job0 & 1;
    const int ch1 = job1 >> 2, rt1 = (job1 >> 1) & 1, ct1 = job1 & 1;

    const int c0 = 2 * r;
    if (t < 32) ci[t] = ctx_idx[b * 32 + t];
    else if (t < 96)
        qi[((t - 32) >> 5) * 32 + (t & 31)] =
            cand_idx[((long)b * 14 + c0 + ((t - 32) >> 5)) * 32 + (t & 31)];
    __syncthreads();
    s16* ctxL = pool16;            // [kc<=12][33][8]
    s16* canL = pool16 + 3168;     // [kc<=12][65][8]
#pragma unroll
    for (int cnk = 0; cnk < 3; ++cnk) {
        const int kcbase = (cnk == 0) ? 0 : (cnk == 1 ? 12 : 20);
        const int kccnt  = (cnk == 0) ? 12 : 8;
        const int scnt   = (cnk == 0) ? 3 : 2;
        if (cnk) __syncthreads();
        for (int it = t; it < kccnt * 32; it += 256) {
            int kcl = it >> 5, row = it & 31;
            int kc = kcbase + kcl;
            short8v v = {0,0,0,0,0,0,0,0};
            if (kc < 25) v = *(const short8v*)(embh + (size_t)ci[row] * 200 + kc * 8);
            *(short8v*)&ctxL[(kcl * 33 + row) * 8] = v;
        }
        for (int it = t; it < kccnt * 64; it += 256) {
            int kcl = it >> 6, col = it & 63;
            int kc = kcbase + kcl;
            short8v v = {0,0,0,0,0,0,0,0};
            if (kc < 25)
                v = *(const short8v*)(embh + (size_t)qi[(col >> 5) * 32 + (col & 31)] * 200 + kc * 8);
            *(short8v*)&canL[(kcl * 65 + col) * 8] = v;
        }
        __syncthreads();
        for (int sl = 0; sl < scnt; ++sl) {
            int kcl = sl * 4 + lg;
            short8v a0 = *(short8v*)&ctxL[(kcl * 33 + rt0 * 16 + lr) * 8];
            short8v b0 = *(short8v*)&canL[(kcl * 65 + ch0 * 32 + ct0 * 16 + lr) * 8];
            short8v b1 = *(short8v*)&canL[(kcl * 65 + ch1 * 32 + ct1 * 16 + lr) * 8];
            cacc0 = __builtin_amdgcn_mfma_f32_16x16x32_bf16(a0, b0, cacc0, 0, 0, 0);
            short8v a1 = (rt0 == rt1) ? a0
                       : *(short8v*)&ctxL[(kcl * 33 + rt1 * 16 + lr) * 8];
            cacc1 = __builtin_amdgcn_mfma_f32_16x16x32_bf16(a1, b1, cacc1, 0, 0, 0);
        }
    }
    conv_pool_epi(sm, feats, nl, cacc0, cacc1);
}

// ---------------------------------------------------------------------------
// Merged launch: blocks 0..895 cand-scan, 896..959 ctx-scan, 960.. M1 blocks.
// ---------------------------------------------------------------------------
__global__ __launch_bounds__(256) void k_scan_m1(
    const u16* __restrict__ proj_ch, const u16* __restrict__ proj_rh,
    const int* __restrict__ ctx_idx, const int* __restrict__ cand_idx,
    const float* __restrict__ Whh_c, const float* __restrict__ Whh_r,
    const float* __restrict__ bhh_c, const float* __restrict__ bhh_r,
    u16* __restrict__ ctx_hh, u16* __restrict__ candh_h,
    const u16* __restrict__ embh, const float* __restrict__ conv_w,
    u16* __restrict__ feats)
{
    __shared__ long long smq[3244];   // 25952 B unified pool
    char* sm = (char*)smq;
    const long bid = blockIdx.x;
    if (bid < 960) {
        const bool cand = (bid < 896);
        gru_body<2, 16>(sm,
                        cand ? (const void*)proj_rh : (const void*)proj_ch,
                        cand ? cand_idx : ctx_idx,
                        cand ? Whh_r : Whh_c,
                        cand ? bhh_r : bhh_c,
                        cand ? (void*)candh_h : (void*)ctx_hh,
                        32, cand ? bid : bid - 896);
    } else {
        m1_body(sm, embh, ctx_idx, cand_idx, conv_w, feats, (int)(bid - 960));
    }
}

// ---------------------------------------------------------------------------
// M2 kernel (slots n = b*14 + 7 + r, r<7): ctxA x candh MFMA + epilogue.
// ---------------------------------------------------------------------------
__global__ __launch_bounds__(256) void k_m2conv(
    const u16* __restrict__ ctxA_h, const u16* __restrict__ candh_h,
    const float* __restrict__ conv_w, u16* __restrict__ feats)
{
    __shared__ long long smq[2490];   // 19920 B
    char* sm = (char*)smq;
    s16* pool16 = (s16*)sm;
    float* wL = (float*)(sm + 18960);
    const int t = threadIdx.x;
    const int wg = blockIdx.x;
    const int xcd = wg & 7, q = wg >> 3;
    const int r7 = q % 7, bq = q / 7;
    const int b = bq * 8 + xcd;
    const long nl = (long)b * 14 + 7 + r7;
    const int w = t >> 6, l = t & 63, lg = l >> 4, lr = l & 15;

    if (t < 144) wL[t] = conv_w[t];

    f32x4 cacc0 = {0,0,0,0}, cacc1 = {0,0,0,0};
    const int job0 = w * 2, job1 = w * 2 + 1;
    const int ch0 = job0 >> 2, rt0 = (job0 >> 1) & 1, ct0 = job0 & 1;
    const int ch1 = job1 >> 2, rt1 = (job1 >> 1) & 1, ct1 = job1 & 1;

    const int c0 = 2 * r7;
    s16* aL = pool16;              // [8][33][8]
    s16* cL = pool16 + 2112;       // [8][65][8]
    for (int it = t; it < 256; it += 256) {
        int kc = it >> 5, row = it & 31;
        short8v v = {0,0,0,0,0,0,0,0};
        if (kc < 7) {
            v = *(const short8v*)(ctxA_h + (size_t)(b * 32 + row) * 56 + kc * 8);
            if (kc == 6) { v[2] = 0; v[3] = 0; v[4] = 0; v[5] = 0; v[6] = 0; v[7] = 0; }
        }
        *(short8v*)&aL[(kc * 33 + row) * 8] = v;
    }
    for (int it = t; it < 512; it += 256) {
        int kc = it >> 6, col = it & 63;
        long row = ((long)b * 14 + c0 + (col >> 5)) * 32 + (col & 31);
        short8v v = {0,0,0,0,0,0,0,0};
        if (kc < 7) {
            v = *(const short8v*)(candh_h + (size_t)row * 56 + kc * 8);
            if (kc == 6) { v[2] = 0; v[3] = 0; v[4] = 0; v[5] = 0; v[6] = 0; v[7] = 0; }
        }
        *(short8v*)&cL[(kc * 65 + col) * 8] = v;
    }
    __syncthreads();
#pragma unroll
    for (int sl = 0; sl < 2; ++sl) {
        int kcl = sl * 4 + lg;
        short8v a0 = *(short8v*)&aL[(kcl * 33 + rt0 * 16 + lr) * 8];
        short8v b0 = *(short8v*)&cL[(kcl * 65 + ch0 * 32 + ct0 * 16 + lr) * 8];
        short8v b1 = *(short8v*)&cL[(kcl * 65 + ch1 * 32 + ct1 * 16 + lr) * 8];
        cacc0 = __builtin_amdgcn_mfma_f32_16x16x32_bf16(a0, b0, cacc0, 0, 0, 0);
        short8v a1 = (rt0 == rt1) ? a0
                   : *(short8v*)&aL[(kcl * 33 + rt1 * 16 + lr) * 8];
        cacc1 = __builtin_amdgcn_mfma_f32_16x16x32_bf16(a1, b1, cacc1, 0, 0, 0);
    }
    conv_pool_epi(sm, feats, nl, cacc0, cacc1);
}

// GRU2 scan: direct fp32 xp2, fp32 hs2.
__global__ __launch_bounds__(256) void k_scan2(
    const float* __restrict__ xp2, const float* __restrict__ Whh2,
    const float* __restrict__ bhh2, float* __restrict__ hs2)
{
    __shared__ long long smq[2396];   // 19168 B
    gru_body<0, 8>((char*)smq, xp2, nullptr, Whh2, bhh2, hs2, 14, (long)blockIdx.x);
}

// ---------------------------------------------------------------------------
// ctxA[r][k] (bf16, stride 56) = sum_j b2f(ctx_hh[r][j]) * A[j][k]
// ---------------------------------------------------------------------------
__global__ __launch_bounds__(256) void k_matA(
    const u16* __restrict__ inh, const float* __restrict__ A,
    u16* __restrict__ outh)
{
    __shared__ float AL[50 * 52];
    __shared__ float inL[32 * 52];
    const int t = threadIdx.x;
    for (int e = t; e < 2500; e += 256) AL[(e / 50) * 52 + (e % 50)] = A[e];
    const long rbase = (long)blockIdx.x * 32;
    for (int e = t; e < 1600; e += 256) {
        int r = e / 50, j = e % 50;
        inL[r * 52 + j] = b2f(inh[(rbase + r) * 56 + j]);
    }
    __syncthreads();
    for (int item = t; item < 1600; item += 256) {
        int r = item / 50, kk = item % 50;
        float acc = 0.f;
#pragma unroll 10
        for (int j = 0; j < 50; ++j)
            acc += inL[r * 52 + j] * AL[j * 52 + kk];
        outh[(rbase + r) * 56 + kk] = f2b(acc);
    }
}

// ---------------------------------------------------------------------------
// xp2 MFMA GEMM: out[r][j] (fp32, stride 152) = dot(feats[r], W2[j]) + bih2[j]
// (k-order of feats and w2h is the shared permuted order.)
// ---------------------------------------------------------------------------
__global__ __launch_bounds__(256) void k_xp2mm(
    const u16* __restrict__ feats, const u16* __restrict__ w2h,
    const float* __restrict__ bih2, float* __restrict__ out)
{
    __shared__ s16 Ab[2048];      // [kc4][row64][e8]
    __shared__ s16 Bb[2560];      // [kc4][col80][e8]
    __shared__ float bhL[160];
    const int t = threadIdx.x;
    const int w = t >> 6, l = t & 63, lg = l >> 4, lr = l & 15;
    const int mb = blockIdx.x >> 1, nb = blockIdx.x & 1;
    const long rowbase = (long)mb * 64;
    const int colbase = nb * 80;
    if (t < 160) bhL[t] = (t < 150) ? bih2[t] : 0.f;

    f32x4 acc[5];
#pragma unroll
    for (int i = 0; i < 5; ++i) acc[i] = (f32x4){0,0,0,0};

    for (int ch = 0; ch < 25; ++ch) {
        __syncthreads();
        {
            int kc = t >> 6, row = t & 63;
            *(short8v*)&Ab[t * 8] =
                *(const short8v*)(feats + (rowbase + row) * 800 + ch * 32 + kc * 8);
        }
        for (int it = t; it < 320; it += 256) {
            int kc = it / 80, col = it % 80;
            int gcol = colbase + col;
            short8v v = {0,0,0,0,0,0,0,0};
            if (gcol < 150)
                v = *(const short8v*)(w2h + (size_t)gcol * 800 + ch * 32 + kc * 8);
            *(short8v*)&Bb[it * 8] = v;
        }
        __syncthreads();
        short8v a = *(short8v*)&Ab[(lg * 64 + w * 16 + lr) * 8];
#pragma unroll
        for (int ct = 0; ct < 5; ++ct) {
            short8v bv = *(short8v*)&Bb[(lg * 80 + ct * 16 + lr) * 8];
            acc[ct] = __builtin_amdgcn_mfma_f32_16x16x32_bf16(a, bv, acc[ct], 0, 0, 0);
        }
    }
#pragma unroll
    for (int ct = 0; ct < 5; ++ct) {
        int gcol = colbase + ct * 16 + lr;
        if (gcol < 150) {
#pragma unroll
            for (int rr = 0; rr < 4; ++rr) {
                long row = rowbase + w * 16 + lg * 4 + rr;
                out[row * 152 + gcol] = acc[ct][rr] + bhL[gcol];
            }
        }
    }
}

// ---------------------------------------------------------------------------
// fc1 + fc2 + log_softmax + KL fused: one block per b.
// ---------------------------------------------------------------------------
__global__ __launch_bounds__(128) void k_head(
    const float* __restrict__ Hs, const float* __restrict__ w1,
    const float* __restrict__ b1, const float* __restrict__ w2,
    const float* __restrict__ b2, const float* __restrict__ y,
    float* __restrict__ partial)
{
    __shared__ float hr[700];
    __shared__ float hidL[100];
    const int t = threadIdx.x;
    const long b = blockIdx.x;
    for (int e = t; e < 700; e += 128) hr[e] = Hs[b * 700 + e];
    __syncthreads();
    if (t < 100) {
        float acc = b1[t];
        const float4* wp = (const float4*)(w1 + (size_t)t * 700);
        for (int k4 = 0; k4 < 175; ++k4) {
            float4 wv = wp[k4];
            float4 hv = *(float4*)&hr[k4 * 4];
            acc += wv.x * hv.x + wv.y * hv.y + wv.z * hv.z + wv.w * hv.w;
        }
        hidL[t] = fmaxf(acc, 0.f);
    }
    __syncthreads();
    if (t < 64) {
        float logit = -1e30f;
        if (t < 14) {
            logit = b2[t];
            for (int k = 0; k < 100; ++k) logit += hidL[k] * w2[t * 100 + k];
        }
        float m = logit;
        for (int off = 8; off; off >>= 1) m = fmaxf(m, __shfl_xor(m, off, 16));
        float ex = (t < 14) ? __expf(logit - m) : 0.f;
        float se = ex;
        for (int off = 8; off; off >>= 1) se += __shfl_xor(se, off, 16);
        float kl = 0.f;
        if (t < 14) {
            float lp = logit - m - __logf(se);
            float yv = y[b * 14 + t];
            kl = (yv > 0.f) ? yv * (__logf(yv) - lp) : 0.f;
        }
        for (int off = 8; off; off >>= 1) kl += __shfl_xor(kl, off, 16);
        if (t == 0) partial[b] = kl;
    }
}

__global__ __launch_bounds__(256) void k_reduce(
    const float* __restrict__ partial, float* __restrict__ out)
{
    __shared__ float sm[256];
    const int t = threadIdx.x;
    sm[t] = partial[t] + partial[t + 256] + partial[t + 512] + partial[t + 768];
    __syncthreads();
    for (int off = 128; off; off >>= 1) {
        if (t < off) sm[t] += sm[t + off];
        __syncthreads();
    }
    if (t == 0) out[0] = sm[0] * (1.f / 14336.f);
}

// ---------------------------------------------------------------------------
extern "C" void kernel_launch(void* const* d_in, const int* in_sizes, int n_in,
                              void* d_out, int out_size, void* d_ws, size_t ws_size,
                              hipStream_t stream)
{
    const int*   ctx_idx  = (const int*)d_in[0];
    const int*   cand_idx = (const int*)d_in[1];
    const float* y_dev    = (const float*)d_in[2];
    const float* emb      = (const float*)d_in[3];
    const float* A        = (const float*)d_in[4];
    const float* Wih_c    = (const float*)d_in[5];
    const float* Whh_c    = (const float*)d_in[6];
    const float* bih_c    = (const float*)d_in[7];
    const float* bhh_c    = (const float*)d_in[8];
    const float* Wih_r    = (const float*)d_in[9];
    const float* Whh_r    = (const float*)d_in[10];
    const float* bih_r    = (const float*)d_in[11];
    const float* bhh_r    = (const float*)d_in[12];
    const float* conv_w   = (const float*)d_in[13];
    const float* Wih2     = (const float*)d_in[14];
    const float* Whh2     = (const float*)d_in[15];
    const float* bih2     = (const float*)d_in[16];
    const float* bhh2     = (const float*)d_in[17];
    const float* fc1_w    = (const float*)d_in[18];
    const float* fc1_b    = (const float*)d_in[19];
    const float* fc2_w    = (const float*)d_in[20];
    const float* fc2_b    = (const float*)d_in[21];

    float* ws = (float*)d_ws;
    // Arena (float slots), total 28,734,128 f = 114.9 MB. All regions disjoint.
    u16*   embh    = (u16*)ws;               // [21128][200] bf16 = 2,112,800 f
    u16*   proj_ch = (u16*)(ws + 2112800);   // [21184][152] bf16 = 1,609,984 f
    u16*   proj_rh = (u16*)(ws + 3722784);   // [21184][152] bf16 = 1,609,984 f
    u16*   ctx_hh  = (u16*)(ws + 5332768);   // [32768][56] bf16 = 917,504 f
    u16*   ctxA_h  = (u16*)(ws + 6250272);   // [32768][56] bf16 = 917,504 f
    u16*   candh_h = (u16*)(ws + 7167776);   // [458752][56] bf16 = 12,845,056 f
    u16*   feats_h = (u16*)(ws + 20012832);  // [14336][800] bf16 = 5,734,400 f
    u16*   w2h     = (u16*)(ws + 25747232);  // [150][800] bf16 = 60,000 f
    u16*   wch     = (u16*)(ws + 25807232);  // [150][200] bf16 = 15,000 f
    u16*   wrh     = (u16*)(ws + 25822232);  // [150][200] bf16 = 15,000 f
    float* xp2     = ws + 25837232;          // [14336][152] = 2,179,072
    float* hs2     = ws + 28016304;          // 716,800
    float* part    = ws + 28733104;          // 1,024

    // 0. bf16 tables (one launch; w2h stored k-permuted)
    k_cvt_all <<<4654, 256, 0, stream>>>(emb, embh, Wih_c, wch, Wih_r, wrh,
                                         Wih2, w2h);
    // 1. both vocab projections (one launch, bih folded, bf16 out)
    k_projmm2 <<<1324, 256, 0, stream>>>(embh, wch, wrh, bih_c, bih_r,
                                         proj_ch, proj_rh, 21128);
    // 2. merged: GRU scans (960 blocks) + M1 match+conv+pool (7168 blocks)
    k_scan_m1 <<<8128, 256, 0, stream>>>(proj_ch, proj_rh, ctx_idx, cand_idx,
                                         Whh_c, Whh_r, bhh_c, bhh_r,
                                         ctx_hh, candh_h, embh, conv_w, feats_h);
    k_matA <<<1024, 256, 0, stream>>>(ctx_hh, A, ctxA_h);
    // 3. M2 match+conv+pool
    k_m2conv <<<7168, 256, 0, stream>>>(ctxA_h, candh_h, conv_w, feats_h);
    // 4. accumulation GRU + fused head
    k_xp2mm <<<448, 256, 0, stream>>>(feats_h, w2h, bih2, xp2);
    k_scan2 <<<128, 256, 0, stream>>>(xp2, Whh2, bhh2, hs2);
    k_head <<<1024, 128, 0, stream>>>(hs2, fc1_w, fc1_b, fc2_w, fc2_b, y_dev, part);
    k_reduce <<<1, 256, 0, stream>>>(part, (float*)d_out);
}